// Round 8
// baseline (718.723 us; speedup 1.0000x reference)
//
#include <hip/hip_runtime.h>
#include <math.h>

// ---------------------------------------------------------------------------
// VQ-VAE forward: NHWC bf16 trunk, implicit-GEMM MFMA convs (fp32 accum,
// BK=64 K-chunks to halve barrier count), LDS-staged packed-key MFMA VQ,
// MFMA tc2, weight-stationary conv1 with LDS-coalesced stores.
//
// Workspace layout (bytes):
//   [0 .. ~2.0MB)   transformed weights + counts/sse + Ebf + enorm1
//   H1  = 2097152   (64,64,64,64)  NHWC bf16  33.5MB   h1, later tc1 out
//   TR  = 35651584  (64,32,32,128) NHWC bf16  16.8MB   enc trunk
//   H3  = 52428800  (64,32,32,128) NHWC bf16  16.8MB   h3, later dec trunk
//   MID = 69206016  (64,32,32,64)  NHWC bf16   8.4MB   res mid
//   ZE  = 77594624  (64,32,32,64)  NHWC bf16   8.4MB
//   ZQ  = 85983232  (64,32,32,64)  NHWC bf16   8.4MB
//   IDX = 94371840  65536 u16      128KB
// ---------------------------------------------------------------------------

typedef unsigned short u16;
typedef __attribute__((ext_vector_type(8))) short bf16x8;
typedef __attribute__((ext_vector_type(4))) float f32x4;

__device__ __forceinline__ float bf2f(u16 h) {
    union { unsigned u; float f; } v; v.u = ((unsigned)h) << 16; return v.f;
}
__device__ __forceinline__ u16 f2bf(float f) {
    union { float f; unsigned u; } v; v.f = f;
    unsigned r = v.u + 0x7FFFu + ((v.u >> 16) & 1u);
    return (u16)(r >> 16);
}
__device__ __forceinline__ unsigned relu2(unsigned x) {
    return x & ~(((x & 0x80008000u) >> 15) * 0xFFFFu);
}

struct Taps { int s; int ntaps; int dh[16]; int dw[16]; };

// ---------------- unified implicit-GEMM MFMA conv (BK=64) ----------------
template<int CIN, int COUT, bool RELU_IN, bool RELU_OUT, bool HAS_BIAS, bool RESID>
__global__ __launch_bounds__(256)
void mfma_conv_k(const u16* __restrict__ in, const u16* __restrict__ wT,
                 const float* __restrict__ bias, u16* __restrict__ out,
                 int Hin, int Win, int Hout, int Wout, int OS, int OPH, int OPW,
                 Taps taps)
{
    constexpr int WN = (COUT == 128) ? 2 : 1;
    constexpr int WM = 4 / WN;
    constexpr int TM = (128 / WM) / 16;
    constexpr int TN = (COUT / WN) / 16;
    constexpr int LDA = 72;  // 64 data + 8 pad (u16)

    __shared__ alignas(16) u16 aT[128 * LDA];
    __shared__ alignas(16) u16 bT[COUT * LDA];

    const int tid = threadIdx.x;
    const int m0 = blockIdx.x * 128;
    const int n_img = m0 >> 10;
    const int pixbase = m0 & 1023;

    const int r = tid >> 1, half = tid & 1;   // staging: row r, 64B half
    const int pr = pixbase + r;
    const int ohr = pr >> 5, owr = pr & 31;
    const u16* inb = in + (size_t)n_img * Hin * Win * CIN;

    const int wv = tid >> 6, lane = tid & 63;
    const int q = lane >> 4, l16 = lane & 15;
    const int wm = wv / WN, wn = wv % WN;
    const int mbase = wm * (TM * 16), cbase = wn * (TN * 16);

    f32x4 acc[TM][TN] = {};

    for (int t = 0; t < taps.ntaps; ++t) {
        const int ih = ohr * taps.s + taps.dh[t];
        const int iw = owr * taps.s + taps.dw[t];
        const bool ok = ((unsigned)ih < (unsigned)Hin) && ((unsigned)iw < (unsigned)Win);
        const u16* asrc = ok ? (inb + ((size_t)ih * Win + iw) * CIN + half * 32) : inb;
        const u16* bsrc = wT + ((size_t)t * COUT + r) * CIN + half * 32;

        for (int c0 = 0; c0 < CIN; c0 += 64) {
            __syncthreads();
            uint4 av[4] = {};
            if (ok) {
                #pragma unroll
                for (int j = 0; j < 4; ++j)
                    av[j] = *(const uint4*)(asrc + c0 + j * 8);
            }
            if (RELU_IN) {
                #pragma unroll
                for (int j = 0; j < 4; ++j) {
                    av[j].x = relu2(av[j].x); av[j].y = relu2(av[j].y);
                    av[j].z = relu2(av[j].z); av[j].w = relu2(av[j].w);
                }
            }
            #pragma unroll
            for (int j = 0; j < 4; ++j)
                *(uint4*)&aT[r * LDA + half * 32 + j * 8] = av[j];
            if (COUT == 128 || r < COUT) {
                #pragma unroll
                for (int j = 0; j < 4; ++j)
                    *(uint4*)&bT[r * LDA + half * 32 + j * 8] =
                        *(const uint4*)(bsrc + c0 + j * 8);
            }
            __syncthreads();

            #pragma unroll
            for (int kk = 0; kk < 2; ++kk) {
                bf16x8 afr[TM], bfr[TN];
                #pragma unroll
                for (int tm = 0; tm < TM; ++tm)
                    afr[tm] = *(const bf16x8*)&aT[(mbase + tm*16 + l16) * LDA + kk*32 + q * 8];
                #pragma unroll
                for (int tn = 0; tn < TN; ++tn)
                    bfr[tn] = *(const bf16x8*)&bT[(cbase + tn*16 + l16) * LDA + kk*32 + q * 8];
                #pragma unroll
                for (int tm = 0; tm < TM; ++tm)
                    #pragma unroll
                    for (int tn = 0; tn < TN; ++tn)
                        acc[tm][tn] = __builtin_amdgcn_mfma_f32_16x16x32_bf16(
                            afr[tm], bfr[tn], acc[tm][tn], 0, 0, 0);
            }
        }
    }

    #pragma unroll
    for (int tm = 0; tm < TM; ++tm) {
        #pragma unroll
        for (int tn = 0; tn < TN; ++tn) {
            const int col = cbase + tn*16 + l16;
            const float bv = HAS_BIAS ? bias[col] : 0.0f;
            #pragma unroll
            for (int rg = 0; rg < 4; ++rg) {
                const int m = mbase + tm*16 + q*4 + rg;
                const int pix = pixbase + m;
                const int oh = pix >> 5, ow = pix & 31;
                size_t oidx = (((size_t)n_img * Hout + (oh*OS + OPH)) * Wout
                               + (ow*OS + OPW)) * COUT + col;
                float v = acc[tm][tn][rg] + bv;
                if (RESID) v += bf2f(out[oidx]);
                if (RELU_OUT) v = fmaxf(v, 0.0f);
                out[oidx] = f2bf(v);
            }
        }
    }
}

// ---------------- conv1: weight-stationary + LDS-coalesced stores ------------
__global__ __launch_bounds__(256)
void conv1_k(const float* __restrict__ x, const float* __restrict__ w,
             const float* __restrict__ b, u16* __restrict__ out)
{
    constexpr int LDC = 72;
    __shared__ alignas(16) u16 cbuf[256 * LDC];

    int tid = threadIdx.x;
    int gpix = blockIdx.x * 256 + tid;
    int ow = gpix & 63, oh = (gpix >> 6) & 63, n = gpix >> 12;
    const float* xb = x + (size_t)n * 3 * 16384;
    const int ih0 = oh * 2 - 1, iw0 = ow * 2 - 1;

    float xr[48];
    #pragma unroll
    for (int ci = 0; ci < 3; ++ci) {
        #pragma unroll
        for (int kh = 0; kh < 4; ++kh) {
            int ih = ih0 + kh;
            bool rowok = (unsigned)ih < 128u;
            #pragma unroll
            for (int kw = 0; kw < 4; ++kw) {
                int iw = iw0 + kw;
                bool ok = rowok && ((unsigned)iw < 128u);
                xr[ci*16 + kh*4 + kw] = ok ? xb[ci*16384 + ih*128 + iw] : 0.0f;
            }
        }
    }

    #pragma unroll
    for (int cg = 0; cg < 8; ++cg) {
        unsigned pk[4];
        #pragma unroll
        for (int cp = 0; cp < 4; ++cp) {
            const int co = cg*8 + cp*2;
            float a0 = b[co], a1 = b[co + 1];
            const float* w0 = w + co * 48;
            #pragma unroll
            for (int j = 0; j < 48; ++j) {
                a0 = fmaf(xr[j], w0[j],      a0);
                a1 = fmaf(xr[j], w0[48 + j], a1);
            }
            a0 = fmaxf(a0, 0.0f);
            a1 = fmaxf(a1, 0.0f);
            pk[cp] = (unsigned)f2bf(a0) | ((unsigned)f2bf(a1) << 16);
        }
        *(uint4*)&cbuf[tid * LDC + cg * 8] = *(uint4*)pk;
    }
    __syncthreads();

    u16* ob = out + (size_t)blockIdx.x * 256 * 64;
    #pragma unroll
    for (int it = 0; it < 8; ++it) {
        int j = it * 256 + tid;
        uint4 v = *(const uint4*)&cbuf[(j >> 3) * LDC + (j & 7) * 8];
        *(uint4*)(ob + j * 8) = v;
    }
}

// ---------------- tc2 as MFMA parity GEMM ----------------
__global__ __launch_bounds__(256)
void tc2_mfma_k(const u16* __restrict__ in, const u16* __restrict__ wT,
                const float* __restrict__ bias, float* __restrict__ out)
{
    constexpr int LDA = 40;
    __shared__ alignas(16) u16 aT[128 * LDA];
    __shared__ alignas(16) u16 bT[16 * LDA];
    __shared__ float cT[128 * 17];

    const int tid = threadIdx.x;
    const int m0 = blockIdx.x * 128;
    const int n_img = m0 >> 12;
    const int pixbase = m0 & 4095;
    const int y0 = pixbase >> 6;

    const int r = tid >> 1, half = tid & 1;
    const int pr = pixbase + r;
    const int yr = pr >> 6, xr = pr & 63;
    const u16* inb = in + (size_t)n_img * 4096 * 64;

    const int wv = tid >> 6, lane = tid & 63;
    const int q = lane >> 4, l16 = lane & 15;
    const int mbase = wv * 32;

    f32x4 acc[2] = {};

    for (int t = 0; t < 9; ++t) {
        const int ih = yr + t/3 - 1;
        const int iw = xr + t%3 - 1;
        const bool ok = ((unsigned)ih < 64u) && ((unsigned)iw < 64u);
        const u16* asrc = ok ? (inb + ((size_t)ih * 64 + iw) * 64 + half * 16) : inb;
        const u16* bsrc = wT + ((size_t)t * 16 + r) * 64 + half * 16;

        for (int c0 = 0; c0 < 64; c0 += 32) {
            __syncthreads();
            uint4 a0 = {0,0,0,0}, a1 = {0,0,0,0};
            if (ok) {
                a0 = *(const uint4*)(asrc + c0);
                a1 = *(const uint4*)(asrc + c0 + 8);
            }
            *(uint4*)&aT[r * LDA + half * 16]     = a0;
            *(uint4*)&aT[r * LDA + half * 16 + 8] = a1;
            if (r < 16) {
                *(uint4*)&bT[r * LDA + half * 16]     = *(const uint4*)(bsrc + c0);
                *(uint4*)&bT[r * LDA + half * 16 + 8] = *(const uint4*)(bsrc + c0 + 8);
            }
            __syncthreads();

            bf16x8 af0 = *(const bf16x8*)&aT[(mbase + l16) * LDA + q * 8];
            bf16x8 af1 = *(const bf16x8*)&aT[(mbase + 16 + l16) * LDA + q * 8];
            bf16x8 bf  = *(const bf16x8*)&bT[l16 * LDA + q * 8];
            acc[0] = __builtin_amdgcn_mfma_f32_16x16x32_bf16(af0, bf, acc[0], 0, 0, 0);
            acc[1] = __builtin_amdgcn_mfma_f32_16x16x32_bf16(af1, bf, acc[1], 0, 0, 0);
        }
    }

    #pragma unroll
    for (int tm = 0; tm < 2; ++tm)
        #pragma unroll
        for (int rg = 0; rg < 4; ++rg)
            cT[(mbase + tm*16 + q*4 + rg) * 17 + l16] = acc[tm][rg];
    __syncthreads();

    #pragma unroll
    for (int it = 0; it < 6; ++it) {
        int j = it * 256 + tid;
        int co  = j >> 9;
        int rem = j & 511;
        int ohl = rem >> 7;
        int ow  = rem & 127;
        int oh  = 2*y0 + ohl;
        int lp  = (ohl >> 1) * 64 + (ow >> 1);
        int col = ((ohl & 1) * 2 + (ow & 1)) * 4 + co;
        float v = cT[lp * 17 + col] + bias[co];
        out[(((size_t)n_img * 3 + co) * 128 + oh) * 128 + ow] = v;
    }
}

// ---------------- VQ: E prep (stores enorm+1 for packed-key trick) ----------
__global__ void eprep_k(const float* __restrict__ E, u16* __restrict__ Ebf,
                        float* __restrict__ enorm1)
{
    int k = blockIdx.x * 256 + threadIdx.x;
    if (k >= 512) return;
    float s = 0.0f;
    #pragma unroll
    for (int d = 0; d < 64; ++d) {
        u16 h = f2bf(E[k*64 + d]);
        Ebf[k*64 + d] = h;
        float v = bf2f(h);
        s = fmaf(v, v, s);
    }
    enorm1[k] = s + 1.0f;   // +1 bias keeps scores positive -> uint-sortable
}

// ---------------- MFMA vector quantizer: LDS codebook + packed-key argmin ----
// Block = 256 thr (4 waves), 128 positions (32/wave = 2 A-tiles). Codebook
// staged in LDS in 2 passes of 256 codes (37KB). score+1 > 0, so fp32 bits
// are order-isomorphic; key = (bits & ~511) | code_idx; v_min_u32 reduce.
__global__ __launch_bounds__(256)
void vq_mfma_k(const u16* __restrict__ Ze, const u16* __restrict__ Ebf,
               const float* __restrict__ enorm1, u16* __restrict__ Zq,
               u16* __restrict__ idx_out, float* __restrict__ sse)
{
    __shared__ alignas(16) u16 eld[256 * 72];
    __shared__ float en1s[256];
    __shared__ int bestk_s[128];
    __shared__ float red[256];

    const int tid = threadIdx.x;
    const int lane = tid & 63, wv = tid >> 6;
    const int q = lane >> 4, l16 = lane & 15;
    const int pb = blockIdx.x * 128 + wv * 32;

    bf16x8 alo[2], ahi[2];
    #pragma unroll
    for (int tile = 0; tile < 2; ++tile) {
        const u16* zp = Ze + (size_t)(pb + tile*16 + l16) * 64;
        alo[tile] = *(const bf16x8*)(zp + q * 8);
        ahi[tile] = *(const bf16x8*)(zp + 32 + q * 8);
    }

    unsigned key[2][4] = {{0xFFFFFFFFu,0xFFFFFFFFu,0xFFFFFFFFu,0xFFFFFFFFu},
                          {0xFFFFFFFFu,0xFFFFFFFFu,0xFFFFFFFFu,0xFFFFFFFFu}};

    for (int k0 = 0; k0 < 512; k0 += 256) {
        __syncthreads();
        const uint4* src = (const uint4*)(Ebf + k0 * 64);
        #pragma unroll
        for (int i = tid; i < 2048; i += 256) {
            int row = i >> 3, sub = i & 7;
            *(uint4*)&eld[row * 72 + sub * 8] = src[i];
        }
        en1s[tid] = enorm1[k0 + tid];
        __syncthreads();

        for (int t = 0; t < 16; ++t) {
            const int nl = t * 16 + l16;
            bf16x8 b0 = *(const bf16x8*)&eld[nl * 72 + q * 8];
            bf16x8 b1 = *(const bf16x8*)&eld[nl * 72 + 32 + q * 8];
            const float en1 = en1s[nl];
            const unsigned ng = (unsigned)(k0 + nl);
            #pragma unroll
            for (int tile = 0; tile < 2; ++tile) {
                f32x4 acc = {0.0f, 0.0f, 0.0f, 0.0f};
                acc = __builtin_amdgcn_mfma_f32_16x16x32_bf16(alo[tile], b0, acc, 0, 0, 0);
                acc = __builtin_amdgcn_mfma_f32_16x16x32_bf16(ahi[tile], b1, acc, 0, 0, 0);
                #pragma unroll
                for (int rg = 0; rg < 4; ++rg) {
                    float sc = fmaf(acc[rg], -2.0f, en1);
                    unsigned kk2 = (__float_as_uint(sc) & 0xFFFFFE00u) | ng;
                    key[tile][rg] = min(key[tile][rg], kk2);
                }
            }
        }
    }

    #pragma unroll
    for (int m = 1; m < 16; m <<= 1) {
        #pragma unroll
        for (int tile = 0; tile < 2; ++tile)
            #pragma unroll
            for (int rg = 0; rg < 4; ++rg) {
                unsigned o = (unsigned)__shfl_xor((int)key[tile][rg], m, 64);
                key[tile][rg] = min(key[tile][rg], o);
            }
    }
    if (l16 == 0) {
        #pragma unroll
        for (int tile = 0; tile < 2; ++tile)
            #pragma unroll
            for (int rg = 0; rg < 4; ++rg)
                bestk_s[wv * 32 + tile * 16 + q * 4 + rg] = (int)(key[tile][rg] & 511u);
    }
    __syncthreads();

    // epilogue: 2 threads/position, 32 elems each; coalesced Zq writes
    const int pos = tid >> 1, seg = tid & 1;
    const int p = blockIdx.x * 128 + pos;
    const int k = bestk_s[pos];
    const u16* ep = Ebf + (size_t)k * 64 + seg * 32;
    const u16* zp = Ze + (size_t)p * 64 + seg * 32;
    u16* qp = Zq + (size_t)p * 64 + seg * 32;
    float local = 0.0f;
    #pragma unroll
    for (int h = 0; h < 4; ++h) {
        uint4 ev = *(const uint4*)(ep + h * 8);
        uint4 zv = *(const uint4*)(zp + h * 8);
        *(uint4*)(qp + h * 8) = ev;
        unsigned ea[4] = {ev.x, ev.y, ev.z, ev.w};
        unsigned za[4] = {zv.x, zv.y, zv.z, zv.w};
        #pragma unroll
        for (int j = 0; j < 4; ++j) {
            float d0 = bf2f((u16)(ea[j] & 0xFFFFu)) - bf2f((u16)(za[j] & 0xFFFFu));
            float d1 = bf2f((u16)(ea[j] >> 16))     - bf2f((u16)(za[j] >> 16));
            local = fmaf(d0, d0, fmaf(d1, d1, local));
        }
    }
    if (seg == 0) idx_out[p] = (u16)k;
    red[tid] = local;
    __syncthreads();
    for (int s = 128; s > 0; s >>= 1) {
        if (tid < s) red[tid] += red[tid + s];
        __syncthreads();
    }
    if (tid == 0) atomicAdd(sse, red[0]);
}

// ---------------- histogram by scan: block k counts code k ----------------
__global__ __launch_bounds__(256)
void hist_k(const u16* __restrict__ idx, float* __restrict__ counts)
{
    __shared__ int red[256];
    const int k = blockIdx.x;
    const int tid = threadIdx.x;
    int c = 0;
    const uint4* p4 = (const uint4*)idx;
    for (int i = tid; i < 8192; i += 256) {
        uint4 v = p4[i];
        unsigned ua[4] = {v.x, v.y, v.z, v.w};
        #pragma unroll
        for (int j = 0; j < 4; ++j) {
            c += ((ua[j] & 0xFFFFu) == (unsigned)k);
            c += ((ua[j] >> 16)     == (unsigned)k);
        }
    }
    red[tid] = c;
    __syncthreads();
    for (int s = 128; s > 0; s >>= 1) {
        if (tid < s) red[tid] += red[tid + s];
        __syncthreads();
    }
    if (tid == 0) counts[k] = (float)red[0];
}

// ---------------- weight transforms ----------------
__global__ void wconv_tf_k(const float* __restrict__ w, u16* __restrict__ o,
                           int COUT, int CIN, int KK, int total)
{
    int i = blockIdx.x * 256 + threadIdx.x;
    if (i >= total) return;
    int ci = i % CIN; int t = i / CIN; int co = t % COUT; t /= COUT;
    o[i] = f2bf(w[(co*CIN + ci)*KK + t]);
}
__global__ void wtc1_tf_k(const float* __restrict__ w, u16* __restrict__ o)
{
    int i = blockIdx.x * 256 + threadIdx.x;
    if (i >= 131072) return;
    int ci = i & 127; int co = (i >> 7) & 63; int t = (i >> 13) & 3; int p = i >> 15;
    int poh = p >> 1, pw = p & 1; int a = t >> 1, bb = t & 1;
    int kh = poh ? (a ? 2 : 0) : (a ? 3 : 1);
    int kw = pw  ? (bb ? 2 : 0) : (bb ? 3 : 1);
    o[i] = f2bf(w[((ci*64 + co)*4 + kh)*4 + kw]);
}
__global__ void wtc2b_tf_k(const float* __restrict__ w, u16* __restrict__ o)
{
    int i = blockIdx.x * 256 + threadIdx.x;   // 9216
    if (i >= 9216) return;
    int ci = i & 63; int col = (i >> 6) & 15; int t = i >> 10;
    int dh = t / 3 - 1, dw = t % 3 - 1;
    int pp = col >> 2, co = col & 3;
    float v = 0.0f;
    if (co < 3) {
        int poh = pp >> 1, pw = pp & 1;
        int kh = poh ? (dh == 1 ? 0 : (dh == 0 ? 2 : -1))
                     : (dh == 0 ? 1 : (dh == -1 ? 3 : -1));
        int kw = pw  ? (dw == 1 ? 0 : (dw == 0 ? 2 : -1))
                     : (dw == 0 ? 1 : (dw == -1 ? 3 : -1));
        if (kh >= 0 && kw >= 0)
            v = w[((ci*3 + co)*4 + kh)*4 + kw];
    }
    o[i] = f2bf(v);
}

// ---------------- scalars ----------------
__global__ void finalize_k(const float* __restrict__ counts, const float* __restrict__ sse,
                           float* __restrict__ out_head, float* __restrict__ out_tail)
{
    __shared__ float red[512];
    int t = threadIdx.x;
    float pr = counts[t] / 65536.0f;
    red[t] = -pr * log2f(pr + 1e-10f);
    __syncthreads();
    for (int s = 256; s > 0; s >>= 1) {
        if (t < s) red[t] += red[t + s];
        __syncthreads();
    }
    if (t == 0) {
        float entropy = red[0];
        float mse = sse[0] / 4194304.0f;
        out_head[0] = 1.25f * mse;
        out_tail[0] = mse;
        out_tail[1] = mse;
        out_tail[2] = exp2f(entropy);
    }
}

__global__ void zero_k(float* __restrict__ p, int n)
{
    int i = blockIdx.x * 256 + threadIdx.x;
    if (i < n) p[i] = 0.0f;
}

// ---------------------------------------------------------------------------
extern "C" void kernel_launch(void* const* d_in, const int* in_sizes, int n_in,
                              void* d_out, int out_size, void* d_ws, size_t ws_size,
                              hipStream_t stream)
{
    const float* x         = (const float*)d_in[0];
    const float* enc_w1    = (const float*)d_in[1];
    const float* enc_b1    = (const float*)d_in[2];
    const float* enc_w2    = (const float*)d_in[3];
    const float* enc_b2    = (const float*)d_in[4];
    const float* enc_w3    = (const float*)d_in[5];
    const float* enc_b3    = (const float*)d_in[6];
    const float* enc_w4    = (const float*)d_in[7];
    const float* enc_b4    = (const float*)d_in[8];
    const float* enc_res_w1= (const float*)d_in[9];
    const float* enc_res_w2= (const float*)d_in[10];
    const float* enc_adj_w = (const float*)d_in[11];
    const float* enc_adj_b = (const float*)d_in[12];
    const float* Ecb       = (const float*)d_in[13];
    const float* dec_adj_w = (const float*)d_in[14];
    const float* dec_adj_b = (const float*)d_in[15];
    const float* dec_res_w1= (const float*)d_in[16];
    const float* dec_res_w2= (const float*)d_in[17];
    const float* tc1_w     = (const float*)d_in[18];
    const float* tc1_b     = (const float*)d_in[19];
    const float* tc2_w     = (const float*)d_in[20];
    const float* tc2_b     = (const float*)d_in[21];

    char* wsb = (char*)d_ws;
    u16*   wc2   = (u16*)(wsb + 0);
    u16*   wc3   = (u16*)(wsb + 262144);
    u16*   wc4   = (u16*)(wsb + 557056);
    u16*   wer1  = (u16*)(wsb + 851968);
    u16*   wer2  = (u16*)(wsb + 1146880);
    u16*   weadj = (u16*)(wsb + 1179648);
    u16*   wdadj = (u16*)(wsb + 1196032);
    u16*   wdr1  = (u16*)(wsb + 1343488);
    u16*   wdr2  = (u16*)(wsb + 1638400);
    u16*   wtc1  = (u16*)(wsb + 1671168);
    u16*   wtc2b = (u16*)(wsb + 1933312);
    float* counts= (float*)(wsb + 1951744);
    float* sse   = counts + 512;
    u16*   Ebf   = (u16*)(wsb + 1955840);
    float* enorm1= (float*)(wsb + 2021376);
    u16*   H1    = (u16*)(wsb + 2097152);
    u16*   TR    = (u16*)(wsb + 35651584);
    u16*   H3    = (u16*)(wsb + 52428800);
    u16*   MID   = (u16*)(wsb + 69206016);
    u16*   ZE    = (u16*)(wsb + 77594624);
    u16*   ZQ    = (u16*)(wsb + 85983232);
    u16*   IDX   = (u16*)(wsb + 94371840);
    u16*   TC1O  = H1;

    float* out  = (float*)d_out;
    float* xrec = out + 1;
    float* tail = out + 1 + 3145728;

    Taps t3x3; t3x3.s = 1; t3x3.ntaps = 9;
    for (int kh = 0; kh < 3; ++kh) for (int kw = 0; kw < 3; ++kw) {
        t3x3.dh[kh*3+kw] = kh - 1; t3x3.dw[kh*3+kw] = kw - 1;
    }
    Taps t1x1; t1x1.s = 1; t1x1.ntaps = 1; t1x1.dh[0] = 0; t1x1.dw[0] = 0;
    Taps t4x4; t4x4.s = 2; t4x4.ntaps = 16;
    for (int kh = 0; kh < 4; ++kh) for (int kw = 0; kw < 4; ++kw) {
        t4x4.dh[kh*4+kw] = kh - 1; t4x4.dw[kh*4+kw] = kw - 1;
    }
    const int dtab[2][2] = {{0, -1}, {1, 0}};
    Taps ttc1[4];
    for (int p = 0; p < 4; ++p) {
        ttc1[p].s = 1; ttc1[p].ntaps = 4;
        for (int a = 0; a < 2; ++a) for (int bb = 0; bb < 2; ++bb) {
            ttc1[p].dh[a*2+bb] = dtab[p>>1][a];
            ttc1[p].dw[a*2+bb] = dtab[p&1][bb];
        }
    }

    // ---- weight transforms + sse zero ----
    zero_k<<<1, 256, 0, stream>>>(sse, 1);
    wconv_tf_k<<<512, 256, 0, stream>>>(enc_w2, wc2, 128, 64, 16, 131072);
    wconv_tf_k<<<576, 256, 0, stream>>>(enc_w3, wc3, 128, 128, 9, 147456);
    wconv_tf_k<<<576, 256, 0, stream>>>(enc_w4, wc4, 128, 128, 9, 147456);
    for (int i = 0; i < 2; ++i) {
        wconv_tf_k<<<288, 256, 0, stream>>>(enc_res_w1 + i*73728, wer1 + i*73728, 64, 128, 9, 73728);
        wconv_tf_k<<<32,  256, 0, stream>>>(enc_res_w2 + i*8192,  wer2 + i*8192,  128, 64, 1, 8192);
        wconv_tf_k<<<288, 256, 0, stream>>>(dec_res_w1 + i*73728, wdr1 + i*73728, 64, 128, 9, 73728);
        wconv_tf_k<<<32,  256, 0, stream>>>(dec_res_w2 + i*8192,  wdr2 + i*8192,  128, 64, 1, 8192);
    }
    wconv_tf_k<<<32,  256, 0, stream>>>(enc_adj_w, weadj, 64, 128, 1, 8192);
    wconv_tf_k<<<288, 256, 0, stream>>>(dec_adj_w, wdadj, 128, 64, 9, 73728);
    wtc1_tf_k<<<512, 256, 0, stream>>>(tc1_w, wtc1);
    wtc2b_tf_k<<<36, 256, 0, stream>>>(tc2_w, wtc2b);
    eprep_k<<<2, 256, 0, stream>>>(Ecb, Ebf, enorm1);

    // ---- encoder ----
    conv1_k<<<1024, 256, 0, stream>>>(x, enc_w1, enc_b1, H1);
    mfma_conv_k<64,128,false,true,true,false><<<512, 256, 0, stream>>>
        (H1, wc2, enc_b2, TR, 64, 64, 32, 32, 1, 0, 0, t4x4);
    mfma_conv_k<128,128,false,true,true,false><<<512, 256, 0, stream>>>
        (TR, wc3, enc_b3, H3, 32, 32, 32, 32, 1, 0, 0, t3x3);
    mfma_conv_k<128,128,false,false,true,false><<<512, 256, 0, stream>>>
        (H3, wc4, enc_b4, TR, 32, 32, 32, 32, 1, 0, 0, t3x3);
    for (int i = 0; i < 2; ++i) {
        mfma_conv_k<128,64,true,false,false,false><<<512, 256, 0, stream>>>
            (TR, wer1 + i*73728, nullptr, MID, 32, 32, 32, 32, 1, 0, 0, t3x3);
        mfma_conv_k<64,128,true,false,false,true><<<512, 256, 0, stream>>>
            (MID, wer2 + i*8192, nullptr, TR, 32, 32, 32, 32, 1, 0, 0, t1x1);
    }
    mfma_conv_k<128,64,true,false,true,false><<<512, 256, 0, stream>>>
        (TR, weadj, enc_adj_b, ZE, 32, 32, 32, 32, 1, 0, 0, t1x1);

    // ---- VQ ----
    vq_mfma_k<<<512, 256, 0, stream>>>(ZE, Ebf, enorm1, ZQ, IDX, sse);
    hist_k<<<512, 256, 0, stream>>>(IDX, counts);

    // ---- decoder ----
    mfma_conv_k<64,128,false,false,true,false><<<512, 256, 0, stream>>>
        (ZQ, wdadj, dec_adj_b, H3, 32, 32, 32, 32, 1, 0, 0, t3x3);
    for (int i = 0; i < 2; ++i) {
        mfma_conv_k<128,64,true,false,false,false><<<512, 256, 0, stream>>>
            (H3, wdr1 + i*73728, nullptr, MID, 32, 32, 32, 32, 1, 0, 0, t3x3);
        mfma_conv_k<64,128,true,false,false,true><<<512, 256, 0, stream>>>
            (MID, wdr2 + i*8192, nullptr, H3, 32, 32, 32, 32, 1, 0, 0, t1x1);
    }
    for (int p = 0; p < 4; ++p) {
        mfma_conv_k<128,64,true,true,true,false><<<512, 256, 0, stream>>>
            (H3, wtc1 + p*32768, tc1_b, TC1O, 32, 32, 64, 64, 2, p>>1, p&1, ttc1[p]);
    }
    tc2_mfma_k<<<2048, 256, 0, stream>>>(TC1O, wtc2b, tc2_b, xrec);

    // ---- scalars ----
    finalize_k<<<1, 512, 0, stream>>>(counts, sse, out, tail);
}

// Round 9
// 623.846 us; speedup vs baseline: 1.1521x; 1.1521x over previous
//
#include <hip/hip_runtime.h>
#include <math.h>

// ---------------------------------------------------------------------------
// VQ-VAE forward: NHWC bf16 trunk, implicit-GEMM MFMA convs (fp32 accum,
// BK=32/LDA=40 — r8's BK=64 regressed: bank conflicts + occupancy loss),
// LDS-staged packed-key MFMA VQ, MFMA tc2, weight-stationary conv1.
//
// Workspace layout (bytes):
//   [0 .. ~2.0MB)   transformed weights + counts/sse + Ebf + enorm1
//   H1  = 2097152   (64,64,64,64)  NHWC bf16  33.5MB   h1, later tc1 out
//   TR  = 35651584  (64,32,32,128) NHWC bf16  16.8MB   enc trunk
//   H3  = 52428800  (64,32,32,128) NHWC bf16  16.8MB   h3, later dec trunk
//   MID = 69206016  (64,32,32,64)  NHWC bf16   8.4MB   res mid
//   ZE  = 77594624  (64,32,32,64)  NHWC bf16   8.4MB
//   ZQ  = 85983232  (64,32,32,64)  NHWC bf16   8.4MB
//   IDX = 94371840  65536 u16      128KB
// ---------------------------------------------------------------------------

typedef unsigned short u16;
typedef __attribute__((ext_vector_type(8))) short bf16x8;
typedef __attribute__((ext_vector_type(4))) float f32x4;

__device__ __forceinline__ float bf2f(u16 h) {
    union { unsigned u; float f; } v; v.u = ((unsigned)h) << 16; return v.f;
}
__device__ __forceinline__ u16 f2bf(float f) {
    union { float f; unsigned u; } v; v.f = f;
    unsigned r = v.u + 0x7FFFu + ((v.u >> 16) & 1u);
    return (u16)(r >> 16);
}
__device__ __forceinline__ unsigned relu2(unsigned x) {
    return x & ~(((x & 0x80008000u) >> 15) * 0xFFFFu);
}

struct Taps { int s; int ntaps; int dh[16]; int dw[16]; };

// ---------------- unified implicit-GEMM MFMA conv (BK=32, LDA=40) ----------
// // BK=32/LDA=40: r8 tried BK=64/LDA=72 -> 2.36M LDS bank conflicts (36-dword
// // row stride, 8-way alias) + 36KB LDS halved blocks/CU; 79us vs 28us. Keep.
template<int CIN, int COUT, bool RELU_IN, bool RELU_OUT, bool HAS_BIAS, bool RESID>
__global__ __launch_bounds__(256)
void mfma_conv_k(const u16* __restrict__ in, const u16* __restrict__ wT,
                 const float* __restrict__ bias, u16* __restrict__ out,
                 int Hin, int Win, int Hout, int Wout, int OS, int OPH, int OPW,
                 Taps taps)
{
    constexpr int WN = (COUT == 128) ? 2 : 1;
    constexpr int WM = 4 / WN;
    constexpr int TM = (128 / WM) / 16;
    constexpr int TN = (COUT / WN) / 16;
    constexpr int LDA = 40;  // 32 data + 8 pad

    __shared__ alignas(16) u16 aT[128 * LDA];
    __shared__ alignas(16) u16 bT[COUT * LDA];

    const int tid = threadIdx.x;
    const int m0 = blockIdx.x * 128;
    const int n_img = m0 >> 10;
    const int pixbase = m0 & 1023;

    const int r = tid >> 1, half = tid & 1;
    const int pr = pixbase + r;
    const int ohr = pr >> 5, owr = pr & 31;
    const u16* inb = in + (size_t)n_img * Hin * Win * CIN;

    const int wv = tid >> 6, lane = tid & 63;
    const int q = lane >> 4, l16 = lane & 15;
    const int wm = wv / WN, wn = wv % WN;
    const int mbase = wm * (TM * 16), cbase = wn * (TN * 16);

    f32x4 acc[TM][TN] = {};

    for (int t = 0; t < taps.ntaps; ++t) {
        const int ih = ohr * taps.s + taps.dh[t];
        const int iw = owr * taps.s + taps.dw[t];
        const bool ok = ((unsigned)ih < (unsigned)Hin) && ((unsigned)iw < (unsigned)Win);
        const u16* asrc = ok ? (inb + ((size_t)ih * Win + iw) * CIN + half * 16) : inb;
        const u16* bsrc = wT + ((size_t)t * COUT + r) * CIN + half * 16;

        for (int c0 = 0; c0 < CIN; c0 += 32) {
            __syncthreads();
            uint4 a0 = {0,0,0,0}, a1 = {0,0,0,0};
            if (ok) {
                a0 = *(const uint4*)(asrc + c0);
                a1 = *(const uint4*)(asrc + c0 + 8);
            }
            if (RELU_IN) {
                a0.x = relu2(a0.x); a0.y = relu2(a0.y); a0.z = relu2(a0.z); a0.w = relu2(a0.w);
                a1.x = relu2(a1.x); a1.y = relu2(a1.y); a1.z = relu2(a1.z); a1.w = relu2(a1.w);
            }
            *(uint4*)&aT[r * LDA + half * 16]     = a0;
            *(uint4*)&aT[r * LDA + half * 16 + 8] = a1;
            if (COUT == 128 || r < COUT) {
                uint4 b0 = *(const uint4*)(bsrc + c0);
                uint4 b1 = *(const uint4*)(bsrc + c0 + 8);
                *(uint4*)&bT[r * LDA + half * 16]     = b0;
                *(uint4*)&bT[r * LDA + half * 16 + 8] = b1;
            }
            __syncthreads();

            bf16x8 afr[TM], bfr[TN];
            #pragma unroll
            for (int tm = 0; tm < TM; ++tm)
                afr[tm] = *(const bf16x8*)&aT[(mbase + tm*16 + l16) * LDA + q * 8];
            #pragma unroll
            for (int tn = 0; tn < TN; ++tn)
                bfr[tn] = *(const bf16x8*)&bT[(cbase + tn*16 + l16) * LDA + q * 8];
            #pragma unroll
            for (int tm = 0; tm < TM; ++tm)
                #pragma unroll
                for (int tn = 0; tn < TN; ++tn)
                    acc[tm][tn] = __builtin_amdgcn_mfma_f32_16x16x32_bf16(
                        afr[tm], bfr[tn], acc[tm][tn], 0, 0, 0);
        }
    }

    #pragma unroll
    for (int tm = 0; tm < TM; ++tm) {
        #pragma unroll
        for (int tn = 0; tn < TN; ++tn) {
            const int col = cbase + tn*16 + l16;
            const float bv = HAS_BIAS ? bias[col] : 0.0f;
            #pragma unroll
            for (int rg = 0; rg < 4; ++rg) {
                const int m = mbase + tm*16 + q*4 + rg;
                const int pix = pixbase + m;
                const int oh = pix >> 5, ow = pix & 31;
                size_t oidx = (((size_t)n_img * Hout + (oh*OS + OPH)) * Wout
                               + (ow*OS + OPW)) * COUT + col;
                float v = acc[tm][tn][rg] + bv;
                if (RESID) v += bf2f(out[oidx]);
                if (RELU_OUT) v = fmaxf(v, 0.0f);
                out[oidx] = f2bf(v);
            }
        }
    }
}

// ---------------- conv1: weight-stationary + LDS-coalesced stores ------------
__global__ __launch_bounds__(256)
void conv1_k(const float* __restrict__ x, const float* __restrict__ w,
             const float* __restrict__ b, u16* __restrict__ out)
{
    constexpr int LDC = 72;
    __shared__ alignas(16) u16 cbuf[256 * LDC];

    int tid = threadIdx.x;
    int gpix = blockIdx.x * 256 + tid;
    int ow = gpix & 63, oh = (gpix >> 6) & 63, n = gpix >> 12;
    const float* xb = x + (size_t)n * 3 * 16384;
    const int ih0 = oh * 2 - 1, iw0 = ow * 2 - 1;

    float xr[48];
    #pragma unroll
    for (int ci = 0; ci < 3; ++ci) {
        #pragma unroll
        for (int kh = 0; kh < 4; ++kh) {
            int ih = ih0 + kh;
            bool rowok = (unsigned)ih < 128u;
            #pragma unroll
            for (int kw = 0; kw < 4; ++kw) {
                int iw = iw0 + kw;
                bool ok = rowok && ((unsigned)iw < 128u);
                xr[ci*16 + kh*4 + kw] = ok ? xb[ci*16384 + ih*128 + iw] : 0.0f;
            }
        }
    }

    #pragma unroll
    for (int cg = 0; cg < 8; ++cg) {
        unsigned pk[4];
        #pragma unroll
        for (int cp = 0; cp < 4; ++cp) {
            const int co = cg*8 + cp*2;
            float a0 = b[co], a1 = b[co + 1];
            const float* w0 = w + co * 48;
            #pragma unroll
            for (int j = 0; j < 48; ++j) {
                a0 = fmaf(xr[j], w0[j],      a0);
                a1 = fmaf(xr[j], w0[48 + j], a1);
            }
            a0 = fmaxf(a0, 0.0f);
            a1 = fmaxf(a1, 0.0f);
            pk[cp] = (unsigned)f2bf(a0) | ((unsigned)f2bf(a1) << 16);
        }
        *(uint4*)&cbuf[tid * LDC + cg * 8] = *(uint4*)pk;
    }
    __syncthreads();

    u16* ob = out + (size_t)blockIdx.x * 256 * 64;
    #pragma unroll
    for (int it = 0; it < 8; ++it) {
        int j = it * 256 + tid;
        uint4 v = *(const uint4*)&cbuf[(j >> 3) * LDC + (j & 7) * 8];
        *(uint4*)(ob + j * 8) = v;
    }
}

// ---------------- tc2 as MFMA parity GEMM ----------------
__global__ __launch_bounds__(256)
void tc2_mfma_k(const u16* __restrict__ in, const u16* __restrict__ wT,
                const float* __restrict__ bias, float* __restrict__ out)
{
    constexpr int LDA = 40;
    __shared__ alignas(16) u16 aT[128 * LDA];
    __shared__ alignas(16) u16 bT[16 * LDA];
    __shared__ float cT[128 * 17];

    const int tid = threadIdx.x;
    const int m0 = blockIdx.x * 128;
    const int n_img = m0 >> 12;
    const int pixbase = m0 & 4095;
    const int y0 = pixbase >> 6;

    const int r = tid >> 1, half = tid & 1;
    const int pr = pixbase + r;
    const int yr = pr >> 6, xr = pr & 63;
    const u16* inb = in + (size_t)n_img * 4096 * 64;

    const int wv = tid >> 6, lane = tid & 63;
    const int q = lane >> 4, l16 = lane & 15;
    const int mbase = wv * 32;

    f32x4 acc[2] = {};

    for (int t = 0; t < 9; ++t) {
        const int ih = yr + t/3 - 1;
        const int iw = xr + t%3 - 1;
        const bool ok = ((unsigned)ih < 64u) && ((unsigned)iw < 64u);
        const u16* asrc = ok ? (inb + ((size_t)ih * 64 + iw) * 64 + half * 16) : inb;
        const u16* bsrc = wT + ((size_t)t * 16 + r) * 64 + half * 16;

        for (int c0 = 0; c0 < 64; c0 += 32) {
            __syncthreads();
            uint4 a0 = {0,0,0,0}, a1 = {0,0,0,0};
            if (ok) {
                a0 = *(const uint4*)(asrc + c0);
                a1 = *(const uint4*)(asrc + c0 + 8);
            }
            *(uint4*)&aT[r * LDA + half * 16]     = a0;
            *(uint4*)&aT[r * LDA + half * 16 + 8] = a1;
            if (r < 16) {
                *(uint4*)&bT[r * LDA + half * 16]     = *(const uint4*)(bsrc + c0);
                *(uint4*)&bT[r * LDA + half * 16 + 8] = *(const uint4*)(bsrc + c0 + 8);
            }
            __syncthreads();

            bf16x8 af0 = *(const bf16x8*)&aT[(mbase + l16) * LDA + q * 8];
            bf16x8 af1 = *(const bf16x8*)&aT[(mbase + 16 + l16) * LDA + q * 8];
            bf16x8 bf  = *(const bf16x8*)&bT[l16 * LDA + q * 8];
            acc[0] = __builtin_amdgcn_mfma_f32_16x16x32_bf16(af0, bf, acc[0], 0, 0, 0);
            acc[1] = __builtin_amdgcn_mfma_f32_16x16x32_bf16(af1, bf, acc[1], 0, 0, 0);
        }
    }

    #pragma unroll
    for (int tm = 0; tm < 2; ++tm)
        #pragma unroll
        for (int rg = 0; rg < 4; ++rg)
            cT[(mbase + tm*16 + q*4 + rg) * 17 + l16] = acc[tm][rg];
    __syncthreads();

    #pragma unroll
    for (int it = 0; it < 6; ++it) {
        int j = it * 256 + tid;
        int co  = j >> 9;
        int rem = j & 511;
        int ohl = rem >> 7;
        int ow  = rem & 127;
        int oh  = 2*y0 + ohl;
        int lp  = (ohl >> 1) * 64 + (ow >> 1);
        int col = ((ohl & 1) * 2 + (ow & 1)) * 4 + co;
        float v = cT[lp * 17 + col] + bias[co];
        out[(((size_t)n_img * 3 + co) * 128 + oh) * 128 + ow] = v;
    }
}

// ---------------- VQ: E prep (stores enorm+1 for packed-key trick) ----------
__global__ void eprep_k(const float* __restrict__ E, u16* __restrict__ Ebf,
                        float* __restrict__ enorm1)
{
    int k = blockIdx.x * 256 + threadIdx.x;
    if (k >= 512) return;
    float s = 0.0f;
    #pragma unroll
    for (int d = 0; d < 64; ++d) {
        u16 h = f2bf(E[k*64 + d]);
        Ebf[k*64 + d] = h;
        float v = bf2f(h);
        s = fmaf(v, v, s);
    }
    enorm1[k] = s + 1.0f;
}

// ---------------- MFMA vector quantizer: LDS codebook + packed-key argmin ----
__global__ __launch_bounds__(256)
void vq_mfma_k(const u16* __restrict__ Ze, const u16* __restrict__ Ebf,
               const float* __restrict__ enorm1, u16* __restrict__ Zq,
               u16* __restrict__ idx_out, float* __restrict__ sse)
{
    __shared__ alignas(16) u16 eld[256 * 72];
    __shared__ float en1s[256];
    __shared__ int bestk_s[128];
    __shared__ float red[256];

    const int tid = threadIdx.x;
    const int lane = tid & 63, wv = tid >> 6;
    const int q = lane >> 4, l16 = lane & 15;
    const int pb = blockIdx.x * 128 + wv * 32;

    bf16x8 alo[2], ahi[2];
    #pragma unroll
    for (int tile = 0; tile < 2; ++tile) {
        const u16* zp = Ze + (size_t)(pb + tile*16 + l16) * 64;
        alo[tile] = *(const bf16x8*)(zp + q * 8);
        ahi[tile] = *(const bf16x8*)(zp + 32 + q * 8);
    }

    unsigned key[2][4] = {{0xFFFFFFFFu,0xFFFFFFFFu,0xFFFFFFFFu,0xFFFFFFFFu},
                          {0xFFFFFFFFu,0xFFFFFFFFu,0xFFFFFFFFu,0xFFFFFFFFu}};

    for (int k0 = 0; k0 < 512; k0 += 256) {
        __syncthreads();
        const uint4* src = (const uint4*)(Ebf + k0 * 64);
        #pragma unroll
        for (int i = tid; i < 2048; i += 256) {
            int row = i >> 3, sub = i & 7;
            *(uint4*)&eld[row * 72 + sub * 8] = src[i];
        }
        en1s[tid] = enorm1[k0 + tid];
        __syncthreads();

        for (int t = 0; t < 16; ++t) {
            const int nl = t * 16 + l16;
            bf16x8 b0 = *(const bf16x8*)&eld[nl * 72 + q * 8];
            bf16x8 b1 = *(const bf16x8*)&eld[nl * 72 + 32 + q * 8];
            const float en1 = en1s[nl];
            const unsigned ng = (unsigned)(k0 + nl);
            #pragma unroll
            for (int tile = 0; tile < 2; ++tile) {
                f32x4 acc = {0.0f, 0.0f, 0.0f, 0.0f};
                acc = __builtin_amdgcn_mfma_f32_16x16x32_bf16(alo[tile], b0, acc, 0, 0, 0);
                acc = __builtin_amdgcn_mfma_f32_16x16x32_bf16(ahi[tile], b1, acc, 0, 0, 0);
                #pragma unroll
                for (int rg = 0; rg < 4; ++rg) {
                    float sc = fmaf(acc[rg], -2.0f, en1);
                    unsigned kk2 = (__float_as_uint(sc) & 0xFFFFFE00u) | ng;
                    key[tile][rg] = min(key[tile][rg], kk2);
                }
            }
        }
    }

    #pragma unroll
    for (int m = 1; m < 16; m <<= 1) {
        #pragma unroll
        for (int tile = 0; tile < 2; ++tile)
            #pragma unroll
            for (int rg = 0; rg < 4; ++rg) {
                unsigned o = (unsigned)__shfl_xor((int)key[tile][rg], m, 64);
                key[tile][rg] = min(key[tile][rg], o);
            }
    }
    if (l16 == 0) {
        #pragma unroll
        for (int tile = 0; tile < 2; ++tile)
            #pragma unroll
            for (int rg = 0; rg < 4; ++rg)
                bestk_s[wv * 32 + tile * 16 + q * 4 + rg] = (int)(key[tile][rg] & 511u);
    }
    __syncthreads();

    const int pos = tid >> 1, seg = tid & 1;
    const int p = blockIdx.x * 128 + pos;
    const int k = bestk_s[pos];
    const u16* ep = Ebf + (size_t)k * 64 + seg * 32;
    const u16* zp = Ze + (size_t)p * 64 + seg * 32;
    u16* qp = Zq + (size_t)p * 64 + seg * 32;
    float local = 0.0f;
    #pragma unroll
    for (int h = 0; h < 4; ++h) {
        uint4 ev = *(const uint4*)(ep + h * 8);
        uint4 zv = *(const uint4*)(zp + h * 8);
        *(uint4*)(qp + h * 8) = ev;
        unsigned ea[4] = {ev.x, ev.y, ev.z, ev.w};
        unsigned za[4] = {zv.x, zv.y, zv.z, zv.w};
        #pragma unroll
        for (int j = 0; j < 4; ++j) {
            float d0 = bf2f((u16)(ea[j] & 0xFFFFu)) - bf2f((u16)(za[j] & 0xFFFFu));
            float d1 = bf2f((u16)(ea[j] >> 16))     - bf2f((u16)(za[j] >> 16));
            local = fmaf(d0, d0, fmaf(d1, d1, local));
        }
    }
    if (seg == 0) idx_out[p] = (u16)k;
    red[tid] = local;
    __syncthreads();
    for (int s = 128; s > 0; s >>= 1) {
        if (tid < s) red[tid] += red[tid + s];
        __syncthreads();
    }
    if (tid == 0) atomicAdd(sse, red[0]);
}

// ---------------- histogram by scan: block k counts code k ----------------
__global__ __launch_bounds__(256)
void hist_k(const u16* __restrict__ idx, float* __restrict__ counts)
{
    __shared__ int red[256];
    const int k = blockIdx.x;
    const int tid = threadIdx.x;
    int c = 0;
    const uint4* p4 = (const uint4*)idx;
    for (int i = tid; i < 8192; i += 256) {
        uint4 v = p4[i];
        unsigned ua[4] = {v.x, v.y, v.z, v.w};
        #pragma unroll
        for (int j = 0; j < 4; ++j) {
            c += ((ua[j] & 0xFFFFu) == (unsigned)k);
            c += ((ua[j] >> 16)     == (unsigned)k);
        }
    }
    red[tid] = c;
    __syncthreads();
    for (int s = 128; s > 0; s >>= 1) {
        if (tid < s) red[tid] += red[tid + s];
        __syncthreads();
    }
    if (tid == 0) counts[k] = (float)red[0];
}

// ---------------- weight transforms ----------------
__global__ void wconv_tf_k(const float* __restrict__ w, u16* __restrict__ o,
                           int COUT, int CIN, int KK, int total)
{
    int i = blockIdx.x * 256 + threadIdx.x;
    if (i >= total) return;
    int ci = i % CIN; int t = i / CIN; int co = t % COUT; t /= COUT;
    o[i] = f2bf(w[(co*CIN + ci)*KK + t]);
}
__global__ void wtc1_tf_k(const float* __restrict__ w, u16* __restrict__ o)
{
    int i = blockIdx.x * 256 + threadIdx.x;
    if (i >= 131072) return;
    int ci = i & 127; int co = (i >> 7) & 63; int t = (i >> 13) & 3; int p = i >> 15;
    int poh = p >> 1, pw = p & 1; int a = t >> 1, bb = t & 1;
    int kh = poh ? (a ? 2 : 0) : (a ? 3 : 1);
    int kw = pw  ? (bb ? 2 : 0) : (bb ? 3 : 1);
    o[i] = f2bf(w[((ci*64 + co)*4 + kh)*4 + kw]);
}
__global__ void wtc2b_tf_k(const float* __restrict__ w, u16* __restrict__ o)
{
    int i = blockIdx.x * 256 + threadIdx.x;   // 9216
    if (i >= 9216) return;
    int ci = i & 63; int col = (i >> 6) & 15; int t = i >> 10;
    int dh = t / 3 - 1, dw = t % 3 - 1;
    int pp = col >> 2, co = col & 3;
    float v = 0.0f;
    if (co < 3) {
        int poh = pp >> 1, pw = pp & 1;
        int kh = poh ? (dh == 1 ? 0 : (dh == 0 ? 2 : -1))
                     : (dh == 0 ? 1 : (dh == -1 ? 3 : -1));
        int kw = pw  ? (dw == 1 ? 0 : (dw == 0 ? 2 : -1))
                     : (dw == 0 ? 1 : (dw == -1 ? 3 : -1));
        if (kh >= 0 && kw >= 0)
            v = w[((ci*3 + co)*4 + kh)*4 + kw];
    }
    o[i] = f2bf(v);
}

// ---------------- scalars ----------------
__global__ void finalize_k(const float* __restrict__ counts, const float* __restrict__ sse,
                           float* __restrict__ out_head, float* __restrict__ out_tail)
{
    __shared__ float red[512];
    int t = threadIdx.x;
    float pr = counts[t] / 65536.0f;
    red[t] = -pr * log2f(pr + 1e-10f);
    __syncthreads();
    for (int s = 256; s > 0; s >>= 1) {
        if (t < s) red[t] += red[t + s];
        __syncthreads();
    }
    if (t == 0) {
        float entropy = red[0];
        float mse = sse[0] / 4194304.0f;
        out_head[0] = 1.25f * mse;
        out_tail[0] = mse;
        out_tail[1] = mse;
        out_tail[2] = exp2f(entropy);
    }
}

__global__ void zero_k(float* __restrict__ p, int n)
{
    int i = blockIdx.x * 256 + threadIdx.x;
    if (i < n) p[i] = 0.0f;
}

// ---------------------------------------------------------------------------
extern "C" void kernel_launch(void* const* d_in, const int* in_sizes, int n_in,
                              void* d_out, int out_size, void* d_ws, size_t ws_size,
                              hipStream_t stream)
{
    const float* x         = (const float*)d_in[0];
    const float* enc_w1    = (const float*)d_in[1];
    const float* enc_b1    = (const float*)d_in[2];
    const float* enc_w2    = (const float*)d_in[3];
    const float* enc_b2    = (const float*)d_in[4];
    const float* enc_w3    = (const float*)d_in[5];
    const float* enc_b3    = (const float*)d_in[6];
    const float* enc_w4    = (const float*)d_in[7];
    const float* enc_b4    = (const float*)d_in[8];
    const float* enc_res_w1= (const float*)d_in[9];
    const float* enc_res_w2= (const float*)d_in[10];
    const float* enc_adj_w = (const float*)d_in[11];
    const float* enc_adj_b = (const float*)d_in[12];
    const float* Ecb       = (const float*)d_in[13];
    const float* dec_adj_w = (const float*)d_in[14];
    const float* dec_adj_b = (const float*)d_in[15];
    const float* dec_res_w1= (const float*)d_in[16];
    const float* dec_res_w2= (const float*)d_in[17];
    const float* tc1_w     = (const float*)d_in[18];
    const float* tc1_b     = (const float*)d_in[19];
    const float* tc2_w     = (const float*)d_in[20];
    const float* tc2_b     = (const float*)d_in[21];

    char* wsb = (char*)d_ws;
    u16*   wc2   = (u16*)(wsb + 0);
    u16*   wc3   = (u16*)(wsb + 262144);
    u16*   wc4   = (u16*)(wsb + 557056);
    u16*   wer1  = (u16*)(wsb + 851968);
    u16*   wer2  = (u16*)(wsb + 1146880);
    u16*   weadj = (u16*)(wsb + 1179648);
    u16*   wdadj = (u16*)(wsb + 1196032);
    u16*   wdr1  = (u16*)(wsb + 1343488);
    u16*   wdr2  = (u16*)(wsb + 1638400);
    u16*   wtc1  = (u16*)(wsb + 1671168);
    u16*   wtc2b = (u16*)(wsb + 1933312);
    float* counts= (float*)(wsb + 1951744);
    float* sse   = counts + 512;
    u16*   Ebf   = (u16*)(wsb + 1955840);
    float* enorm1= (float*)(wsb + 2021376);
    u16*   H1    = (u16*)(wsb + 2097152);
    u16*   TR    = (u16*)(wsb + 35651584);
    u16*   H3    = (u16*)(wsb + 52428800);
    u16*   MID   = (u16*)(wsb + 69206016);
    u16*   ZE    = (u16*)(wsb + 77594624);
    u16*   ZQ    = (u16*)(wsb + 85983232);
    u16*   IDX   = (u16*)(wsb + 94371840);
    u16*   TC1O  = H1;

    float* out  = (float*)d_out;
    float* xrec = out + 1;
    float* tail = out + 1 + 3145728;

    Taps t3x3; t3x3.s = 1; t3x3.ntaps = 9;
    for (int kh = 0; kh < 3; ++kh) for (int kw = 0; kw < 3; ++kw) {
        t3x3.dh[kh*3+kw] = kh - 1; t3x3.dw[kh*3+kw] = kw - 1;
    }
    Taps t1x1; t1x1.s = 1; t1x1.ntaps = 1; t1x1.dh[0] = 0; t1x1.dw[0] = 0;
    Taps t4x4; t4x4.s = 2; t4x4.ntaps = 16;
    for (int kh = 0; kh < 4; ++kh) for (int kw = 0; kw < 4; ++kw) {
        t4x4.dh[kh*4+kw] = kh - 1; t4x4.dw[kh*4+kw] = kw - 1;
    }
    const int dtab[2][2] = {{0, -1}, {1, 0}};
    Taps ttc1[4];
    for (int p = 0; p < 4; ++p) {
        ttc1[p].s = 1; ttc1[p].ntaps = 4;
        for (int a = 0; a < 2; ++a) for (int bb = 0; bb < 2; ++bb) {
            ttc1[p].dh[a*2+bb] = dtab[p>>1][a];
            ttc1[p].dw[a*2+bb] = dtab[p&1][bb];
        }
    }

    // ---- weight transforms + sse zero ----
    zero_k<<<1, 256, 0, stream>>>(sse, 1);
    wconv_tf_k<<<512, 256, 0, stream>>>(enc_w2, wc2, 128, 64, 16, 131072);
    wconv_tf_k<<<576, 256, 0, stream>>>(enc_w3, wc3, 128, 128, 9, 147456);
    wconv_tf_k<<<576, 256, 0, stream>>>(enc_w4, wc4, 128, 128, 9, 147456);
    for (int i = 0; i < 2; ++i) {
        wconv_tf_k<<<288, 256, 0, stream>>>(enc_res_w1 + i*73728, wer1 + i*73728, 64, 128, 9, 73728);
        wconv_tf_k<<<32,  256, 0, stream>>>(enc_res_w2 + i*8192,  wer2 + i*8192,  128, 64, 1, 8192);
        wconv_tf_k<<<288, 256, 0, stream>>>(dec_res_w1 + i*73728, wdr1 + i*73728, 64, 128, 9, 73728);
        wconv_tf_k<<<32,  256, 0, stream>>>(dec_res_w2 + i*8192,  wdr2 + i*8192,  128, 64, 1, 8192);
    }
    wconv_tf_k<<<32,  256, 0, stream>>>(enc_adj_w, weadj, 64, 128, 1, 8192);
    wconv_tf_k<<<288, 256, 0, stream>>>(dec_adj_w, wdadj, 128, 64, 9, 73728);
    wtc1_tf_k<<<512, 256, 0, stream>>>(tc1_w, wtc1);
    wtc2b_tf_k<<<36, 256, 0, stream>>>(tc2_w, wtc2b);
    eprep_k<<<2, 256, 0, stream>>>(Ecb, Ebf, enorm1);

    // ---- encoder ----
    conv1_k<<<1024, 256, 0, stream>>>(x, enc_w1, enc_b1, H1);
    mfma_conv_k<64,128,false,true,true,false><<<512, 256, 0, stream>>>
        (H1, wc2, enc_b2, TR, 64, 64, 32, 32, 1, 0, 0, t4x4);
    mfma_conv_k<128,128,false,true,true,false><<<512, 256, 0, stream>>>
        (TR, wc3, enc_b3, H3, 32, 32, 32, 32, 1, 0, 0, t3x3);
    mfma_conv_k<128,128,false,false,true,false><<<512, 256, 0, stream>>>
        (H3, wc4, enc_b4, TR, 32, 32, 32, 32, 1, 0, 0, t3x3);
    for (int i = 0; i < 2; ++i) {
        mfma_conv_k<128,64,true,false,false,false><<<512, 256, 0, stream>>>
            (TR, wer1 + i*73728, nullptr, MID, 32, 32, 32, 32, 1, 0, 0, t3x3);
        mfma_conv_k<64,128,true,false,false,true><<<512, 256, 0, stream>>>
            (MID, wer2 + i*8192, nullptr, TR, 32, 32, 32, 32, 1, 0, 0, t1x1);
    }
    mfma_conv_k<128,64,true,false,true,false><<<512, 256, 0, stream>>>
        (TR, weadj, enc_adj_b, ZE, 32, 32, 32, 32, 1, 0, 0, t1x1);

    // ---- VQ ----
    vq_mfma_k<<<512, 256, 0, stream>>>(ZE, Ebf, enorm1, ZQ, IDX, sse);
    hist_k<<<512, 256, 0, stream>>>(IDX, counts);

    // ---- decoder ----
    mfma_conv_k<64,128,false,false,true,false><<<512, 256, 0, stream>>>
        (ZQ, wdadj, dec_adj_b, H3, 32, 32, 32, 32, 1, 0, 0, t3x3);
    for (int i = 0; i < 2; ++i) {
        mfma_conv_k<128,64,true,false,false,false><<<512, 256, 0, stream>>>
            (H3, wdr1 + i*73728, nullptr, MID, 32, 32, 32, 32, 1, 0, 0, t3x3);
        mfma_conv_k<64,128,true,false,false,true><<<512, 256, 0, stream>>>
            (MID, wdr2 + i*8192, nullptr, H3, 32, 32, 32, 32, 1, 0, 0, t1x1);
    }
    for (int p = 0; p < 4; ++p) {
        mfma_conv_k<128,64,true,true,true,false><<<512, 256, 0, stream>>>
            (H3, wtc1 + p*32768, tc1_b, TC1O, 32, 32, 64, 64, 2, p>>1, p&1, ttc1[p]);
    }
    tc2_mfma_k<<<2048, 256, 0, stream>>>(TC1O, wtc2b, tc2_b, xrec);

    // ---- scalars ----
    finalize_k<<<1, 512, 0, stream>>>(counts, sse, out, tail);
}

// Round 10
// 559.509 us; speedup vs baseline: 1.2846x; 1.1150x over previous
//
#include <hip/hip_runtime.h>
#include <math.h>

// ---------------------------------------------------------------------------
// VQ-VAE forward: NHWC bf16 trunk, implicit-GEMM MFMA convs (fp32 accum,
// BK=32/LDA=40, software-pipelined K-loop: iter i+1's global loads issued
// before iter i's MFMAs), LDS-staged packed-key MFMA VQ, MFMA tc2,
// weight-stationary conv1, single merged prep dispatch.
//
// Workspace layout (bytes):
//   [0 .. ~2.0MB)   transformed weights + counts/sse + Ebf + enorm1
//   H1  = 2097152   (64,64,64,64)  NHWC bf16  33.5MB   h1, later tc1 out
//   TR  = 35651584  (64,32,32,128) NHWC bf16  16.8MB   enc trunk
//   H3  = 52428800  (64,32,32,128) NHWC bf16  16.8MB   h3, later dec trunk
//   MID = 69206016  (64,32,32,64)  NHWC bf16   8.4MB   res mid
//   ZE  = 77594624  (64,32,32,64)  NHWC bf16   8.4MB
//   ZQ  = 85983232  (64,32,32,64)  NHWC bf16   8.4MB
//   IDX = 94371840  65536 u16      128KB
// ---------------------------------------------------------------------------

typedef unsigned short u16;
typedef __attribute__((ext_vector_type(8))) short bf16x8;
typedef __attribute__((ext_vector_type(4))) float f32x4;

__device__ __forceinline__ float bf2f(u16 h) {
    union { unsigned u; float f; } v; v.u = ((unsigned)h) << 16; return v.f;
}
__device__ __forceinline__ u16 f2bf(float f) {
    union { float f; unsigned u; } v; v.f = f;
    unsigned r = v.u + 0x7FFFu + ((v.u >> 16) & 1u);
    return (u16)(r >> 16);
}
__device__ __forceinline__ unsigned relu2(unsigned x) {
    return x & ~(((x & 0x80008000u) >> 15) * 0xFFFFu);
}

struct Taps { int s; int ntaps; int dh[16]; int dw[16]; };

// ---------------- unified implicit-GEMM MFMA conv (BK=32, LDA=40) ----------
// BK=32/LDA=40: r8's BK=64/LDA=72 regressed (2.36M LDS bank conflicts +
// occupancy loss). r10: flattened (tap,chunk) loop with register prefetch of
// the NEXT iteration's A/B global loads issued before this iter's MFMAs, so
// L2 latency overlaps compute instead of being exposed per barrier-pair.
template<int CIN, int COUT, bool RELU_IN, bool RELU_OUT, bool HAS_BIAS, bool RESID>
__global__ __launch_bounds__(256)
void mfma_conv_k(const u16* __restrict__ in, const u16* __restrict__ wT,
                 const float* __restrict__ bias, u16* __restrict__ out,
                 int Hin, int Win, int Hout, int Wout, int OS, int OPH, int OPW,
                 Taps taps)
{
    constexpr int WN = (COUT == 128) ? 2 : 1;
    constexpr int WM = 4 / WN;
    constexpr int TM = (128 / WM) / 16;
    constexpr int TN = (COUT / WN) / 16;
    constexpr int LDA = 40;      // 32 data + 8 pad
    constexpr int NCH = CIN / 32;

    __shared__ alignas(16) u16 aT[128 * LDA];
    __shared__ alignas(16) u16 bT[COUT * LDA];

    const int tid = threadIdx.x;
    const int m0 = blockIdx.x * 128;
    const int n_img = m0 >> 10;
    const int pixbase = m0 & 1023;

    const int r = tid >> 1, half = tid & 1;
    const int pr = pixbase + r;
    const int ohr = pr >> 5, owr = pr & 31;
    const u16* inb = in + (size_t)n_img * Hin * Win * CIN;

    const int wv = tid >> 6, lane = tid & 63;
    const int q = lane >> 4, l16 = lane & 15;
    const int wm = wv / WN, wn = wv % WN;
    const int mbase = wm * (TM * 16), cbase = wn * (TN * 16);
    const bool bload = (COUT == 128) || (r < COUT);

    f32x4 acc[TM][TN] = {};

    const int total_it = taps.ntaps * NCH;
    uint4 pa0, pa1, pb0 = {0,0,0,0}, pb1 = {0,0,0,0};

#define LOAD_IT(IT) do {                                                        \
        int t_ = (IT) / NCH, cc_ = ((IT) % NCH) * 32;                           \
        int ih_ = ohr * taps.s + taps.dh[t_];                                   \
        int iw_ = owr * taps.s + taps.dw[t_];                                   \
        bool ok_ = ((unsigned)ih_ < (unsigned)Hin) &&                           \
                   ((unsigned)iw_ < (unsigned)Win);                             \
        pa0 = (uint4){0,0,0,0}; pa1 = (uint4){0,0,0,0};                         \
        if (ok_) {                                                              \
            const u16* as_ = inb + ((size_t)ih_ * Win + iw_) * CIN              \
                             + half * 16 + cc_;                                 \
            pa0 = *(const uint4*)(as_);                                         \
            pa1 = *(const uint4*)(as_ + 8);                                     \
        }                                                                       \
        if (bload) {                                                            \
            const u16* bs_ = wT + ((size_t)t_ * COUT + r) * CIN                 \
                             + half * 16 + cc_;                                 \
            pb0 = *(const uint4*)(bs_);                                         \
            pb1 = *(const uint4*)(bs_ + 8);                                     \
        }                                                                       \
    } while (0)

    LOAD_IT(0);

    for (int it = 0; it < total_it; ++it) {
        __syncthreads();
        uint4 a0 = pa0, a1 = pa1;
        if (RELU_IN) {
            a0.x = relu2(a0.x); a0.y = relu2(a0.y); a0.z = relu2(a0.z); a0.w = relu2(a0.w);
            a1.x = relu2(a1.x); a1.y = relu2(a1.y); a1.z = relu2(a1.z); a1.w = relu2(a1.w);
        }
        *(uint4*)&aT[r * LDA + half * 16]     = a0;
        *(uint4*)&aT[r * LDA + half * 16 + 8] = a1;
        if (bload) {
            *(uint4*)&bT[r * LDA + half * 16]     = pb0;
            *(uint4*)&bT[r * LDA + half * 16 + 8] = pb1;
        }
        __syncthreads();
        if (it + 1 < total_it) LOAD_IT(it + 1);   // prefetch overlaps MFMAs below

        bf16x8 afr[TM], bfr[TN];
        #pragma unroll
        for (int tm = 0; tm < TM; ++tm)
            afr[tm] = *(const bf16x8*)&aT[(mbase + tm*16 + l16) * LDA + q * 8];
        #pragma unroll
        for (int tn = 0; tn < TN; ++tn)
            bfr[tn] = *(const bf16x8*)&bT[(cbase + tn*16 + l16) * LDA + q * 8];
        #pragma unroll
        for (int tm = 0; tm < TM; ++tm)
            #pragma unroll
            for (int tn = 0; tn < TN; ++tn)
                acc[tm][tn] = __builtin_amdgcn_mfma_f32_16x16x32_bf16(
                    afr[tm], bfr[tn], acc[tm][tn], 0, 0, 0);
    }
#undef LOAD_IT

    #pragma unroll
    for (int tm = 0; tm < TM; ++tm) {
        #pragma unroll
        for (int tn = 0; tn < TN; ++tn) {
            const int col = cbase + tn*16 + l16;
            const float bv = HAS_BIAS ? bias[col] : 0.0f;
            #pragma unroll
            for (int rg = 0; rg < 4; ++rg) {
                const int m = mbase + tm*16 + q*4 + rg;
                const int pix = pixbase + m;
                const int oh = pix >> 5, ow = pix & 31;
                size_t oidx = (((size_t)n_img * Hout + (oh*OS + OPH)) * Wout
                               + (ow*OS + OPW)) * COUT + col;
                float v = acc[tm][tn][rg] + bv;
                if (RESID) v += bf2f(out[oidx]);
                if (RELU_OUT) v = fmaxf(v, 0.0f);
                out[oidx] = f2bf(v);
            }
        }
    }
}

// ---------------- conv1: weight-stationary + LDS-coalesced stores ------------
__global__ __launch_bounds__(256)
void conv1_k(const float* __restrict__ x, const float* __restrict__ w,
             const float* __restrict__ b, u16* __restrict__ out)
{
    constexpr int LDC = 72;
    __shared__ alignas(16) u16 cbuf[256 * LDC];

    int tid = threadIdx.x;
    int gpix = blockIdx.x * 256 + tid;
    int ow = gpix & 63, oh = (gpix >> 6) & 63, n = gpix >> 12;
    const float* xb = x + (size_t)n * 3 * 16384;
    const int ih0 = oh * 2 - 1, iw0 = ow * 2 - 1;

    float xr[48];
    #pragma unroll
    for (int ci = 0; ci < 3; ++ci) {
        #pragma unroll
        for (int kh = 0; kh < 4; ++kh) {
            int ih = ih0 + kh;
            bool rowok = (unsigned)ih < 128u;
            #pragma unroll
            for (int kw = 0; kw < 4; ++kw) {
                int iw = iw0 + kw;
                bool ok = rowok && ((unsigned)iw < 128u);
                xr[ci*16 + kh*4 + kw] = ok ? xb[ci*16384 + ih*128 + iw] : 0.0f;
            }
        }
    }

    #pragma unroll
    for (int cg = 0; cg < 8; ++cg) {
        unsigned pk[4];
        #pragma unroll
        for (int cp = 0; cp < 4; ++cp) {
            const int co = cg*8 + cp*2;
            float a0 = b[co], a1 = b[co + 1];
            const float* w0 = w + co * 48;
            #pragma unroll
            for (int j = 0; j < 48; ++j) {
                a0 = fmaf(xr[j], w0[j],      a0);
                a1 = fmaf(xr[j], w0[48 + j], a1);
            }
            a0 = fmaxf(a0, 0.0f);
            a1 = fmaxf(a1, 0.0f);
            pk[cp] = (unsigned)f2bf(a0) | ((unsigned)f2bf(a1) << 16);
        }
        *(uint4*)&cbuf[tid * LDC + cg * 8] = *(uint4*)pk;
    }
    __syncthreads();

    u16* ob = out + (size_t)blockIdx.x * 256 * 64;
    #pragma unroll
    for (int it = 0; it < 8; ++it) {
        int j = it * 256 + tid;
        uint4 v = *(const uint4*)&cbuf[(j >> 3) * LDC + (j & 7) * 8];
        *(uint4*)(ob + j * 8) = v;
    }
}

// ---------------- tc2 as MFMA parity GEMM ----------------
__global__ __launch_bounds__(256)
void tc2_mfma_k(const u16* __restrict__ in, const u16* __restrict__ wT,
                const float* __restrict__ bias, float* __restrict__ out)
{
    constexpr int LDA = 40;
    __shared__ alignas(16) u16 aT[128 * LDA];
    __shared__ alignas(16) u16 bT[16 * LDA];
    __shared__ float cT[128 * 17];

    const int tid = threadIdx.x;
    const int m0 = blockIdx.x * 128;
    const int n_img = m0 >> 12;
    const int pixbase = m0 & 4095;
    const int y0 = pixbase >> 6;

    const int r = tid >> 1, half = tid & 1;
    const int pr = pixbase + r;
    const int yr = pr >> 6, xr = pr & 63;
    const u16* inb = in + (size_t)n_img * 4096 * 64;

    const int wv = tid >> 6, lane = tid & 63;
    const int q = lane >> 4, l16 = lane & 15;
    const int mbase = wv * 32;

    f32x4 acc[2] = {};

    for (int t = 0; t < 9; ++t) {
        const int ih = yr + t/3 - 1;
        const int iw = xr + t%3 - 1;
        const bool ok = ((unsigned)ih < 64u) && ((unsigned)iw < 64u);
        const u16* asrc = ok ? (inb + ((size_t)ih * 64 + iw) * 64 + half * 16) : inb;
        const u16* bsrc = wT + ((size_t)t * 16 + r) * 64 + half * 16;

        for (int c0 = 0; c0 < 64; c0 += 32) {
            __syncthreads();
            uint4 a0 = {0,0,0,0}, a1 = {0,0,0,0};
            if (ok) {
                a0 = *(const uint4*)(asrc + c0);
                a1 = *(const uint4*)(asrc + c0 + 8);
            }
            *(uint4*)&aT[r * LDA + half * 16]     = a0;
            *(uint4*)&aT[r * LDA + half * 16 + 8] = a1;
            if (r < 16) {
                *(uint4*)&bT[r * LDA + half * 16]     = *(const uint4*)(bsrc + c0);
                *(uint4*)&bT[r * LDA + half * 16 + 8] = *(const uint4*)(bsrc + c0 + 8);
            }
            __syncthreads();

            bf16x8 af0 = *(const bf16x8*)&aT[(mbase + l16) * LDA + q * 8];
            bf16x8 af1 = *(const bf16x8*)&aT[(mbase + 16 + l16) * LDA + q * 8];
            bf16x8 bf  = *(const bf16x8*)&bT[l16 * LDA + q * 8];
            acc[0] = __builtin_amdgcn_mfma_f32_16x16x32_bf16(af0, bf, acc[0], 0, 0, 0);
            acc[1] = __builtin_amdgcn_mfma_f32_16x16x32_bf16(af1, bf, acc[1], 0, 0, 0);
        }
    }

    #pragma unroll
    for (int tm = 0; tm < 2; ++tm)
        #pragma unroll
        for (int rg = 0; rg < 4; ++rg)
            cT[(mbase + tm*16 + q*4 + rg) * 17 + l16] = acc[tm][rg];
    __syncthreads();

    #pragma unroll
    for (int it = 0; it < 6; ++it) {
        int j = it * 256 + tid;
        int co  = j >> 9;
        int rem = j & 511;
        int ohl = rem >> 7;
        int ow  = rem & 127;
        int oh  = 2*y0 + ohl;
        int lp  = (ohl >> 1) * 64 + (ow >> 1);
        int col = ((ohl & 1) * 2 + (ow & 1)) * 4 + co;
        float v = cT[lp * 17 + col] + bias[co];
        out[(((size_t)n_img * 3 + co) * 128 + oh) * 128 + ow] = v;
    }
}

// ---------------- MFMA vector quantizer: LDS codebook + packed-key argmin ----
__global__ __launch_bounds__(256)
void vq_mfma_k(const u16* __restrict__ Ze, const u16* __restrict__ Ebf,
               const float* __restrict__ enorm1, u16* __restrict__ Zq,
               u16* __restrict__ idx_out, float* __restrict__ sse)
{
    __shared__ alignas(16) u16 eld[256 * 72];
    __shared__ float en1s[256];
    __shared__ int bestk_s[128];
    __shared__ float red[256];

    const int tid = threadIdx.x;
    const int lane = tid & 63, wv = tid >> 6;
    const int q = lane >> 4, l16 = lane & 15;
    const int pb = blockIdx.x * 128 + wv * 32;

    bf16x8 alo[2], ahi[2];
    #pragma unroll
    for (int tile = 0; tile < 2; ++tile) {
        const u16* zp = Ze + (size_t)(pb + tile*16 + l16) * 64;
        alo[tile] = *(const bf16x8*)(zp + q * 8);
        ahi[tile] = *(const bf16x8*)(zp + 32 + q * 8);
    }

    unsigned key[2][4] = {{0xFFFFFFFFu,0xFFFFFFFFu,0xFFFFFFFFu,0xFFFFFFFFu},
                          {0xFFFFFFFFu,0xFFFFFFFFu,0xFFFFFFFFu,0xFFFFFFFFu}};

    for (int k0 = 0; k0 < 512; k0 += 256) {
        __syncthreads();
        const uint4* src = (const uint4*)(Ebf + k0 * 64);
        #pragma unroll
        for (int i = tid; i < 2048; i += 256) {
            int row = i >> 3, sub = i & 7;
            *(uint4*)&eld[row * 72 + sub * 8] = src[i];
        }
        en1s[tid] = enorm1[k0 + tid];
        __syncthreads();

        for (int t = 0; t < 16; ++t) {
            const int nl = t * 16 + l16;
            bf16x8 b0 = *(const bf16x8*)&eld[nl * 72 + q * 8];
            bf16x8 b1 = *(const bf16x8*)&eld[nl * 72 + 32 + q * 8];
            const float en1 = en1s[nl];
            const unsigned ng = (unsigned)(k0 + nl);
            #pragma unroll
            for (int tile = 0; tile < 2; ++tile) {
                f32x4 acc = {0.0f, 0.0f, 0.0f, 0.0f};
                acc = __builtin_amdgcn_mfma_f32_16x16x32_bf16(alo[tile], b0, acc, 0, 0, 0);
                acc = __builtin_amdgcn_mfma_f32_16x16x32_bf16(ahi[tile], b1, acc, 0, 0, 0);
                #pragma unroll
                for (int rg = 0; rg < 4; ++rg) {
                    float sc = fmaf(acc[rg], -2.0f, en1);
                    unsigned kk2 = (__float_as_uint(sc) & 0xFFFFFE00u) | ng;
                    key[tile][rg] = min(key[tile][rg], kk2);
                }
            }
        }
    }

    #pragma unroll
    for (int m = 1; m < 16; m <<= 1) {
        #pragma unroll
        for (int tile = 0; tile < 2; ++tile)
            #pragma unroll
            for (int rg = 0; rg < 4; ++rg) {
                unsigned o = (unsigned)__shfl_xor((int)key[tile][rg], m, 64);
                key[tile][rg] = min(key[tile][rg], o);
            }
    }
    if (l16 == 0) {
        #pragma unroll
        for (int tile = 0; tile < 2; ++tile)
            #pragma unroll
            for (int rg = 0; rg < 4; ++rg)
                bestk_s[wv * 32 + tile * 16 + q * 4 + rg] = (int)(key[tile][rg] & 511u);
    }
    __syncthreads();

    const int pos = tid >> 1, seg = tid & 1;
    const int p = blockIdx.x * 128 + pos;
    const int k = bestk_s[pos];
    const u16* ep = Ebf + (size_t)k * 64 + seg * 32;
    const u16* zp = Ze + (size_t)p * 64 + seg * 32;
    u16* qp = Zq + (size_t)p * 64 + seg * 32;
    float local = 0.0f;
    #pragma unroll
    for (int h = 0; h < 4; ++h) {
        uint4 ev = *(const uint4*)(ep + h * 8);
        uint4 zv = *(const uint4*)(zp + h * 8);
        *(uint4*)(qp + h * 8) = ev;
        unsigned ea[4] = {ev.x, ev.y, ev.z, ev.w};
        unsigned za[4] = {zv.x, zv.y, zv.z, zv.w};
        #pragma unroll
        for (int j = 0; j < 4; ++j) {
            float d0 = bf2f((u16)(ea[j] & 0xFFFFu)) - bf2f((u16)(za[j] & 0xFFFFu));
            float d1 = bf2f((u16)(ea[j] >> 16))     - bf2f((u16)(za[j] >> 16));
            local = fmaf(d0, d0, fmaf(d1, d1, local));
        }
    }
    if (seg == 0) idx_out[p] = (u16)k;
    red[tid] = local;
    __syncthreads();
    for (int s = 128; s > 0; s >>= 1) {
        if (tid < s) red[tid] += red[tid + s];
        __syncthreads();
    }
    if (tid == 0) atomicAdd(sse, red[0]);
}

// ---------------- histogram by scan: block k counts code k ----------------
__global__ __launch_bounds__(256)
void hist_k(const u16* __restrict__ idx, float* __restrict__ counts)
{
    __shared__ int red[256];
    const int k = blockIdx.x;
    const int tid = threadIdx.x;
    int c = 0;
    const uint4* p4 = (const uint4*)idx;
    for (int i = tid; i < 8192; i += 256) {
        uint4 v = p4[i];
        unsigned ua[4] = {v.x, v.y, v.z, v.w};
        #pragma unroll
        for (int j = 0; j < 4; ++j) {
            c += ((ua[j] & 0xFFFFu) == (unsigned)k);
            c += ((ua[j] >> 16)     == (unsigned)k);
        }
    }
    red[tid] = c;
    __syncthreads();
    for (int s = 128; s > 0; s >>= 1) {
        if (tid < s) red[tid] += red[tid + s];
        __syncthreads();
    }
    if (tid == 0) counts[k] = (float)red[0];
}

// ---------------- merged prep: all weight transforms + eprep + sse zero ------
__device__ __forceinline__ void wconv_tf(const float* __restrict__ w,
                                         u16* __restrict__ o,
                                         int COUT, int CIN, int KK, int i)
{
    int ci = i % CIN; int t = i / CIN; int co = t % COUT; t /= COUT;
    o[i] = f2bf(w[(co*CIN + ci)*KK + t]);
}

__global__ __launch_bounds__(256)
void prep_k(const float* __restrict__ enc_w2, const float* __restrict__ enc_w3,
            const float* __restrict__ enc_w4, const float* __restrict__ enc_res_w1,
            const float* __restrict__ enc_res_w2, const float* __restrict__ dec_res_w1,
            const float* __restrict__ dec_res_w2, const float* __restrict__ enc_adj_w,
            const float* __restrict__ dec_adj_w, const float* __restrict__ tc1_w,
            const float* __restrict__ tc2_w, const float* __restrict__ E,
            u16* __restrict__ wc2, u16* __restrict__ wc3, u16* __restrict__ wc4,
            u16* __restrict__ wer1, u16* __restrict__ wer2, u16* __restrict__ wdr1,
            u16* __restrict__ wdr2, u16* __restrict__ weadj, u16* __restrict__ wdadj,
            u16* __restrict__ wtc1, u16* __restrict__ wtc2b,
            u16* __restrict__ Ebf, float* __restrict__ enorm1, float* __restrict__ sse)
{
    const int b = blockIdx.x, tid = threadIdx.x;
    if (b < 512) {                      // wc2: 131072, (128,64,16)
        wconv_tf(enc_w2, wc2, 128, 64, 16, b * 256 + tid);
    } else if (b < 1088) {              // wc3: 147456, (128,128,9)
        wconv_tf(enc_w3, wc3, 128, 128, 9, (b - 512) * 256 + tid);
    } else if (b < 1664) {              // wc4
        wconv_tf(enc_w4, wc4, 128, 128, 9, (b - 1088) * 256 + tid);
    } else if (b < 2240) {              // er1: 2 x 73728, (64,128,9)
        int i = (b - 1664) * 256 + tid;
        int sub = i / 73728, rem = i - sub * 73728;
        wconv_tf(enc_res_w1 + sub * 73728, wer1 + sub * 73728, 64, 128, 9, rem);
    } else if (b < 2816) {              // dr1
        int i = (b - 2240) * 256 + tid;
        int sub = i / 73728, rem = i - sub * 73728;
        wconv_tf(dec_res_w1 + sub * 73728, wdr1 + sub * 73728, 64, 128, 9, rem);
    } else if (b < 2880) {              // er2: 2 x 8192, (128,64,1)
        int i = (b - 2816) * 256 + tid;
        int sub = i >> 13, rem = i & 8191;
        wconv_tf(enc_res_w2 + sub * 8192, wer2 + sub * 8192, 128, 64, 1, rem);
    } else if (b < 2944) {              // dr2
        int i = (b - 2880) * 256 + tid;
        int sub = i >> 13, rem = i & 8191;
        wconv_tf(dec_res_w2 + sub * 8192, wdr2 + sub * 8192, 128, 64, 1, rem);
    } else if (b < 2976) {              // eadj: 8192, (64,128,1)
        wconv_tf(enc_adj_w, weadj, 64, 128, 1, (b - 2944) * 256 + tid);
    } else if (b < 3264) {              // dadj: 73728, (128,64,9)
        wconv_tf(dec_adj_w, wdadj, 128, 64, 9, (b - 2976) * 256 + tid);
    } else if (b < 3776) {              // tc1: 131072
        int i = (b - 3264) * 256 + tid;
        int ci = i & 127; int co = (i >> 7) & 63; int t = (i >> 13) & 3; int p = i >> 15;
        int poh = p >> 1, pw = p & 1; int a = t >> 1, bb = t & 1;
        int kh = poh ? (a ? 2 : 0) : (a ? 3 : 1);
        int kw = pw  ? (bb ? 2 : 0) : (bb ? 3 : 1);
        wtc1[i] = f2bf(tc1_w[((ci*64 + co)*4 + kh)*4 + kw]);
    } else if (b < 3812) {              // tc2b: 9216 zero-padded parity weights
        int i = (b - 3776) * 256 + tid;
        int ci = i & 63; int col = (i >> 6) & 15; int t = i >> 10;
        int dh = t / 3 - 1, dw = t % 3 - 1;
        int pp = col >> 2, co = col & 3;
        float v = 0.0f;
        if (co < 3) {
            int poh = pp >> 1, pw = pp & 1;
            int kh = poh ? (dh == 1 ? 0 : (dh == 0 ? 2 : -1))
                         : (dh == 0 ? 1 : (dh == -1 ? 3 : -1));
            int kw = pw  ? (dw == 1 ? 0 : (dw == 0 ? 2 : -1))
                         : (dw == 0 ? 1 : (dw == -1 ? 3 : -1));
            if (kh >= 0 && kw >= 0)
                v = tc2_w[((ci*3 + co)*4 + kh)*4 + kw];
        }
        wtc2b[i] = f2bf(v);
    } else if (b < 3814) {              // eprep: 512 codes
        int k = (b - 3812) * 256 + tid;
        float s = 0.0f;
        #pragma unroll
        for (int d = 0; d < 64; ++d) {
            u16 h = f2bf(E[k*64 + d]);
            Ebf[k*64 + d] = h;
            float v = bf2f(h);
            s = fmaf(v, v, s);
        }
        enorm1[k] = s + 1.0f;
    } else {                            // sse zero
        if (tid == 0) sse[0] = 0.0f;
    }
}

// ---------------- scalars ----------------
__global__ void finalize_k(const float* __restrict__ counts, const float* __restrict__ sse,
                           float* __restrict__ out_head, float* __restrict__ out_tail)
{
    __shared__ float red[512];
    int t = threadIdx.x;
    float pr = counts[t] / 65536.0f;
    red[t] = -pr * log2f(pr + 1e-10f);
    __syncthreads();
    for (int s = 256; s > 0; s >>= 1) {
        if (t < s) red[t] += red[t + s];
        __syncthreads();
    }
    if (t == 0) {
        float entropy = red[0];
        float mse = sse[0] / 4194304.0f;
        out_head[0] = 1.25f * mse;
        out_tail[0] = mse;
        out_tail[1] = mse;
        out_tail[2] = exp2f(entropy);
    }
}

// ---------------------------------------------------------------------------
extern "C" void kernel_launch(void* const* d_in, const int* in_sizes, int n_in,
                              void* d_out, int out_size, void* d_ws, size_t ws_size,
                              hipStream_t stream)
{
    const float* x         = (const float*)d_in[0];
    const float* enc_w1    = (const float*)d_in[1];
    const float* enc_b1    = (const float*)d_in[2];
    const float* enc_w2    = (const float*)d_in[3];
    const float* enc_b2    = (const float*)d_in[4];
    const float* enc_w3    = (const float*)d_in[5];
    const float* enc_b3    = (const float*)d_in[6];
    const float* enc_w4    = (const float*)d_in[7];
    const float* enc_b4    = (const float*)d_in[8];
    const float* enc_res_w1= (const float*)d_in[9];
    const float* enc_res_w2= (const float*)d_in[10];
    const float* enc_adj_w = (const float*)d_in[11];
    const float* enc_adj_b = (const float*)d_in[12];
    const float* Ecb       = (const float*)d_in[13];
    const float* dec_adj_w = (const float*)d_in[14];
    const float* dec_adj_b = (const float*)d_in[15];
    const float* dec_res_w1= (const float*)d_in[16];
    const float* dec_res_w2= (const float*)d_in[17];
    const float* tc1_w     = (const float*)d_in[18];
    const float* tc1_b     = (const float*)d_in[19];
    const float* tc2_w     = (const float*)d_in[20];
    const float* tc2_b     = (const float*)d_in[21];

    char* wsb = (char*)d_ws;
    u16*   wc2   = (u16*)(wsb + 0);
    u16*   wc3   = (u16*)(wsb + 262144);
    u16*   wc4   = (u16*)(wsb + 557056);
    u16*   wer1  = (u16*)(wsb + 851968);
    u16*   wer2  = (u16*)(wsb + 1146880);
    u16*   weadj = (u16*)(wsb + 1179648);
    u16*   wdadj = (u16*)(wsb + 1196032);
    u16*   wdr1  = (u16*)(wsb + 1343488);
    u16*   wdr2  = (u16*)(wsb + 1638400);
    u16*   wtc1  = (u16*)(wsb + 1671168);
    u16*   wtc2b = (u16*)(wsb + 1933312);
    float* counts= (float*)(wsb + 1951744);
    float* sse   = counts + 512;
    u16*   Ebf   = (u16*)(wsb + 1955840);
    float* enorm1= (float*)(wsb + 2021376);
    u16*   H1    = (u16*)(wsb + 2097152);
    u16*   TR    = (u16*)(wsb + 35651584);
    u16*   H3    = (u16*)(wsb + 52428800);
    u16*   MID   = (u16*)(wsb + 69206016);
    u16*   ZE    = (u16*)(wsb + 77594624);
    u16*   ZQ    = (u16*)(wsb + 85983232);
    u16*   IDX   = (u16*)(wsb + 94371840);
    u16*   TC1O  = H1;

    float* out  = (float*)d_out;
    float* xrec = out + 1;
    float* tail = out + 1 + 3145728;

    Taps t3x3; t3x3.s = 1; t3x3.ntaps = 9;
    for (int kh = 0; kh < 3; ++kh) for (int kw = 0; kw < 3; ++kw) {
        t3x3.dh[kh*3+kw] = kh - 1; t3x3.dw[kh*3+kw] = kw - 1;
    }
    Taps t1x1; t1x1.s = 1; t1x1.ntaps = 1; t1x1.dh[0] = 0; t1x1.dw[0] = 0;
    Taps t4x4; t4x4.s = 2; t4x4.ntaps = 16;
    for (int kh = 0; kh < 4; ++kh) for (int kw = 0; kw < 4; ++kw) {
        t4x4.dh[kh*4+kw] = kh - 1; t4x4.dw[kh*4+kw] = kw - 1;
    }
    const int dtab[2][2] = {{0, -1}, {1, 0}};
    Taps ttc1[4];
    for (int p = 0; p < 4; ++p) {
        ttc1[p].s = 1; ttc1[p].ntaps = 4;
        for (int a = 0; a < 2; ++a) for (int bb = 0; bb < 2; ++bb) {
            ttc1[p].dh[a*2+bb] = dtab[p>>1][a];
            ttc1[p].dw[a*2+bb] = dtab[p&1][bb];
        }
    }

    // ---- single merged prep dispatch ----
    prep_k<<<3815, 256, 0, stream>>>(enc_w2, enc_w3, enc_w4, enc_res_w1,
        enc_res_w2, dec_res_w1, dec_res_w2, enc_adj_w, dec_adj_w, tc1_w, tc2_w,
        Ecb, wc2, wc3, wc4, wer1, wer2, wdr1, wdr2, weadj, wdadj, wtc1, wtc2b,
        Ebf, enorm1, sse);

    // ---- encoder ----
    conv1_k<<<1024, 256, 0, stream>>>(x, enc_w1, enc_b1, H1);
    mfma_conv_k<64,128,false,true,true,false><<<512, 256, 0, stream>>>
        (H1, wc2, enc_b2, TR, 64, 64, 32, 32, 1, 0, 0, t4x4);
    mfma_conv_k<128,128,false,true,true,false><<<512, 256, 0, stream>>>
        (TR, wc3, enc_b3, H3, 32, 32, 32, 32, 1, 0, 0, t3x3);
    mfma_conv_k<128,128,false,false,true,false><<<512, 256, 0, stream>>>
        (H3, wc4, enc_b4, TR, 32, 32, 32, 32, 1, 0, 0, t3x3);
    for (int i = 0; i < 2; ++i) {
        mfma_conv_k<128,64,true,false,false,false><<<512, 256, 0, stream>>>
            (TR, wer1 + i*73728, nullptr, MID, 32, 32, 32, 32, 1, 0, 0, t3x3);
        mfma_conv_k<64,128,true,false,false,true><<<512, 256, 0, stream>>>
            (MID, wer2 + i*8192, nullptr, TR, 32, 32, 32, 32, 1, 0, 0, t1x1);
    }
    mfma_conv_k<128,64,true,false,true,false><<<512, 256, 0, stream>>>
        (TR, weadj, enc_adj_b, ZE, 32, 32, 32, 32, 1, 0, 0, t1x1);

    // ---- VQ ----
    vq_mfma_k<<<512, 256, 0, stream>>>(ZE, Ebf, enorm1, ZQ, IDX, sse);
    hist_k<<<512, 256, 0, stream>>>(IDX, counts);

    // ---- decoder ----
    mfma_conv_k<64,128,false,false,true,false><<<512, 256, 0, stream>>>
        (ZQ, wdadj, dec_adj_b, H3, 32, 32, 32, 32, 1, 0, 0, t3x3);
    for (int i = 0; i < 2; ++i) {
        mfma_conv_k<128,64,true,false,false,false><<<512, 256, 0, stream>>>
            (H3, wdr1 + i*73728, nullptr, MID, 32, 32, 32, 32, 1, 0, 0, t3x3);
        mfma_conv_k<64,128,true,false,false,true><<<512, 256, 0, stream>>>
            (MID, wdr2 + i*8192, nullptr, H3, 32, 32, 32, 32, 1, 0, 0, t1x1);
    }
    for (int p = 0; p < 4; ++p) {
        mfma_conv_k<128,64,true,true,true,false><<<512, 256, 0, stream>>>
            (H3, wtc1 + p*32768, tc1_b, TC1O, 32, 32, 64, 64, 2, p>>1, p&1, ttc1[p]);
    }
    tc2_mfma_k<<<2048, 256, 0, stream>>>(TC1O, wtc2b, tc2_b, xrec);

    // ---- scalars ----
    finalize_k<<<1, 512, 0, stream>>>(counts, sse, out, tail);
}

// Round 11
// 524.058 us; speedup vs baseline: 1.3715x; 1.0676x over previous
//
#include <hip/hip_runtime.h>
#include <math.h>

// ---------------------------------------------------------------------------
// VQ-VAE forward: NHWC bf16 trunk, implicit-GEMM MFMA convs (fp32 accum,
// BK=32/LDA=40, register-prefetch K-loop, COUT-split grid.y for 128-out
// convs -> 4 blocks/CU), MFMA im2col conv1 (K=48 zero-padded to 64),
// LDS-staged packed-key MFMA VQ, MFMA tc2, single merged prep dispatch.
//
// Workspace layout (bytes):
//   [0 .. ~2.1MB)   transformed weights + counts/sse + Ebf + enorm1 + wc1b
//   H1  = 2097152   (64,64,64,64)  NHWC bf16  33.5MB   h1, later tc1 out
//   TR  = 35651584  (64,32,32,128) NHWC bf16  16.8MB   enc trunk
//   H3  = 52428800  (64,32,32,128) NHWC bf16  16.8MB   h3, later dec trunk
//   MID = 69206016  (64,32,32,64)  NHWC bf16   8.4MB   res mid
//   ZE  = 77594624  (64,32,32,64)  NHWC bf16   8.4MB
//   ZQ  = 85983232  (64,32,32,64)  NHWC bf16   8.4MB
//   IDX = 94371840  65536 u16      128KB
// ---------------------------------------------------------------------------

typedef unsigned short u16;
typedef __attribute__((ext_vector_type(8))) short bf16x8;
typedef __attribute__((ext_vector_type(4))) float f32x4;

__device__ __forceinline__ float bf2f(u16 h) {
    union { unsigned u; float f; } v; v.u = ((unsigned)h) << 16; return v.f;
}
__device__ __forceinline__ u16 f2bf(float f) {
    union { float f; unsigned u; } v; v.f = f;
    unsigned r = v.u + 0x7FFFu + ((v.u >> 16) & 1u);
    return (u16)(r >> 16);
}
__device__ __forceinline__ unsigned relu2(unsigned x) {
    return x & ~(((x & 0x80008000u) >> 15) * 0xFFFFu);
}

struct Taps { int s; int ntaps; int dh[16]; int dw[16]; };

// ---------------- unified implicit-GEMM MFMA conv ----------------
// BK=32/LDA=40 (r8: BK=64/LDA=72 regressed — bank conflicts + LDS occupancy).
// Block = 128 px x 64 cols; gridDim.y = COUT/64 (r11: grid=512 capped convs
// at 2 blocks/CU — grid-limited occupancy, not LDS/VGPR). Register prefetch
// of next iter's A/B overlaps L2 latency with MFMAs (r10 win).
template<int CIN, int COUT, bool RELU_IN, bool RELU_OUT, bool HAS_BIAS, bool RESID>
__global__ __launch_bounds__(256)
void mfma_conv_k(const u16* __restrict__ in, const u16* __restrict__ wT,
                 const float* __restrict__ bias, u16* __restrict__ out,
                 int Hin, int Win, int Hout, int Wout, int OS, int OPH, int OPW,
                 Taps taps)
{
    constexpr int TM = 2, TN = 4;
    constexpr int LDA = 40;      // 32 data + 8 pad
    constexpr int NCH = CIN / 32;

    __shared__ alignas(16) u16 aT[128 * LDA];
    __shared__ alignas(16) u16 bT[64 * LDA];

    const int tid = threadIdx.x;
    const int m0 = blockIdx.x * 128;
    const int colbase = blockIdx.y << 6;
    const int n_img = m0 >> 10;
    const int pixbase = m0 & 1023;

    const int r = tid >> 1, half = tid & 1;
    const int pr = pixbase + r;
    const int ohr = pr >> 5, owr = pr & 31;
    const u16* inb = in + (size_t)n_img * Hin * Win * CIN;

    const int wv = tid >> 6, lane = tid & 63;
    const int q = lane >> 4, l16 = lane & 15;
    const int mbase = wv * 32;
    const bool bload = r < 64;

    f32x4 acc[TM][TN] = {};

    const int total_it = taps.ntaps * NCH;
    uint4 pa0, pa1, pb0 = {0,0,0,0}, pb1 = {0,0,0,0};

#define LOAD_IT(IT) do {                                                        \
        int t_ = (IT) / NCH, cc_ = ((IT) % NCH) * 32;                           \
        int ih_ = ohr * taps.s + taps.dh[t_];                                   \
        int iw_ = owr * taps.s + taps.dw[t_];                                   \
        bool ok_ = ((unsigned)ih_ < (unsigned)Hin) &&                           \
                   ((unsigned)iw_ < (unsigned)Win);                             \
        pa0 = (uint4){0,0,0,0}; pa1 = (uint4){0,0,0,0};                         \
        if (ok_) {                                                              \
            const u16* as_ = inb + ((size_t)ih_ * Win + iw_) * CIN              \
                             + half * 16 + cc_;                                 \
            pa0 = *(const uint4*)(as_);                                         \
            pa1 = *(const uint4*)(as_ + 8);                                     \
        }                                                                       \
        if (bload) {                                                            \
            const u16* bs_ = wT + ((size_t)t_ * COUT + colbase + r) * CIN       \
                             + half * 16 + cc_;                                 \
            pb0 = *(const uint4*)(bs_);                                         \
            pb1 = *(const uint4*)(bs_ + 8);                                     \
        }                                                                       \
    } while (0)

    LOAD_IT(0);

    for (int it = 0; it < total_it; ++it) {
        __syncthreads();
        uint4 a0 = pa0, a1 = pa1;
        if (RELU_IN) {
            a0.x = relu2(a0.x); a0.y = relu2(a0.y); a0.z = relu2(a0.z); a0.w = relu2(a0.w);
            a1.x = relu2(a1.x); a1.y = relu2(a1.y); a1.z = relu2(a1.z); a1.w = relu2(a1.w);
        }
        *(uint4*)&aT[r * LDA + half * 16]     = a0;
        *(uint4*)&aT[r * LDA + half * 16 + 8] = a1;
        if (bload) {
            *(uint4*)&bT[r * LDA + half * 16]     = pb0;
            *(uint4*)&bT[r * LDA + half * 16 + 8] = pb1;
        }
        __syncthreads();
        if (it + 1 < total_it) LOAD_IT(it + 1);   // prefetch overlaps MFMAs below

        bf16x8 afr[TM], bfr[TN];
        #pragma unroll
        for (int tm = 0; tm < TM; ++tm)
            afr[tm] = *(const bf16x8*)&aT[(mbase + tm*16 + l16) * LDA + q * 8];
        #pragma unroll
        for (int tn = 0; tn < TN; ++tn)
            bfr[tn] = *(const bf16x8*)&bT[(tn*16 + l16) * LDA + q * 8];
        #pragma unroll
        for (int tm = 0; tm < TM; ++tm)
            #pragma unroll
            for (int tn = 0; tn < TN; ++tn)
                acc[tm][tn] = __builtin_amdgcn_mfma_f32_16x16x32_bf16(
                    afr[tm], bfr[tn], acc[tm][tn], 0, 0, 0);
    }
#undef LOAD_IT

    #pragma unroll
    for (int tm = 0; tm < TM; ++tm) {
        #pragma unroll
        for (int tn = 0; tn < TN; ++tn) {
            const int col = colbase + tn*16 + l16;
            const float bv = HAS_BIAS ? bias[col] : 0.0f;
            #pragma unroll
            for (int rg = 0; rg < 4; ++rg) {
                const int m = mbase + tm*16 + q*4 + rg;
                const int pix = pixbase + m;
                const int oh = pix >> 5, ow = pix & 31;
                size_t oidx = (((size_t)n_img * Hout + (oh*OS + OPH)) * Wout
                               + (ow*OS + OPW)) * COUT + col;
                float v = acc[tm][tn][rg] + bv;
                if (RESID) v += bf2f(out[oidx]);
                if (RELU_OUT) v = fmaxf(v, 0.0f);
                out[oidx] = f2bf(v);
            }
        }
    }
}

// ---------------- conv1 as MFMA im2col GEMM ----------------
// M=262144 px, N=64 co, K=48 (3ci x 4x4) zero-padded to 64. Block = 128 px,
// all 64 co, single staging (no K-loop). wc1b: bf16 [co][k64] built in prep.
// A/B split into two 32-k LDS halves (LDA=40 each, conflict-free); second
// MFMA's upper 16 k are zeros on both sides. Output via LDS-transpose for
// coalesced NHWC stores (r7: scattered u16 stores = 4.7x write amplification).
__global__ __launch_bounds__(256)
void conv1_mfma_k(const float* __restrict__ x, const u16* __restrict__ wc1b,
                  const float* __restrict__ b, u16* __restrict__ out)
{
    __shared__ alignas(16) u16 smem[15360];   // aT0|aT1|bT0|bT1 (30.7KB)
    u16* aT0 = smem;
    u16* aT1 = smem + 5120;
    u16* bT0 = smem + 10240;
    u16* bT1 = smem + 12800;

    const int tid = threadIdx.x;
    const int gbase = blockIdx.x * 128;       // 2048 blocks
    const int r = tid >> 1, half = tid & 1;
    const int p = gbase + r;
    const int ow = p & 63, oh = (p >> 6) & 63, n = p >> 12;
    const float* xb = x + (size_t)n * 3 * 16384;

    // B staging: 64 rows x 64 k (two 32-k halves), 8KB total
    {
        int row = tid >> 2, sub = tid & 3;
        *(uint4*)&bT0[row*40 + sub*8] = *(const uint4*)(wc1b + row*64 + sub*8);
        *(uint4*)&bT1[row*40 + sub*8] = *(const uint4*)(wc1b + row*64 + 32 + sub*8);
    }

    // A staging: this thread covers k = half*24 .. half*24+23 of pixel row r
    float vals[24];
    const int kb = half * 24;
    #pragma unroll
    for (int j = 0; j < 24; ++j) {
        int k = kb + j;
        int ci = k >> 4, kh = (k >> 2) & 3, kw = k & 3;
        int ih = oh*2 - 1 + kh, iw = ow*2 - 1 + kw;
        bool ok = ((unsigned)ih < 128u) && ((unsigned)iw < 128u);
        vals[j] = ok ? xb[ci*16384 + ih*128 + iw] : 0.0f;
    }
    unsigned pk[12];
    #pragma unroll
    for (int jj = 0; jj < 12; ++jj)
        pk[jj] = (unsigned)f2bf(vals[2*jj]) | ((unsigned)f2bf(vals[2*jj+1]) << 16);
    unsigned* a0row = (unsigned*)&aT0[r * 40];
    unsigned* a1row = (unsigned*)&aT1[r * 40];
    if (half == 0) {
        #pragma unroll
        for (int jj = 0; jj < 12; ++jj) a0row[jj] = pk[jj];       // k 0..23
    } else {
        a0row[12] = pk[0]; a0row[13] = pk[1];                      // k 24..31
        a0row[14] = pk[2]; a0row[15] = pk[3];
        #pragma unroll
        for (int jj = 4; jj < 12; ++jj) a1row[jj - 4] = pk[jj];    // k 32..47
        *(uint4*)&aT1[r*40 + 16] = (uint4){0,0,0,0};               // k 48..63
        *(uint4*)&aT1[r*40 + 24] = (uint4){0,0,0,0};
    }
    __syncthreads();

    const int wv = tid >> 6, lane = tid & 63;
    const int q = lane >> 4, l16 = lane & 15;
    const int mbase = wv * 32;

    f32x4 acc[2][4] = {};
    bf16x8 af0[2], af1[2], bf0[4], bf1[4];
    #pragma unroll
    for (int tm = 0; tm < 2; ++tm) {
        af0[tm] = *(const bf16x8*)&aT0[(mbase + tm*16 + l16) * 40 + q * 8];
        af1[tm] = *(const bf16x8*)&aT1[(mbase + tm*16 + l16) * 40 + q * 8];
    }
    #pragma unroll
    for (int tn = 0; tn < 4; ++tn) {
        bf0[tn] = *(const bf16x8*)&bT0[(tn*16 + l16) * 40 + q * 8];
        bf1[tn] = *(const bf16x8*)&bT1[(tn*16 + l16) * 40 + q * 8];
    }
    #pragma unroll
    for (int tm = 0; tm < 2; ++tm)
        #pragma unroll
        for (int tn = 0; tn < 4; ++tn) {
            acc[tm][tn] = __builtin_amdgcn_mfma_f32_16x16x32_bf16(
                af0[tm], bf0[tn], acc[tm][tn], 0, 0, 0);
            acc[tm][tn] = __builtin_amdgcn_mfma_f32_16x16x32_bf16(
                af1[tm], bf1[tn], acc[tm][tn], 0, 0, 0);
        }

    float bv[4];
    #pragma unroll
    for (int tn = 0; tn < 4; ++tn) bv[tn] = b[tn*16 + l16];

    __syncthreads();                 // A/B LDS dead; reuse as output transpose
    u16* cbuf = smem;                // 128 x 72
    #pragma unroll
    for (int tm = 0; tm < 2; ++tm)
        #pragma unroll
        for (int tn = 0; tn < 4; ++tn)
            #pragma unroll
            for (int rg = 0; rg < 4; ++rg) {
                int row = mbase + tm*16 + q*4 + rg;
                int col = tn*16 + l16;
                cbuf[row*72 + col] = f2bf(fmaxf(acc[tm][tn][rg] + bv[tn], 0.0f));
            }
    __syncthreads();

    u16* ob = out + (size_t)gbase * 64;
    #pragma unroll
    for (int it = 0; it < 4; ++it) {
        int j = it * 256 + tid;
        uint4 v = *(const uint4*)&cbuf[(j >> 3) * 72 + (j & 7) * 8];
        *(uint4*)(ob + j * 8) = v;
    }
}

// ---------------- tc2 as MFMA parity GEMM ----------------
__global__ __launch_bounds__(256)
void tc2_mfma_k(const u16* __restrict__ in, const u16* __restrict__ wT,
                const float* __restrict__ bias, float* __restrict__ out)
{
    constexpr int LDA = 40;
    __shared__ alignas(16) u16 aT[128 * LDA];
    __shared__ alignas(16) u16 bT[16 * LDA];
    __shared__ float cT[128 * 17];

    const int tid = threadIdx.x;
    const int m0 = blockIdx.x * 128;
    const int n_img = m0 >> 12;
    const int pixbase = m0 & 4095;
    const int y0 = pixbase >> 6;

    const int r = tid >> 1, half = tid & 1;
    const int pr = pixbase + r;
    const int yr = pr >> 6, xr = pr & 63;
    const u16* inb = in + (size_t)n_img * 4096 * 64;

    const int wv = tid >> 6, lane = tid & 63;
    const int q = lane >> 4, l16 = lane & 15;
    const int mbase = wv * 32;

    f32x4 acc[2] = {};

    for (int t = 0; t < 9; ++t) {
        const int ih = yr + t/3 - 1;
        const int iw = xr + t%3 - 1;
        const bool ok = ((unsigned)ih < 64u) && ((unsigned)iw < 64u);
        const u16* asrc = ok ? (inb + ((size_t)ih * 64 + iw) * 64 + half * 16) : inb;
        const u16* bsrc = wT + ((size_t)t * 16 + r) * 64 + half * 16;

        for (int c0 = 0; c0 < 64; c0 += 32) {
            __syncthreads();
            uint4 a0 = {0,0,0,0}, a1 = {0,0,0,0};
            if (ok) {
                a0 = *(const uint4*)(asrc + c0);
                a1 = *(const uint4*)(asrc + c0 + 8);
            }
            *(uint4*)&aT[r * LDA + half * 16]     = a0;
            *(uint4*)&aT[r * LDA + half * 16 + 8] = a1;
            if (r < 16) {
                *(uint4*)&bT[r * LDA + half * 16]     = *(const uint4*)(bsrc + c0);
                *(uint4*)&bT[r * LDA + half * 16 + 8] = *(const uint4*)(bsrc + c0 + 8);
            }
            __syncthreads();

            bf16x8 af0 = *(const bf16x8*)&aT[(mbase + l16) * LDA + q * 8];
            bf16x8 af1 = *(const bf16x8*)&aT[(mbase + 16 + l16) * LDA + q * 8];
            bf16x8 bf  = *(const bf16x8*)&bT[l16 * LDA + q * 8];
            acc[0] = __builtin_amdgcn_mfma_f32_16x16x32_bf16(af0, bf, acc[0], 0, 0, 0);
            acc[1] = __builtin_amdgcn_mfma_f32_16x16x32_bf16(af1, bf, acc[1], 0, 0, 0);
        }
    }

    #pragma unroll
    for (int tm = 0; tm < 2; ++tm)
        #pragma unroll
        for (int rg = 0; rg < 4; ++rg)
            cT[(mbase + tm*16 + q*4 + rg) * 17 + l16] = acc[tm][rg];
    __syncthreads();

    #pragma unroll
    for (int it = 0; it < 6; ++it) {
        int j = it * 256 + tid;
        int co  = j >> 9;
        int rem = j & 511;
        int ohl = rem >> 7;
        int ow  = rem & 127;
        int oh  = 2*y0 + ohl;
        int lp  = (ohl >> 1) * 64 + (ow >> 1);
        int col = ((ohl & 1) * 2 + (ow & 1)) * 4 + co;
        float v = cT[lp * 17 + col] + bias[co];
        out[(((size_t)n_img * 3 + co) * 128 + oh) * 128 + ow] = v;
    }
}

// ---------------- MFMA vector quantizer: LDS codebook + packed-key argmin ----
__global__ __launch_bounds__(256)
void vq_mfma_k(const u16* __restrict__ Ze, const u16* __restrict__ Ebf,
               const float* __restrict__ enorm1, u16* __restrict__ Zq,
               u16* __restrict__ idx_out, float* __restrict__ sse)
{
    __shared__ alignas(16) u16 eld[256 * 72];
    __shared__ float en1s[256];
    __shared__ int bestk_s[128];
    __shared__ float red[256];

    const int tid = threadIdx.x;
    const int lane = tid & 63, wv = tid >> 6;
    const int q = lane >> 4, l16 = lane & 15;
    const int pb = blockIdx.x * 128 + wv * 32;

    bf16x8 alo[2], ahi[2];
    #pragma unroll
    for (int tile = 0; tile < 2; ++tile) {
        const u16* zp = Ze + (size_t)(pb + tile*16 + l16) * 64;
        alo[tile] = *(const bf16x8*)(zp + q * 8);
        ahi[tile] = *(const bf16x8*)(zp + 32 + q * 8);
    }

    unsigned key[2][4] = {{0xFFFFFFFFu,0xFFFFFFFFu,0xFFFFFFFFu,0xFFFFFFFFu},
                          {0xFFFFFFFFu,0xFFFFFFFFu,0xFFFFFFFFu,0xFFFFFFFFu}};

    for (int k0 = 0; k0 < 512; k0 += 256) {
        __syncthreads();
        const uint4* src = (const uint4*)(Ebf + k0 * 64);
        #pragma unroll
        for (int i = tid; i < 2048; i += 256) {
            int row = i >> 3, sub = i & 7;
            *(uint4*)&eld[row * 72 + sub * 8] = src[i];
        }
        en1s[tid] = enorm1[k0 + tid];
        __syncthreads();

        for (int t = 0; t < 16; ++t) {
            const int nl = t * 16 + l16;
            bf16x8 b0 = *(const bf16x8*)&eld[nl * 72 + q * 8];
            bf16x8 b1 = *(const bf16x8*)&eld[nl * 72 + 32 + q * 8];
            const float en1 = en1s[nl];
            const unsigned ng = (unsigned)(k0 + nl);
            #pragma unroll
            for (int tile = 0; tile < 2; ++tile) {
                f32x4 acc = {0.0f, 0.0f, 0.0f, 0.0f};
                acc = __builtin_amdgcn_mfma_f32_16x16x32_bf16(alo[tile], b0, acc, 0, 0, 0);
                acc = __builtin_amdgcn_mfma_f32_16x16x32_bf16(ahi[tile], b1, acc, 0, 0, 0);
                #pragma unroll
                for (int rg = 0; rg < 4; ++rg) {
                    float sc = fmaf(acc[rg], -2.0f, en1);
                    unsigned kk2 = (__float_as_uint(sc) & 0xFFFFFE00u) | ng;
                    key[tile][rg] = min(key[tile][rg], kk2);
                }
            }
        }
    }

    #pragma unroll
    for (int m = 1; m < 16; m <<= 1) {
        #pragma unroll
        for (int tile = 0; tile < 2; ++tile)
            #pragma unroll
            for (int rg = 0; rg < 4; ++rg) {
                unsigned o = (unsigned)__shfl_xor((int)key[tile][rg], m, 64);
                key[tile][rg] = min(key[tile][rg], o);
            }
    }
    if (l16 == 0) {
        #pragma unroll
        for (int tile = 0; tile < 2; ++tile)
            #pragma unroll
            for (int rg = 0; rg < 4; ++rg)
                bestk_s[wv * 32 + tile * 16 + q * 4 + rg] = (int)(key[tile][rg] & 511u);
    }
    __syncthreads();

    const int pos = tid >> 1, seg = tid & 1;
    const int p = blockIdx.x * 128 + pos;
    const int k = bestk_s[pos];
    const u16* ep = Ebf + (size_t)k * 64 + seg * 32;
    const u16* zp = Ze + (size_t)p * 64 + seg * 32;
    u16* qp = Zq + (size_t)p * 64 + seg * 32;
    float local = 0.0f;
    #pragma unroll
    for (int h = 0; h < 4; ++h) {
        uint4 ev = *(const uint4*)(ep + h * 8);
        uint4 zv = *(const uint4*)(zp + h * 8);
        *(uint4*)(qp + h * 8) = ev;
        unsigned ea[4] = {ev.x, ev.y, ev.z, ev.w};
        unsigned za[4] = {zv.x, zv.y, zv.z, zv.w};
        #pragma unroll
        for (int j = 0; j < 4; ++j) {
            float d0 = bf2f((u16)(ea[j] & 0xFFFFu)) - bf2f((u16)(za[j] & 0xFFFFu));
            float d1 = bf2f((u16)(ea[j] >> 16))     - bf2f((u16)(za[j] >> 16));
            local = fmaf(d0, d0, fmaf(d1, d1, local));
        }
    }
    if (seg == 0) idx_out[p] = (u16)k;
    red[tid] = local;
    __syncthreads();
    for (int s = 128; s > 0; s >>= 1) {
        if (tid < s) red[tid] += red[tid + s];
        __syncthreads();
    }
    if (tid == 0) atomicAdd(sse, red[0]);
}

// ---------------- histogram by scan: block k counts code k ----------------
__global__ __launch_bounds__(256)
void hist_k(const u16* __restrict__ idx, float* __restrict__ counts)
{
    __shared__ int red[256];
    const int k = blockIdx.x;
    const int tid = threadIdx.x;
    int c = 0;
    const uint4* p4 = (const uint4*)idx;
    for (int i = tid; i < 8192; i += 256) {
        uint4 v = p4[i];
        unsigned ua[4] = {v.x, v.y, v.z, v.w};
        #pragma unroll
        for (int j = 0; j < 4; ++j) {
            c += ((ua[j] & 0xFFFFu) == (unsigned)k);
            c += ((ua[j] >> 16)     == (unsigned)k);
        }
    }
    red[tid] = c;
    __syncthreads();
    for (int s = 128; s > 0; s >>= 1) {
        if (tid < s) red[tid] += red[tid + s];
        __syncthreads();
    }
    if (tid == 0) counts[k] = (float)red[0];
}

// ---------------- merged prep: all weight transforms + eprep + sse zero ------
__device__ __forceinline__ void wconv_tf(const float* __restrict__ w,
                                         u16* __restrict__ o,
                                         int COUT, int CIN, int KK, int i)
{
    int ci = i % CIN; int t = i / CIN; int co = t % COUT; t /= COUT;
    o[i] = f2bf(w[(co*CIN + ci)*KK + t]);
}

__global__ __launch_bounds__(256)
void prep_k(const float* __restrict__ enc_w1, const float* __restrict__ enc_w2,
            const float* __restrict__ enc_w3, const float* __restrict__ enc_w4,
            const float* __restrict__ enc_res_w1, const float* __restrict__ enc_res_w2,
            const float* __restrict__ dec_res_w1, const float* __restrict__ dec_res_w2,
            const float* __restrict__ enc_adj_w, const float* __restrict__ dec_adj_w,
            const float* __restrict__ tc1_w, const float* __restrict__ tc2_w,
            const float* __restrict__ E,
            u16* __restrict__ wc1b, u16* __restrict__ wc2, u16* __restrict__ wc3,
            u16* __restrict__ wc4, u16* __restrict__ wer1, u16* __restrict__ wer2,
            u16* __restrict__ wdr1, u16* __restrict__ wdr2, u16* __restrict__ weadj,
            u16* __restrict__ wdadj, u16* __restrict__ wtc1, u16* __restrict__ wtc2b,
            u16* __restrict__ Ebf, float* __restrict__ enorm1, float* __restrict__ sse)
{
    const int b = blockIdx.x, tid = threadIdx.x;
    if (b < 512) {                      // wc2: 131072, (128,64,16)
        wconv_tf(enc_w2, wc2, 128, 64, 16, b * 256 + tid);
    } else if (b < 1088) {              // wc3: 147456, (128,128,9)
        wconv_tf(enc_w3, wc3, 128, 128, 9, (b - 512) * 256 + tid);
    } else if (b < 1664) {              // wc4
        wconv_tf(enc_w4, wc4, 128, 128, 9, (b - 1088) * 256 + tid);
    } else if (b < 2240) {              // er1: 2 x 73728, (64,128,9)
        int i = (b - 1664) * 256 + tid;
        int sub = i / 73728, rem = i - sub * 73728;
        wconv_tf(enc_res_w1 + sub * 73728, wer1 + sub * 73728, 64, 128, 9, rem);
    } else if (b < 2816) {              // dr1
        int i = (b - 2240) * 256 + tid;
        int sub = i / 73728, rem = i - sub * 73728;
        wconv_tf(dec_res_w1 + sub * 73728, wdr1 + sub * 73728, 64, 128, 9, rem);
    } else if (b < 2880) {              // er2: 2 x 8192, (128,64,1)
        int i = (b - 2816) * 256 + tid;
        int sub = i >> 13, rem = i & 8191;
        wconv_tf(enc_res_w2 + sub * 8192, wer2 + sub * 8192, 128, 64, 1, rem);
    } else if (b < 2944) {              // dr2
        int i = (b - 2880) * 256 + tid;
        int sub = i >> 13, rem = i & 8191;
        wconv_tf(dec_res_w2 + sub * 8192, wdr2 + sub * 8192, 128, 64, 1, rem);
    } else if (b < 2976) {              // eadj: 8192, (64,128,1)
        wconv_tf(enc_adj_w, weadj, 64, 128, 1, (b - 2944) * 256 + tid);
    } else if (b < 3264) {              // dadj: 73728, (128,64,9)
        wconv_tf(dec_adj_w, wdadj, 128, 64, 9, (b - 2976) * 256 + tid);
    } else if (b < 3776) {              // tc1: 131072
        int i = (b - 3264) * 256 + tid;
        int ci = i & 127; int co = (i >> 7) & 63; int t = (i >> 13) & 3; int p = i >> 15;
        int poh = p >> 1, pw = p & 1; int a = t >> 1, bb = t & 1;
        int kh = poh ? (a ? 2 : 0) : (a ? 3 : 1);
        int kw = pw  ? (bb ? 2 : 0) : (bb ? 3 : 1);
        wtc1[i] = f2bf(tc1_w[((ci*64 + co)*4 + kh)*4 + kw]);
    } else if (b < 3812) {              // tc2b: 9216 zero-padded parity weights
        int i = (b - 3776) * 256 + tid;
        int ci = i & 63; int col = (i >> 6) & 15; int t = i >> 10;
        int dh = t / 3 - 1, dw = t % 3 - 1;
        int pp = col >> 2, co = col & 3;
        float v = 0.0f;
        if (co < 3) {
            int poh = pp >> 1, pw = pp & 1;
            int kh = poh ? (dh == 1 ? 0 : (dh == 0 ? 2 : -1))
                         : (dh == 0 ? 1 : (dh == -1 ? 3 : -1));
            int kw = pw  ? (dw == 1 ? 0 : (dw == 0 ? 2 : -1))
                         : (dw == 0 ? 1 : (dw == -1 ? 3 : -1));
            if (kh >= 0 && kw >= 0)
                v = tc2_w[((ci*3 + co)*4 + kh)*4 + kw];
        }
        wtc2b[i] = f2bf(v);
    } else if (b < 3814) {              // eprep: 512 codes
        int k = (b - 3812) * 256 + tid;
        float s = 0.0f;
        #pragma unroll
        for (int d = 0; d < 64; ++d) {
            u16 h = f2bf(E[k*64 + d]);
            Ebf[k*64 + d] = h;
            float v = bf2f(h);
            s = fmaf(v, v, s);
        }
        enorm1[k] = s + 1.0f;
    } else if (b < 3830) {              // wc1b: 4096 = 64co x 64k (48 real)
        int i = (b - 3814) * 256 + tid;
        int co = i >> 6, k = i & 63;
        float v = 0.0f;
        if (k < 48) {
            int ci = k >> 4, kh = (k >> 2) & 3, kw = k & 3;
            v = enc_w1[((co*3 + ci)*4 + kh)*4 + kw];
        }
        wc1b[i] = f2bf(v);
    } else {                            // sse zero
        if (tid == 0) sse[0] = 0.0f;
    }
}

// ---------------- scalars ----------------
__global__ void finalize_k(const float* __restrict__ counts, const float* __restrict__ sse,
                           float* __restrict__ out_head, float* __restrict__ out_tail)
{
    __shared__ float red[512];
    int t = threadIdx.x;
    float pr = counts[t] / 65536.0f;
    red[t] = -pr * log2f(pr + 1e-10f);
    __syncthreads();
    for (int s = 256; s > 0; s >>= 1) {
        if (t < s) red[t] += red[t + s];
        __syncthreads();
    }
    if (t == 0) {
        float entropy = red[0];
        float mse = sse[0] / 4194304.0f;
        out_head[0] = 1.25f * mse;
        out_tail[0] = mse;
        out_tail[1] = mse;
        out_tail[2] = exp2f(entropy);
    }
}

// ---------------------------------------------------------------------------
extern "C" void kernel_launch(void* const* d_in, const int* in_sizes, int n_in,
                              void* d_out, int out_size, void* d_ws, size_t ws_size,
                              hipStream_t stream)
{
    const float* x         = (const float*)d_in[0];
    const float* enc_w1    = (const float*)d_in[1];
    const float* enc_b1    = (const float*)d_in[2];
    const float* enc_w2    = (const float*)d_in[3];
    const float* enc_b2    = (const float*)d_in[4];
    const float* enc_w3    = (const float*)d_in[5];
    const float* enc_b3    = (const float*)d_in[6];
    const float* enc_w4    = (const float*)d_in[7];
    const float* enc_b4    = (const float*)d_in[8];
    const float* enc_res_w1= (const float*)d_in[9];
    const float* enc_res_w2= (const float*)d_in[10];
    const float* enc_adj_w = (const float*)d_in[11];
    const float* enc_adj_b = (const float*)d_in[12];
    const float* Ecb       = (const float*)d_in[13];
    const float* dec_adj_w = (const float*)d_in[14];
    const float* dec_adj_b = (const float*)d_in[15];
    const float* dec_res_w1= (const float*)d_in[16];
    const float* dec_res_w2= (const float*)d_in[17];
    const float* tc1_w     = (const float*)d_in[18];
    const float* tc1_b     = (const float*)d_in[19];
    const float* tc2_w     = (const float*)d_in[20];
    const float* tc2_b     = (const float*)d_in[21];

    char* wsb = (char*)d_ws;
    u16*   wc2   = (u16*)(wsb + 0);
    u16*   wc3   = (u16*)(wsb + 262144);
    u16*   wc4   = (u16*)(wsb + 557056);
    u16*   wer1  = (u16*)(wsb + 851968);
    u16*   wer2  = (u16*)(wsb + 1146880);
    u16*   weadj = (u16*)(wsb + 1179648);
    u16*   wdadj = (u16*)(wsb + 1196032);
    u16*   wdr1  = (u16*)(wsb + 1343488);
    u16*   wdr2  = (u16*)(wsb + 1638400);
    u16*   wtc1  = (u16*)(wsb + 1671168);
    u16*   wtc2b = (u16*)(wsb + 1933312);
    float* counts= (float*)(wsb + 1951744);
    float* sse   = counts + 512;
    u16*   Ebf   = (u16*)(wsb + 1955840);
    float* enorm1= (float*)(wsb + 2021376);
    u16*   wc1b  = (u16*)(wsb + 2023424);   // 8KB, ends 2031616 < 2097152
    u16*   H1    = (u16*)(wsb + 2097152);
    u16*   TR    = (u16*)(wsb + 35651584);
    u16*   H3    = (u16*)(wsb + 52428800);
    u16*   MID   = (u16*)(wsb + 69206016);
    u16*   ZE    = (u16*)(wsb + 77594624);
    u16*   ZQ    = (u16*)(wsb + 85983232);
    u16*   IDX   = (u16*)(wsb + 94371840);
    u16*   TC1O  = H1;

    float* out  = (float*)d_out;
    float* xrec = out + 1;
    float* tail = out + 1 + 3145728;

    Taps t3x3; t3x3.s = 1; t3x3.ntaps = 9;
    for (int kh = 0; kh < 3; ++kh) for (int kw = 0; kw < 3; ++kw) {
        t3x3.dh[kh*3+kw] = kh - 1; t3x3.dw[kh*3+kw] = kw - 1;
    }
    Taps t1x1; t1x1.s = 1; t1x1.ntaps = 1; t1x1.dh[0] = 0; t1x1.dw[0] = 0;
    Taps t4x4; t4x4.s = 2; t4x4.ntaps = 16;
    for (int kh = 0; kh < 4; ++kh) for (int kw = 0; kw < 4; ++kw) {
        t4x4.dh[kh*4+kw] = kh - 1; t4x4.dw[kh*4+kw] = kw - 1;
    }
    const int dtab[2][2] = {{0, -1}, {1, 0}};
    Taps ttc1[4];
    for (int p = 0; p < 4; ++p) {
        ttc1[p].s = 1; ttc1[p].ntaps = 4;
        for (int a = 0; a < 2; ++a) for (int bb = 0; bb < 2; ++bb) {
            ttc1[p].dh[a*2+bb] = dtab[p>>1][a];
            ttc1[p].dw[a*2+bb] = dtab[p&1][bb];
        }
    }

    // ---- single merged prep dispatch ----
    prep_k<<<3831, 256, 0, stream>>>(enc_w1, enc_w2, enc_w3, enc_w4,
        enc_res_w1, enc_res_w2, dec_res_w1, dec_res_w2, enc_adj_w, dec_adj_w,
        tc1_w, tc2_w, Ecb, wc1b, wc2, wc3, wc4, wer1, wer2, wdr1, wdr2,
        weadj, wdadj, wtc1, wtc2b, Ebf, enorm1, sse);

    // ---- encoder ----
    conv1_mfma_k<<<2048, 256, 0, stream>>>(x, wc1b, enc_b1, H1);
    mfma_conv_k<64,128,false,true,true,false><<<dim3(512,2), 256, 0, stream>>>
        (H1, wc2, enc_b2, TR, 64, 64, 32, 32, 1, 0, 0, t4x4);
    mfma_conv_k<128,128,false,true,true,false><<<dim3(512,2), 256, 0, stream>>>
        (TR, wc3, enc_b3, H3, 32, 32, 32, 32, 1, 0, 0, t3x3);
    mfma_conv_k<128,128,false,false,true,false><<<dim3(512,2), 256, 0, stream>>>
        (H3, wc4, enc_b4, TR, 32, 32, 32, 32, 1, 0, 0, t3x3);
    for (int i = 0; i < 2; ++i) {
        mfma_conv_k<128,64,true,false,false,false><<<dim3(512,1), 256, 0, stream>>>
            (TR, wer1 + i*73728, nullptr, MID, 32, 32, 32, 32, 1, 0, 0, t3x3);
        mfma_conv_k<64,128,true,false,false,true><<<dim3(512,2), 256, 0, stream>>>
            (MID, wer2 + i*8192, nullptr, TR, 32, 32, 32, 32, 1, 0, 0, t1x1);
    }
    mfma_conv_k<128,64,true,false,true,false><<<dim3(512,1), 256, 0, stream>>>
        (TR, weadj, enc_adj_b, ZE, 32, 32, 32, 32, 1, 0, 0, t1x1);

    // ---- VQ ----
    vq_mfma_k<<<512, 256, 0, stream>>>(ZE, Ebf, enorm1, ZQ, IDX, sse);
    hist_k<<<512, 256, 0, stream>>>(IDX, counts);

    // ---- decoder ----
    mfma_conv_k<64,128,false,false,true,false><<<dim3(512,2), 256, 0, stream>>>
        (ZQ, wdadj, dec_adj_b, H3, 32, 32, 32, 32, 1, 0, 0, t3x3);
    for (int i = 0; i < 2; ++i) {
        mfma_conv_k<128,64,true,false,false,false><<<dim3(512,1), 256, 0, stream>>>
            (H3, wdr1 + i*73728, nullptr, MID, 32, 32, 32, 32, 1, 0, 0, t3x3);
        mfma_conv_k<64,128,true,false,false,true><<<dim3(512,2), 256, 0, stream>>>
            (MID, wdr2 + i*8192, nullptr, H3, 32, 32, 32, 32, 1, 0, 0, t1x1);
    }
    for (int p = 0; p < 4; ++p) {
        mfma_conv_k<128,64,true,true,true,false><<<dim3(512,1), 256, 0, stream>>>
            (H3, wtc1 + p*32768, tc1_b, TC1O, 32, 32, 64, 64, 2, p>>1, p&1, ttc1[p]);
    }
    tc2_mfma_k<<<2048, 256, 0, stream>>>(TC1O, wtc2b, tc2_b, xrec);

    // ---- scalars ----
    finalize_k<<<1, 512, 0, stream>>>(counts, sse, out, tail);
}

// Round 12
// 463.497 us; speedup vs baseline: 1.5507x; 1.1307x over previous
//
#include <hip/hip_runtime.h>
#include <math.h>

// ---------------------------------------------------------------------------
// VQ-VAE forward: NHWC bf16 trunk, implicit-GEMM MFMA convs (fp32 accum,
// BK=32/LDA=40, register-prefetch K-loop, COUT-split grid.y, PAR4 merged
// tc1), fused res blocks (3x3 -> relu -> 1x1 + resid in one kernel, mid kept
// in LDS), MFMA im2col conv1, LDS-staged packed-key MFMA VQ, MFMA tc2,
// single merged prep dispatch.
//
// Workspace layout (bytes):
//   [0 .. ~2.1MB)   transformed weights + counts/sse + Ebf + enorm1 + wc1b
//   H1  = 2097152   (64,64,64,64)  NHWC bf16  33.5MB   h1, later tc1 out
//   TR  = 35651584  (64,32,32,128) NHWC bf16  16.8MB   trunk ping
//   H3  = 52428800  (64,32,32,128) NHWC bf16  16.8MB   trunk pong
//   ZE  = 77594624  (64,32,32,64)  NHWC bf16   8.4MB
//   ZQ  = 85983232  (64,32,32,64)  NHWC bf16   8.4MB
//   IDX = 94371840  65536 u16      128KB
// ---------------------------------------------------------------------------

typedef unsigned short u16;
typedef __attribute__((ext_vector_type(8))) short bf16x8;
typedef __attribute__((ext_vector_type(4))) float f32x4;

__device__ __forceinline__ float bf2f(u16 h) {
    union { unsigned u; float f; } v; v.u = ((unsigned)h) << 16; return v.f;
}
__device__ __forceinline__ u16 f2bf(float f) {
    union { float f; unsigned u; } v; v.f = f;
    unsigned r = v.u + 0x7FFFu + ((v.u >> 16) & 1u);
    return (u16)(r >> 16);
}
__device__ __forceinline__ unsigned relu2(unsigned x) {
    return x & ~(((x & 0x80008000u) >> 15) * 0xFFFFu);
}

struct Taps { int s; int ntaps; int dh[16]; int dw[16]; };

// ---------------- unified implicit-GEMM MFMA conv ----------------
// BK=32/LDA=40 (r8: BK=64/LDA=72 regressed). Register prefetch (r10 win).
// grid.y = COUT/64 col split (r11 win). PAR4: blockIdx.z selects transpose-
// conv parity (tap table offset pz*4, weight offset pz*4*COUT*CIN, output
// phase (pz>>1, pz&1)) — merges tc1's 4 sequential dispatches into one.
template<int CIN, int COUT, bool RELU_IN, bool RELU_OUT, bool HAS_BIAS,
         bool RESID, bool PAR4>
__global__ __launch_bounds__(256)
void mfma_conv_k(const u16* __restrict__ in, const u16* __restrict__ wT,
                 const float* __restrict__ bias, u16* __restrict__ out,
                 int Hin, int Win, int Hout, int Wout, int OS, int OPH, int OPW,
                 Taps taps)
{
    constexpr int TM = 2, TN = 4;
    constexpr int LDA = 40;      // 32 data + 8 pad
    constexpr int NCH = CIN / 32;

    __shared__ alignas(16) u16 aT[128 * LDA];
    __shared__ alignas(16) u16 bT[64 * LDA];

    const int tid = threadIdx.x;
    const int m0 = blockIdx.x * 128;
    const int colbase = blockIdx.y << 6;
    const int pz = PAR4 ? blockIdx.z : 0;
    const int tapo = PAR4 ? pz * 4 : 0;
    const u16* wTb = PAR4 ? wT + (size_t)pz * 4 * COUT * CIN : wT;
    const int oph = PAR4 ? (pz >> 1) : OPH;
    const int opw = PAR4 ? (pz & 1) : OPW;
    const int n_img = m0 >> 10;
    const int pixbase = m0 & 1023;

    const int r = tid >> 1, half = tid & 1;
    const int pr = pixbase + r;
    const int ohr = pr >> 5, owr = pr & 31;
    const u16* inb = in + (size_t)n_img * Hin * Win * CIN;

    const int wv = tid >> 6, lane = tid & 63;
    const int q = lane >> 4, l16 = lane & 15;
    const int mbase = wv * 32;
    const bool bload = r < 64;

    f32x4 acc[TM][TN] = {};

    const int total_it = taps.ntaps * NCH;
    uint4 pa0, pa1, pb0 = {0,0,0,0}, pb1 = {0,0,0,0};

#define LOAD_IT(IT) do {                                                        \
        int t_ = (IT) / NCH, cc_ = ((IT) % NCH) * 32;                           \
        int ih_ = ohr * taps.s + taps.dh[tapo + t_];                            \
        int iw_ = owr * taps.s + taps.dw[tapo + t_];                            \
        bool ok_ = ((unsigned)ih_ < (unsigned)Hin) &&                           \
                   ((unsigned)iw_ < (unsigned)Win);                             \
        pa0 = (uint4){0,0,0,0}; pa1 = (uint4){0,0,0,0};                         \
        if (ok_) {                                                              \
            const u16* as_ = inb + ((size_t)ih_ * Win + iw_) * CIN              \
                             + half * 16 + cc_;                                 \
            pa0 = *(const uint4*)(as_);                                         \
            pa1 = *(const uint4*)(as_ + 8);                                     \
        }                                                                       \
        if (bload) {                                                            \
            const u16* bs_ = wTb + ((size_t)t_ * COUT + colbase + r) * CIN      \
                             + half * 16 + cc_;                                 \
            pb0 = *(const uint4*)(bs_);                                         \
            pb1 = *(const uint4*)(bs_ + 8);                                     \
        }                                                                       \
    } while (0)

    LOAD_IT(0);

    for (int it = 0; it < total_it; ++it) {
        __syncthreads();
        uint4 a0 = pa0, a1 = pa1;
        if (RELU_IN) {
            a0.x = relu2(a0.x); a0.y = relu2(a0.y); a0.z = relu2(a0.z); a0.w = relu2(a0.w);
            a1.x = relu2(a1.x); a1.y = relu2(a1.y); a1.z = relu2(a1.z); a1.w = relu2(a1.w);
        }
        *(uint4*)&aT[r * LDA + half * 16]     = a0;
        *(uint4*)&aT[r * LDA + half * 16 + 8] = a1;
        if (bload) {
            *(uint4*)&bT[r * LDA + half * 16]     = pb0;
            *(uint4*)&bT[r * LDA + half * 16 + 8] = pb1;
        }
        __syncthreads();
        if (it + 1 < total_it) LOAD_IT(it + 1);   // prefetch overlaps MFMAs

        bf16x8 afr[TM], bfr[TN];
        #pragma unroll
        for (int tm = 0; tm < TM; ++tm)
            afr[tm] = *(const bf16x8*)&aT[(mbase + tm*16 + l16) * LDA + q * 8];
        #pragma unroll
        for (int tn = 0; tn < TN; ++tn)
            bfr[tn] = *(const bf16x8*)&bT[(tn*16 + l16) * LDA + q * 8];
        #pragma unroll
        for (int tm = 0; tm < TM; ++tm)
            #pragma unroll
            for (int tn = 0; tn < TN; ++tn)
                acc[tm][tn] = __builtin_amdgcn_mfma_f32_16x16x32_bf16(
                    afr[tm], bfr[tn], acc[tm][tn], 0, 0, 0);
    }
#undef LOAD_IT

    #pragma unroll
    for (int tm = 0; tm < TM; ++tm) {
        #pragma unroll
        for (int tn = 0; tn < TN; ++tn) {
            const int col = colbase + tn*16 + l16;
            const float bv = HAS_BIAS ? bias[col] : 0.0f;
            #pragma unroll
            for (int rg = 0; rg < 4; ++rg) {
                const int m = mbase + tm*16 + q*4 + rg;
                const int pix = pixbase + m;
                const int oh = pix >> 5, ow = pix & 31;
                size_t oidx = (((size_t)n_img * Hout + (oh*OS + oph)) * Wout
                               + (ow*OS + opw)) * COUT + col;
                float v = acc[tm][tn][rg] + bv;
                if (RESID) v += bf2f(out[oidx]);
                if (RELU_OUT) v = fmaxf(v, 0.0f);
                out[oidx] = f2bf(v);
            }
        }
    }
}

// ---------------- fused residual block ----------------
// out = in + conv1x1(relu(conv3x3(relu(in))));  in/out distinct (halo race).
// Phase 1: standard 128px x 64mid implicit GEMM (36 iters, prefetch).
// Phase 2: mid (relu'd) kept in LDS, w2 (128co x 64k) staged once at start
// into a disjoint LDS region; 32 MFMAs/wave; residual from `in`.
__global__ __launch_bounds__(256)
void res_fused_k(const u16* __restrict__ in, const u16* __restrict__ w1,
                 const u16* __restrict__ w2, u16* __restrict__ out)
{
    constexpr int LDA = 40;
    __shared__ alignas(16) u16 smem[20480];   // 40KB
    u16* aT   = smem;            // 128*40 (phase1 A) / phase2 mT0
    u16* bT   = smem + 5120;     // 64*40  (phase1 B)
    u16* mT0  = smem;            // 128*40 mid k0..31
    u16* mT1  = smem + 5120;     // 128*40 mid k32..63
    u16* b2T0 = smem + 10240;    // 128*40 w2 k0..31
    u16* b2T1 = smem + 15360;    // 128*40 w2 k32..63

    const int tid = threadIdx.x;
    const int m0 = blockIdx.x * 128;
    const int n_img = m0 >> 10;
    const int pixbase = m0 & 1023;

    const int r = tid >> 1, half = tid & 1;
    const int pr = pixbase + r;
    const int ohr = pr >> 5, owr = pr & 31;
    const u16* inb = in + (size_t)n_img * 1024 * 128;

    const int wv = tid >> 6, lane = tid & 63;
    const int q = lane >> 4, l16 = lane & 15;
    const int mbase = wv * 32;
    const bool bload = r < 64;

    // stage w2 once (region disjoint from phase-1 tiles)
    {
        const u16* s = w2 + r * 64 + half * 32;
        u16* d = (half ? b2T1 : b2T0) + r * LDA;
        *(uint4*)(d)      = *(const uint4*)(s);
        *(uint4*)(d + 8)  = *(const uint4*)(s + 8);
        *(uint4*)(d + 16) = *(const uint4*)(s + 16);
        *(uint4*)(d + 24) = *(const uint4*)(s + 24);
    }

    f32x4 acc[2][4] = {};
    uint4 pa0, pa1, pb0 = {0,0,0,0}, pb1 = {0,0,0,0};

#define RLOAD(IT) do {                                                          \
        int t_ = (IT) >> 2, cc_ = ((IT) & 3) * 32;                              \
        int ih_ = ohr + t_/3 - 1, iw_ = owr + t_%3 - 1;                         \
        bool ok_ = ((unsigned)ih_ < 32u) && ((unsigned)iw_ < 32u);              \
        pa0 = (uint4){0,0,0,0}; pa1 = (uint4){0,0,0,0};                         \
        if (ok_) {                                                              \
            const u16* as_ = inb + ((size_t)ih_ * 32 + iw_) * 128               \
                             + half * 16 + cc_;                                 \
            pa0 = *(const uint4*)(as_);                                         \
            pa1 = *(const uint4*)(as_ + 8);                                     \
        }                                                                       \
        if (bload) {                                                            \
            const u16* bs_ = w1 + ((size_t)t_ * 64 + r) * 128                   \
                             + half * 16 + cc_;                                 \
            pb0 = *(const uint4*)(bs_);                                         \
            pb1 = *(const uint4*)(bs_ + 8);                                     \
        }                                                                       \
    } while (0)

    RLOAD(0);
    for (int it = 0; it < 36; ++it) {
        __syncthreads();
        uint4 a0 = pa0, a1 = pa1;
        a0.x = relu2(a0.x); a0.y = relu2(a0.y); a0.z = relu2(a0.z); a0.w = relu2(a0.w);
        a1.x = relu2(a1.x); a1.y = relu2(a1.y); a1.z = relu2(a1.z); a1.w = relu2(a1.w);
        *(uint4*)&aT[r * LDA + half * 16]     = a0;
        *(uint4*)&aT[r * LDA + half * 16 + 8] = a1;
        if (bload) {
            *(uint4*)&bT[r * LDA + half * 16]     = pb0;
            *(uint4*)&bT[r * LDA + half * 16 + 8] = pb1;
        }
        __syncthreads();
        if (it + 1 < 36) RLOAD(it + 1);

        bf16x8 afr[2], bfr[4];
        #pragma unroll
        for (int tm = 0; tm < 2; ++tm)
            afr[tm] = *(const bf16x8*)&aT[(mbase + tm*16 + l16) * LDA + q * 8];
        #pragma unroll
        for (int tn = 0; tn < 4; ++tn)
            bfr[tn] = *(const bf16x8*)&bT[(tn*16 + l16) * LDA + q * 8];
        #pragma unroll
        for (int tm = 0; tm < 2; ++tm)
            #pragma unroll
            for (int tn = 0; tn < 4; ++tn)
                acc[tm][tn] = __builtin_amdgcn_mfma_f32_16x16x32_bf16(
                    afr[tm], bfr[tn], acc[tm][tn], 0, 0, 0);
    }
#undef RLOAD

    __syncthreads();   // drain last ds_reads before overwriting aT/bT with mid

    // relu(mid) -> LDS (C layout: row=mbase+tm*16+q*4+rg, ch=tn*16+l16)
    #pragma unroll
    for (int tm = 0; tm < 2; ++tm)
        #pragma unroll
        for (int tn = 0; tn < 4; ++tn) {
            u16* dst = (tn < 2) ? mT0 : mT1;
            const int kc = (tn & 1) * 16 + l16;
            #pragma unroll
            for (int rg = 0; rg < 4; ++rg) {
                int row = mbase + tm*16 + q*4 + rg;
                dst[row * LDA + kc] = f2bf(fmaxf(acc[tm][tn][rg], 0.0f));
            }
        }
    __syncthreads();

    // phase 2: 128px x 128co, K=64
    f32x4 acc2[2][8] = {};
    #pragma unroll
    for (int kk = 0; kk < 2; ++kk) {
        const u16* mp = kk ? mT1 : mT0;
        const u16* bp = kk ? b2T1 : b2T0;
        bf16x8 af[2], bf[8];
        #pragma unroll
        for (int tm = 0; tm < 2; ++tm)
            af[tm] = *(const bf16x8*)&mp[(mbase + tm*16 + l16) * LDA + q * 8];
        #pragma unroll
        for (int tn = 0; tn < 8; ++tn)
            bf[tn] = *(const bf16x8*)&bp[(tn*16 + l16) * LDA + q * 8];
        #pragma unroll
        for (int tm = 0; tm < 2; ++tm)
            #pragma unroll
            for (int tn = 0; tn < 8; ++tn)
                acc2[tm][tn] = __builtin_amdgcn_mfma_f32_16x16x32_bf16(
                    af[tm], bf[tn], acc2[tm][tn], 0, 0, 0);
    }

    // epilogue: out = in + acc2
    #pragma unroll
    for (int tm = 0; tm < 2; ++tm)
        #pragma unroll
        for (int tn = 0; tn < 8; ++tn) {
            const int col = tn*16 + l16;
            #pragma unroll
            for (int rg = 0; rg < 4; ++rg) {
                const int m = mbase + tm*16 + q*4 + rg;
                const int pix = pixbase + m;
                size_t off = ((size_t)n_img * 1024 + pix) * 128 + col;
                out[off] = f2bf(acc2[tm][tn][rg] + bf2f(in[off]));
            }
        }
}

// ---------------- conv1 as MFMA im2col GEMM ----------------
__global__ __launch_bounds__(256)
void conv1_mfma_k(const float* __restrict__ x, const u16* __restrict__ wc1b,
                  const float* __restrict__ b, u16* __restrict__ out)
{
    __shared__ alignas(16) u16 smem[15360];
    u16* aT0 = smem;
    u16* aT1 = smem + 5120;
    u16* bT0 = smem + 10240;
    u16* bT1 = smem + 12800;

    const int tid = threadIdx.x;
    const int gbase = blockIdx.x * 128;
    const int r = tid >> 1, half = tid & 1;
    const int p = gbase + r;
    const int ow = p & 63, oh = (p >> 6) & 63, n = p >> 12;
    const float* xb = x + (size_t)n * 3 * 16384;

    {
        int row = tid >> 2, sub = tid & 3;
        *(uint4*)&bT0[row*40 + sub*8] = *(const uint4*)(wc1b + row*64 + sub*8);
        *(uint4*)&bT1[row*40 + sub*8] = *(const uint4*)(wc1b + row*64 + 32 + sub*8);
    }

    float vals[24];
    const int kb = half * 24;
    #pragma unroll
    for (int j = 0; j < 24; ++j) {
        int k = kb + j;
        int ci = k >> 4, kh = (k >> 2) & 3, kw = k & 3;
        int ih = oh*2 - 1 + kh, iw = ow*2 - 1 + kw;
        bool ok = ((unsigned)ih < 128u) && ((unsigned)iw < 128u);
        vals[j] = ok ? xb[ci*16384 + ih*128 + iw] : 0.0f;
    }
    unsigned pk[12];
    #pragma unroll
    for (int jj = 0; jj < 12; ++jj)
        pk[jj] = (unsigned)f2bf(vals[2*jj]) | ((unsigned)f2bf(vals[2*jj+1]) << 16);
    unsigned* a0row = (unsigned*)&aT0[r * 40];
    unsigned* a1row = (unsigned*)&aT1[r * 40];
    if (half == 0) {
        #pragma unroll
        for (int jj = 0; jj < 12; ++jj) a0row[jj] = pk[jj];
    } else {
        a0row[12] = pk[0]; a0row[13] = pk[1];
        a0row[14] = pk[2]; a0row[15] = pk[3];
        #pragma unroll
        for (int jj = 4; jj < 12; ++jj) a1row[jj - 4] = pk[jj];
        *(uint4*)&aT1[r*40 + 16] = (uint4){0,0,0,0};
        *(uint4*)&aT1[r*40 + 24] = (uint4){0,0,0,0};
    }
    __syncthreads();

    const int wv = tid >> 6, lane = tid & 63;
    const int q = lane >> 4, l16 = lane & 15;
    const int mbase = wv * 32;

    f32x4 acc[2][4] = {};
    bf16x8 af0[2], af1[2], bf0[4], bf1[4];
    #pragma unroll
    for (int tm = 0; tm < 2; ++tm) {
        af0[tm] = *(const bf16x8*)&aT0[(mbase + tm*16 + l16) * 40 + q * 8];
        af1[tm] = *(const bf16x8*)&aT1[(mbase + tm*16 + l16) * 40 + q * 8];
    }
    #pragma unroll
    for (int tn = 0; tn < 4; ++tn) {
        bf0[tn] = *(const bf16x8*)&bT0[(tn*16 + l16) * 40 + q * 8];
        bf1[tn] = *(const bf16x8*)&bT1[(tn*16 + l16) * 40 + q * 8];
    }
    #pragma unroll
    for (int tm = 0; tm < 2; ++tm)
        #pragma unroll
        for (int tn = 0; tn < 4; ++tn) {
            acc[tm][tn] = __builtin_amdgcn_mfma_f32_16x16x32_bf16(
                af0[tm], bf0[tn], acc[tm][tn], 0, 0, 0);
            acc[tm][tn] = __builtin_amdgcn_mfma_f32_16x16x32_bf16(
                af1[tm], bf1[tn], acc[tm][tn], 0, 0, 0);
        }

    float bv[4];
    #pragma unroll
    for (int tn = 0; tn < 4; ++tn) bv[tn] = b[tn*16 + l16];

    __syncthreads();
    u16* cbuf = smem;
    #pragma unroll
    for (int tm = 0; tm < 2; ++tm)
        #pragma unroll
        for (int tn = 0; tn < 4; ++tn)
            #pragma unroll
            for (int rg = 0; rg < 4; ++rg) {
                int row = mbase + tm*16 + q*4 + rg;
                int col = tn*16 + l16;
                cbuf[row*72 + col] = f2bf(fmaxf(acc[tm][tn][rg] + bv[tn], 0.0f));
            }
    __syncthreads();

    u16* ob = out + (size_t)gbase * 64;
    #pragma unroll
    for (int it = 0; it < 4; ++it) {
        int j = it * 256 + tid;
        uint4 v = *(const uint4*)&cbuf[(j >> 3) * 72 + (j & 7) * 8];
        *(uint4*)(ob + j * 8) = v;
    }
}

// ---------------- tc2 as MFMA parity GEMM ----------------
__global__ __launch_bounds__(256)
void tc2_mfma_k(const u16* __restrict__ in, const u16* __restrict__ wT,
                const float* __restrict__ bias, float* __restrict__ out)
{
    constexpr int LDA = 40;
    __shared__ alignas(16) u16 aT[128 * LDA];
    __shared__ alignas(16) u16 bT[16 * LDA];
    __shared__ float cT[128 * 17];

    const int tid = threadIdx.x;
    const int m0 = blockIdx.x * 128;
    const int n_img = m0 >> 12;
    const int pixbase = m0 & 4095;
    const int y0 = pixbase >> 6;

    const int r = tid >> 1, half = tid & 1;
    const int pr = pixbase + r;
    const int yr = pr >> 6, xr = pr & 63;
    const u16* inb = in + (size_t)n_img * 4096 * 64;

    const int wv = tid >> 6, lane = tid & 63;
    const int q = lane >> 4, l16 = lane & 15;
    const int mbase = wv * 32;

    f32x4 acc[2] = {};

    for (int t = 0; t < 9; ++t) {
        const int ih = yr + t/3 - 1;
        const int iw = xr + t%3 - 1;
        const bool ok = ((unsigned)ih < 64u) && ((unsigned)iw < 64u);
        const u16* asrc = ok ? (inb + ((size_t)ih * 64 + iw) * 64 + half * 16) : inb;
        const u16* bsrc = wT + ((size_t)t * 16 + r) * 64 + half * 16;

        for (int c0 = 0; c0 < 64; c0 += 32) {
            __syncthreads();
            uint4 a0 = {0,0,0,0}, a1 = {0,0,0,0};
            if (ok) {
                a0 = *(const uint4*)(asrc + c0);
                a1 = *(const uint4*)(asrc + c0 + 8);
            }
            *(uint4*)&aT[r * LDA + half * 16]     = a0;
            *(uint4*)&aT[r * LDA + half * 16 + 8] = a1;
            if (r < 16) {
                *(uint4*)&bT[r * LDA + half * 16]     = *(const uint4*)(bsrc + c0);
                *(uint4*)&bT[r * LDA + half * 16 + 8] = *(const uint4*)(bsrc + c0 + 8);
            }
            __syncthreads();

            bf16x8 af0 = *(const bf16x8*)&aT[(mbase + l16) * LDA + q * 8];
            bf16x8 af1 = *(const bf16x8*)&aT[(mbase + 16 + l16) * LDA + q * 8];
            bf16x8 bf  = *(const bf16x8*)&bT[l16 * LDA + q * 8];
            acc[0] = __builtin_amdgcn_mfma_f32_16x16x32_bf16(af0, bf, acc[0], 0, 0, 0);
            acc[1] = __builtin_amdgcn_mfma_f32_16x16x32_bf16(af1, bf, acc[1], 0, 0, 0);
        }
    }

    #pragma unroll
    for (int tm = 0; tm < 2; ++tm)
        #pragma unroll
        for (int rg = 0; rg < 4; ++rg)
            cT[(mbase + tm*16 + q*4 + rg) * 17 + l16] = acc[tm][rg];
    __syncthreads();

    #pragma unroll
    for (int it = 0; it < 6; ++it) {
        int j = it * 256 + tid;
        int co  = j >> 9;
        int rem = j & 511;
        int ohl = rem >> 7;
        int ow  = rem & 127;
        int oh  = 2*y0 + ohl;
        int lp  = (ohl >> 1) * 64 + (ow >> 1);
        int col = ((ohl & 1) * 2 + (ow & 1)) * 4 + co;
        float v = cT[lp * 17 + col] + bias[co];
        out[(((size_t)n_img * 3 + co) * 128 + oh) * 128 + ow] = v;
    }
}

// ---------------- MFMA vector quantizer ----------------
__global__ __launch_bounds__(256)
void vq_mfma_k(const u16* __restrict__ Ze, const u16* __restrict__ Ebf,
               const float* __restrict__ enorm1, u16* __restrict__ Zq,
               u16* __restrict__ idx_out, float* __restrict__ sse)
{
    __shared__ alignas(16) u16 eld[256 * 72];
    __shared__ float en1s[256];
    __shared__ int bestk_s[128];
    __shared__ float red[256];

    const int tid = threadIdx.x;
    const int lane = tid & 63, wv = tid >> 6;
    const int q = lane >> 4, l16 = lane & 15;
    const int pb = blockIdx.x * 128 + wv * 32;

    bf16x8 alo[2], ahi[2];
    #pragma unroll
    for (int tile = 0; tile < 2; ++tile) {
        const u16* zp = Ze + (size_t)(pb + tile*16 + l16) * 64;
        alo[tile] = *(const bf16x8*)(zp + q * 8);
        ahi[tile] = *(const bf16x8*)(zp + 32 + q * 8);
    }

    unsigned key[2][4] = {{0xFFFFFFFFu,0xFFFFFFFFu,0xFFFFFFFFu,0xFFFFFFFFu},
                          {0xFFFFFFFFu,0xFFFFFFFFu,0xFFFFFFFFu,0xFFFFFFFFu}};

    for (int k0 = 0; k0 < 512; k0 += 256) {
        __syncthreads();
        const uint4* src = (const uint4*)(Ebf + k0 * 64);
        #pragma unroll
        for (int i = tid; i < 2048; i += 256) {
            int row = i >> 3, sub = i & 7;
            *(uint4*)&eld[row * 72 + sub * 8] = src[i];
        }
        en1s[tid] = enorm1[k0 + tid];
        __syncthreads();

        for (int t = 0; t < 16; ++t) {
            const int nl = t * 16 + l16;
            bf16x8 b0 = *(const bf16x8*)&eld[nl * 72 + q * 8];
            bf16x8 b1 = *(const bf16x8*)&eld[nl * 72 + 32 + q * 8];
            const float en1 = en1s[nl];
            const unsigned ng = (unsigned)(k0 + nl);
            #pragma unroll
            for (int tile = 0; tile < 2; ++tile) {
                f32x4 acc = {0.0f, 0.0f, 0.0f, 0.0f};
                acc = __builtin_amdgcn_mfma_f32_16x16x32_bf16(alo[tile], b0, acc, 0, 0, 0);
                acc = __builtin_amdgcn_mfma_f32_16x16x32_bf16(ahi[tile], b1, acc, 0, 0, 0);
                #pragma unroll
                for (int rg = 0; rg < 4; ++rg) {
                    float sc = fmaf(acc[rg], -2.0f, en1);
                    unsigned kk2 = (__float_as_uint(sc) & 0xFFFFFE00u) | ng;
                    key[tile][rg] = min(key[tile][rg], kk2);
                }
            }
        }
    }

    #pragma unroll
    for (int m = 1; m < 16; m <<= 1) {
        #pragma unroll
        for (int tile = 0; tile < 2; ++tile)
            #pragma unroll
            for (int rg = 0; rg < 4; ++rg) {
                unsigned o = (unsigned)__shfl_xor((int)key[tile][rg], m, 64);
                key[tile][rg] = min(key[tile][rg], o);
            }
    }
    if (l16 == 0) {
        #pragma unroll
        for (int tile = 0; tile < 2; ++tile)
            #pragma unroll
            for (int rg = 0; rg < 4; ++rg)
                bestk_s[wv * 32 + tile * 16 + q * 4 + rg] = (int)(key[tile][rg] & 511u);
    }
    __syncthreads();

    const int pos = tid >> 1, seg = tid & 1;
    const int p = blockIdx.x * 128 + pos;
    const int k = bestk_s[pos];
    const u16* ep = Ebf + (size_t)k * 64 + seg * 32;
    const u16* zp = Ze + (size_t)p * 64 + seg * 32;
    u16* qp = Zq + (size_t)p * 64 + seg * 32;
    float local = 0.0f;
    #pragma unroll
    for (int h = 0; h < 4; ++h) {
        uint4 ev = *(const uint4*)(ep + h * 8);
        uint4 zv = *(const uint4*)(zp + h * 8);
        *(uint4*)(qp + h * 8) = ev;
        unsigned ea[4] = {ev.x, ev.y, ev.z, ev.w};
        unsigned za[4] = {zv.x, zv.y, zv.z, zv.w};
        #pragma unroll
        for (int j = 0; j < 4; ++j) {
            float d0 = bf2f((u16)(ea[j] & 0xFFFFu)) - bf2f((u16)(za[j] & 0xFFFFu));
            float d1 = bf2f((u16)(ea[j] >> 16))     - bf2f((u16)(za[j] >> 16));
            local = fmaf(d0, d0, fmaf(d1, d1, local));
        }
    }
    if (seg == 0) idx_out[p] = (u16)k;
    red[tid] = local;
    __syncthreads();
    for (int s = 128; s > 0; s >>= 1) {
        if (tid < s) red[tid] += red[tid + s];
        __syncthreads();
    }
    if (tid == 0) atomicAdd(sse, red[0]);
}

// ---------------- histogram by scan ----------------
__global__ __launch_bounds__(256)
void hist_k(const u16* __restrict__ idx, float* __restrict__ counts)
{
    __shared__ int red[256];
    const int k = blockIdx.x;
    const int tid = threadIdx.x;
    int c = 0;
    const uint4* p4 = (const uint4*)idx;
    for (int i = tid; i < 8192; i += 256) {
        uint4 v = p4[i];
        unsigned ua[4] = {v.x, v.y, v.z, v.w};
        #pragma unroll
        for (int j = 0; j < 4; ++j) {
            c += ((ua[j] & 0xFFFFu) == (unsigned)k);
            c += ((ua[j] >> 16)     == (unsigned)k);
        }
    }
    red[tid] = c;
    __syncthreads();
    for (int s = 128; s > 0; s >>= 1) {
        if (tid < s) red[tid] += red[tid + s];
        __syncthreads();
    }
    if (tid == 0) counts[k] = (float)red[0];
}

// ---------------- merged prep ----------------
__device__ __forceinline__ void wconv_tf(const float* __restrict__ w,
                                         u16* __restrict__ o,
                                         int COUT, int CIN, int KK, int i)
{
    int ci = i % CIN; int t = i / CIN; int co = t % COUT; t /= COUT;
    o[i] = f2bf(w[(co*CIN + ci)*KK + t]);
}

__global__ __launch_bounds__(256)
void prep_k(const float* __restrict__ enc_w1, const float* __restrict__ enc_w2,
            const float* __restrict__ enc_w3, const float* __restrict__ enc_w4,
            const float* __restrict__ enc_res_w1, const float* __restrict__ enc_res_w2,
            const float* __restrict__ dec_res_w1, const float* __restrict__ dec_res_w2,
            const float* __restrict__ enc_adj_w, const float* __restrict__ dec_adj_w,
            const float* __restrict__ tc1_w, const float* __restrict__ tc2_w,
            const float* __restrict__ E,
            u16* __restrict__ wc1b, u16* __restrict__ wc2, u16* __restrict__ wc3,
            u16* __restrict__ wc4, u16* __restrict__ wer1, u16* __restrict__ wer2,
            u16* __restrict__ wdr1, u16* __restrict__ wdr2, u16* __restrict__ weadj,
            u16* __restrict__ wdadj, u16* __restrict__ wtc1, u16* __restrict__ wtc2b,
            u16* __restrict__ Ebf, float* __restrict__ enorm1, float* __restrict__ sse)
{
    const int b = blockIdx.x, tid = threadIdx.x;
    if (b < 512) {
        wconv_tf(enc_w2, wc2, 128, 64, 16, b * 256 + tid);
    } else if (b < 1088) {
        wconv_tf(enc_w3, wc3, 128, 128, 9, (b - 512) * 256 + tid);
    } else if (b < 1664) {
        wconv_tf(enc_w4, wc4, 128, 128, 9, (b - 1088) * 256 + tid);
    } else if (b < 2240) {
        int i = (b - 1664) * 256 + tid;
        int sub = i / 73728, rem = i - sub * 73728;
        wconv_tf(enc_res_w1 + sub * 73728, wer1 + sub * 73728, 64, 128, 9, rem);
    } else if (b < 2816) {
        int i = (b - 2240) * 256 + tid;
        int sub = i / 73728, rem = i - sub * 73728;
        wconv_tf(dec_res_w1 + sub * 73728, wdr1 + sub * 73728, 64, 128, 9, rem);
    } else if (b < 2880) {
        int i = (b - 2816) * 256 + tid;
        int sub = i >> 13, rem = i & 8191;
        wconv_tf(enc_res_w2 + sub * 8192, wer2 + sub * 8192, 128, 64, 1, rem);
    } else if (b < 2944) {
        int i = (b - 2880) * 256 + tid;
        int sub = i >> 13, rem = i & 8191;
        wconv_tf(dec_res_w2 + sub * 8192, wdr2 + sub * 8192, 128, 64, 1, rem);
    } else if (b < 2976) {
        wconv_tf(enc_adj_w, weadj, 64, 128, 1, (b - 2944) * 256 + tid);
    } else if (b < 3264) {
        wconv_tf(dec_adj_w, wdadj, 128, 64, 9, (b - 2976) * 256 + tid);
    } else if (b < 3776) {
        int i = (b - 3264) * 256 + tid;
        int ci = i & 127; int co = (i >> 7) & 63; int t = (i >> 13) & 3; int p = i >> 15;
        int poh = p >> 1, pw = p & 1; int a = t >> 1, bb = t & 1;
        int kh = poh ? (a ? 2 : 0) : (a ? 3 : 1);
        int kw = pw  ? (bb ? 2 : 0) : (bb ? 3 : 1);
        wtc1[i] = f2bf(tc1_w[((ci*64 + co)*4 + kh)*4 + kw]);
    } else if (b < 3812) {
        int i = (b - 3776) * 256 + tid;
        int ci = i & 63; int col = (i >> 6) & 15; int t = i >> 10;
        int dh = t / 3 - 1, dw = t % 3 - 1;
        int pp = col >> 2, co = col & 3;
        float v = 0.0f;
        if (co < 3) {
            int poh = pp >> 1, pw = pp & 1;
            int kh = poh ? (dh == 1 ? 0 : (dh == 0 ? 2 : -1))
                         : (dh == 0 ? 1 : (dh == -1 ? 3 : -1));
            int kw = pw  ? (dw == 1 ? 0 : (dw == 0 ? 2 : -1))
                         : (dw == 0 ? 1 : (dw == -1 ? 3 : -1));
            if (kh >= 0 && kw >= 0)
                v = tc2_w[((ci*3 + co)*4 + kh)*4 + kw];
        }
        wtc2b[i] = f2bf(v);
    } else if (b < 3814) {
        int k = (b - 3812) * 256 + tid;
        float s = 0.0f;
        #pragma unroll
        for (int d = 0; d < 64; ++d) {
            u16 h = f2bf(E[k*64 + d]);
            Ebf[k*64 + d] = h;
            float v = bf2f(h);
            s = fmaf(v, v, s);
        }
        enorm1[k] = s + 1.0f;
    } else if (b < 3830) {
        int i = (b - 3814) * 256 + tid;
        int co = i >> 6, k = i & 63;
        float v = 0.0f;
        if (k < 48) {
            int ci = k >> 4, kh = (k >> 2) & 3, kw = k & 3;
            v = enc_w1[((co*3 + ci)*4 + kh)*4 + kw];
        }
        wc1b[i] = f2bf(v);
    } else {
        if (tid == 0) sse[0] = 0.0f;
    }
}

// ---------------- scalars ----------------
__global__ void finalize_k(const float* __restrict__ counts, const float* __restrict__ sse,
                           float* __restrict__ out_head, float* __restrict__ out_tail)
{
    __shared__ float red[512];
    int t = threadIdx.x;
    float pr = counts[t] / 65536.0f;
    red[t] = -pr * log2f(pr + 1e-10f);
    __syncthreads();
    for (int s = 256; s > 0; s >>= 1) {
        if (t < s) red[t] += red[t + s];
        __syncthreads();
    }
    if (t == 0) {
        float entropy = red[0];
        float mse = sse[0] / 4194304.0f;
        out_head[0] = 1.25f * mse;
        out_tail[0] = mse;
        out_tail[1] = mse;
        out_tail[2] = exp2f(entropy);
    }
}

// ---------------------------------------------------------------------------
extern "C" void kernel_launch(void* const* d_in, const int* in_sizes, int n_in,
                              void* d_out, int out_size, void* d_ws, size_t ws_size,
                              hipStream_t stream)
{
    const float* x         = (const float*)d_in[0];
    const float* enc_w1    = (const float*)d_in[1];
    const float* enc_b1    = (const float*)d_in[2];
    const float* enc_w2    = (const float*)d_in[3];
    const float* enc_b2    = (const float*)d_in[4];
    const float* enc_w3    = (const float*)d_in[5];
    const float* enc_b3    = (const float*)d_in[6];
    const float* enc_w4    = (const float*)d_in[7];
    const float* enc_b4    = (const float*)d_in[8];
    const float* enc_res_w1= (const float*)d_in[9];
    const float* enc_res_w2= (const float*)d_in[10];
    const float* enc_adj_w = (const float*)d_in[11];
    const float* enc_adj_b = (const float*)d_in[12];
    const float* Ecb       = (const float*)d_in[13];
    const float* dec_adj_w = (const float*)d_in[14];
    const float* dec_adj_b = (const float*)d_in[15];
    const float* dec_res_w1= (const float*)d_in[16];
    const float* dec_res_w2= (const float*)d_in[17];
    const float* tc1_w     = (const float*)d_in[18];
    const float* tc1_b     = (const float*)d_in[19];
    const float* tc2_w     = (const float*)d_in[20];
    const float* tc2_b     = (const float*)d_in[21];

    char* wsb = (char*)d_ws;
    u16*   wc2   = (u16*)(wsb + 0);
    u16*   wc3   = (u16*)(wsb + 262144);
    u16*   wc4   = (u16*)(wsb + 557056);
    u16*   wer1  = (u16*)(wsb + 851968);
    u16*   wer2  = (u16*)(wsb + 1146880);
    u16*   weadj = (u16*)(wsb + 1179648);
    u16*   wdadj = (u16*)(wsb + 1196032);
    u16*   wdr1  = (u16*)(wsb + 1343488);
    u16*   wdr2  = (u16*)(wsb + 1638400);
    u16*   wtc1  = (u16*)(wsb + 1671168);
    u16*   wtc2b = (u16*)(wsb + 1933312);
    float* counts= (float*)(wsb + 1951744);
    float* sse   = counts + 512;
    u16*   Ebf   = (u16*)(wsb + 1955840);
    float* enorm1= (float*)(wsb + 2021376);
    u16*   wc1b  = (u16*)(wsb + 2023424);
    u16*   H1    = (u16*)(wsb + 2097152);
    u16*   TR    = (u16*)(wsb + 35651584);
    u16*   H3    = (u16*)(wsb + 52428800);
    u16*   ZE    = (u16*)(wsb + 77594624);
    u16*   ZQ    = (u16*)(wsb + 85983232);
    u16*   IDX   = (u16*)(wsb + 94371840);
    u16*   TC1O  = H1;

    float* out  = (float*)d_out;
    float* xrec = out + 1;
    float* tail = out + 1 + 3145728;

    Taps t3x3; t3x3.s = 1; t3x3.ntaps = 9;
    for (int kh = 0; kh < 3; ++kh) for (int kw = 0; kw < 3; ++kw) {
        t3x3.dh[kh*3+kw] = kh - 1; t3x3.dw[kh*3+kw] = kw - 1;
    }
    Taps t1x1; t1x1.s = 1; t1x1.ntaps = 1; t1x1.dh[0] = 0; t1x1.dw[0] = 0;
    Taps t4x4; t4x4.s = 2; t4x4.ntaps = 16;
    for (int kh = 0; kh < 4; ++kh) for (int kw = 0; kw < 4; ++kw) {
        t4x4.dh[kh*4+kw] = kh - 1; t4x4.dw[kh*4+kw] = kw - 1;
    }
    const int dtab[2][2] = {{0, -1}, {1, 0}};
    Taps ttc1m; ttc1m.s = 1; ttc1m.ntaps = 4;   // parity-major: dh[p*4 + a*2+b]
    for (int p = 0; p < 4; ++p)
        for (int a = 0; a < 2; ++a) for (int bb = 0; bb < 2; ++bb) {
            ttc1m.dh[p*4 + a*2 + bb] = dtab[p>>1][a];
            ttc1m.dw[p*4 + a*2 + bb] = dtab[p&1][bb];
        }

    // ---- single merged prep dispatch ----
    prep_k<<<3831, 256, 0, stream>>>(enc_w1, enc_w2, enc_w3, enc_w4,
        enc_res_w1, enc_res_w2, dec_res_w1, dec_res_w2, enc_adj_w, dec_adj_w,
        tc1_w, tc2_w, Ecb, wc1b, wc2, wc3, wc4, wer1, wer2, wdr1, wdr2,
        weadj, wdadj, wtc1, wtc2b, Ebf, enorm1, sse);

    // ---- encoder ----
    conv1_mfma_k<<<2048, 256, 0, stream>>>(x, wc1b, enc_b1, H1);
    mfma_conv_k<64,128,false,true,true,false,false><<<dim3(512,2), 256, 0, stream>>>
        (H1, wc2, enc_b2, TR, 64, 64, 32, 32, 1, 0, 0, t4x4);
    mfma_conv_k<128,128,false,true,true,false,false><<<dim3(512,2), 256, 0, stream>>>
        (TR, wc3, enc_b3, H3, 32, 32, 32, 32, 1, 0, 0, t3x3);
    mfma_conv_k<128,128,false,false,true,false,false><<<dim3(512,2), 256, 0, stream>>>
        (H3, wc4, enc_b4, TR, 32, 32, 32, 32, 1, 0, 0, t3x3);
    // fused res blocks: TR -> H3 -> TR
    res_fused_k<<<512, 256, 0, stream>>>(TR, wer1,         wer2,        H3);
    res_fused_k<<<512, 256, 0, stream>>>(H3, wer1 + 73728, wer2 + 8192, TR);
    mfma_conv_k<128,64,true,false,true,false,false><<<dim3(512,1), 256, 0, stream>>>
        (TR, weadj, enc_adj_b, ZE, 32, 32, 32, 32, 1, 0, 0, t1x1);

    // ---- VQ ----
    vq_mfma_k<<<512, 256, 0, stream>>>(ZE, Ebf, enorm1, ZQ, IDX, sse);
    hist_k<<<512, 256, 0, stream>>>(IDX, counts);

    // ---- decoder ----
    mfma_conv_k<64,128,false,false,true,false,false><<<dim3(512,2), 256, 0, stream>>>
        (ZQ, wdadj, dec_adj_b, H3, 32, 32, 32, 32, 1, 0, 0, t3x3);
    // fused res blocks: H3 -> TR -> H3
    res_fused_k<<<512, 256, 0, stream>>>(H3, wdr1,         wdr2,        TR);
    res_fused_k<<<512, 256, 0, stream>>>(TR, wdr1 + 73728, wdr2 + 8192, H3);
    // tc1: all 4 parities in one dispatch (blockIdx.z)
    mfma_conv_k<128,64,true,true,true,false,true><<<dim3(512,1,4), 256, 0, stream>>>
        (H3, wtc1, tc1_b, TC1O, 32, 32, 64, 64, 2, 0, 0, ttc1m);
    tc2_mfma_k<<<2048, 256, 0, stream>>>(TC1O, wtc2b, tc2_b, xrec);

    // ---- scalars ----
    finalize_k<<<1, 512, 0, stream>>>(counts, sse, out, tail);
}

// Round 13
// 453.858 us; speedup vs baseline: 1.5836x; 1.0212x over previous
//
#include <hip/hip_runtime.h>
#include <math.h>

// ---------------------------------------------------------------------------
// VQ-VAE forward: NHWC bf16 trunk, implicit-GEMM MFMA convs (fp32 accum,
// BK=32/LDA=40, register-prefetch K-loop, COUT-split grid.y, PAR4 merged tc1,
// inline templated tap math — no runtime-indexed kernarg arrays), fused res
// blocks, fused enc_adj+VQ (1x1 conv -> LDS relayout -> packed-key argmin,
// no ZE buffer), MFMA im2col conv1, MFMA tc2, single merged prep dispatch.
//
// Workspace layout (bytes):
//   [0 .. ~2.1MB)   transformed weights + counts/sse + Ebf + enorm1 + wc1b
//   H1  = 2097152   (64,64,64,64)  NHWC bf16  33.5MB   h1, later tc1 out
//   TR  = 35651584  (64,32,32,128) NHWC bf16  16.8MB   trunk ping
//   H3  = 52428800  (64,32,32,128) NHWC bf16  16.8MB   trunk pong
//   ZQ  = 85983232  (64,32,32,64)  NHWC bf16   8.4MB
//   IDX = 94371840  65536 u16      128KB
// ---------------------------------------------------------------------------

typedef unsigned short u16;
typedef __attribute__((ext_vector_type(8))) short bf16x8;
typedef __attribute__((ext_vector_type(4))) float f32x4;

__device__ __forceinline__ float bf2f(u16 h) {
    union { unsigned u; float f; } v; v.u = ((unsigned)h) << 16; return v.f;
}
__device__ __forceinline__ u16 f2bf(float f) {
    union { float f; unsigned u; } v; v.f = f;
    unsigned r = v.u + 0x7FFFu + ((v.u >> 16) & 1u);
    return (u16)(r >> 16);
}
__device__ __forceinline__ unsigned relu2(unsigned x) {
    return x & ~(((x & 0x80008000u) >> 15) * 0xFFFFu);
}

// ---------------- unified implicit-GEMM MFMA conv ----------------
// BK=32/LDA=40 (r8: bigger K-tile regressed). Register prefetch (r10).
// grid.y col split (r11). TAPMODE inline tap math (r13): 0=1x1, 1=3x3,
// 2=4x4 stride2, 3=PAR4 transpose-conv parity via blockIdx.z.
template<int CIN, int COUT, int TAPMODE, bool RELU_IN, bool RELU_OUT,
         bool HAS_BIAS, bool RESID>
__global__ __launch_bounds__(256)
void mfma_conv_k(const u16* __restrict__ in, const u16* __restrict__ wT,
                 const float* __restrict__ bias, u16* __restrict__ out,
                 int Hin, int Win, int Hout, int Wout, int OS)
{
    constexpr int TM = 2, TN = 4;
    constexpr int LDA = 40;
    constexpr int NCH = CIN / 32;
    constexpr int NTAPS = (TAPMODE == 0) ? 1 : (TAPMODE == 1) ? 9
                        : (TAPMODE == 2) ? 16 : 4;
    constexpr int S = (TAPMODE == 2) ? 2 : 1;

    __shared__ alignas(16) u16 aT[128 * LDA];
    __shared__ alignas(16) u16 bT[64 * LDA];

    const int tid = threadIdx.x;
    const int m0 = blockIdx.x * 128;
    const int colbase = blockIdx.y << 6;
    const int pz = (TAPMODE == 3) ? blockIdx.z : 0;
    const u16* wTb = (TAPMODE == 3) ? wT + (size_t)pz * 4 * COUT * CIN : wT;
    const int oph = (TAPMODE == 3) ? (pz >> 1) : 0;
    const int opw = (TAPMODE == 3) ? (pz & 1) : 0;
    const int n_img = m0 >> 10;
    const int pixbase = m0 & 1023;

    const int r = tid >> 1, half = tid & 1;
    const int pr = pixbase + r;
    const int ohr = pr >> 5, owr = pr & 31;
    const u16* inb = in + (size_t)n_img * Hin * Win * CIN;

    const int wv = tid >> 6, lane = tid & 63;
    const int q = lane >> 4, l16 = lane & 15;
    const int mbase = wv * 32;
    const bool bload = r < 64;

    f32x4 acc[TM][TN] = {};

    const int total_it = NTAPS * NCH;
    uint4 pa0, pa1, pb0 = {0,0,0,0}, pb1 = {0,0,0,0};

#define LOAD_IT(IT) do {                                                        \
        int t_ = (IT) / NCH, cc_ = ((IT) % NCH) * 32;                           \
        int dh_, dw_;                                                           \
        if (TAPMODE == 0)      { dh_ = 0;              dw_ = 0; }               \
        else if (TAPMODE == 1) { dh_ = t_/3 - 1;       dw_ = t_%3 - 1; }        \
        else if (TAPMODE == 2) { dh_ = (t_>>2) - 1;    dw_ = (t_&3) - 1; }      \
        else                   { dh_ = (pz>>1) - (t_>>1); dw_ = (pz&1) - (t_&1); } \
        int ih_ = ohr * S + dh_;                                                \
        int iw_ = owr * S + dw_;                                                \
        bool ok_ = ((unsigned)ih_ < (unsigned)Hin) &&                           \
                   ((unsigned)iw_ < (unsigned)Win);                             \
        pa0 = (uint4){0,0,0,0}; pa1 = (uint4){0,0,0,0};                         \
        if (ok_) {                                                              \
            const u16* as_ = inb + ((size_t)ih_ * Win + iw_) * CIN              \
                             + half * 16 + cc_;                                 \
            pa0 = *(const uint4*)(as_);                                         \
            pa1 = *(const uint4*)(as_ + 8);                                     \
        }                                                                       \
        if (bload) {                                                            \
            const u16* bs_ = wTb + ((size_t)t_ * COUT + colbase + r) * CIN      \
                             + half * 16 + cc_;                                 \
            pb0 = *(const uint4*)(bs_);                                         \
            pb1 = *(const uint4*)(bs_ + 8);                                     \
        }                                                                       \
    } while (0)

    LOAD_IT(0);

    for (int it = 0; it < total_it; ++it) {
        __syncthreads();
        uint4 a0 = pa0, a1 = pa1;
        if (RELU_IN) {
            a0.x = relu2(a0.x); a0.y = relu2(a0.y); a0.z = relu2(a0.z); a0.w = relu2(a0.w);
            a1.x = relu2(a1.x); a1.y = relu2(a1.y); a1.z = relu2(a1.z); a1.w = relu2(a1.w);
        }
        *(uint4*)&aT[r * LDA + half * 16]     = a0;
        *(uint4*)&aT[r * LDA + half * 16 + 8] = a1;
        if (bload) {
            *(uint4*)&bT[r * LDA + half * 16]     = pb0;
            *(uint4*)&bT[r * LDA + half * 16 + 8] = pb1;
        }
        __syncthreads();
        if (it + 1 < total_it) LOAD_IT(it + 1);   // prefetch overlaps MFMAs

        bf16x8 afr[TM], bfr[TN];
        #pragma unroll
        for (int tm = 0; tm < TM; ++tm)
            afr[tm] = *(const bf16x8*)&aT[(mbase + tm*16 + l16) * LDA + q * 8];
        #pragma unroll
        for (int tn = 0; tn < TN; ++tn)
            bfr[tn] = *(const bf16x8*)&bT[(tn*16 + l16) * LDA + q * 8];
        #pragma unroll
        for (int tm = 0; tm < TM; ++tm)
            #pragma unroll
            for (int tn = 0; tn < TN; ++tn)
                acc[tm][tn] = __builtin_amdgcn_mfma_f32_16x16x32_bf16(
                    afr[tm], bfr[tn], acc[tm][tn], 0, 0, 0);
    }
#undef LOAD_IT

    #pragma unroll
    for (int tm = 0; tm < TM; ++tm) {
        #pragma unroll
        for (int tn = 0; tn < TN; ++tn) {
            const int col = colbase + tn*16 + l16;
            const float bv = HAS_BIAS ? bias[col] : 0.0f;
            #pragma unroll
            for (int rg = 0; rg < 4; ++rg) {
                const int m = mbase + tm*16 + q*4 + rg;
                const int pix = pixbase + m;
                const int oh = pix >> 5, ow = pix & 31;
                size_t oidx = (((size_t)n_img * Hout + (oh*OS + oph)) * Wout
                               + (ow*OS + opw)) * COUT + col;
                float v = acc[tm][tn][rg] + bv;
                if (RESID) v += bf2f(out[oidx]);
                if (RELU_OUT) v = fmaxf(v, 0.0f);
                out[oidx] = f2bf(v);
            }
        }
    }
}

// ---------------- fused residual block ----------------
__global__ __launch_bounds__(256)
void res_fused_k(const u16* __restrict__ in, const u16* __restrict__ w1,
                 const u16* __restrict__ w2, u16* __restrict__ out)
{
    constexpr int LDA = 40;
    __shared__ alignas(16) u16 smem[20480];   // 40KB
    u16* aT   = smem;
    u16* bT   = smem + 5120;
    u16* mT0  = smem;
    u16* mT1  = smem + 5120;
    u16* b2T0 = smem + 10240;
    u16* b2T1 = smem + 15360;

    const int tid = threadIdx.x;
    const int m0 = blockIdx.x * 128;
    const int n_img = m0 >> 10;
    const int pixbase = m0 & 1023;

    const int r = tid >> 1, half = tid & 1;
    const int pr = pixbase + r;
    const int ohr = pr >> 5, owr = pr & 31;
    const u16* inb = in + (size_t)n_img * 1024 * 128;

    const int wv = tid >> 6, lane = tid & 63;
    const int q = lane >> 4, l16 = lane & 15;
    const int mbase = wv * 32;
    const bool bload = r < 64;

    {
        const u16* s = w2 + r * 64 + half * 32;
        u16* d = (half ? b2T1 : b2T0) + r * LDA;
        *(uint4*)(d)      = *(const uint4*)(s);
        *(uint4*)(d + 8)  = *(const uint4*)(s + 8);
        *(uint4*)(d + 16) = *(const uint4*)(s + 16);
        *(uint4*)(d + 24) = *(const uint4*)(s + 24);
    }

    f32x4 acc[2][4] = {};
    uint4 pa0, pa1, pb0 = {0,0,0,0}, pb1 = {0,0,0,0};

#define RLOAD(IT) do {                                                          \
        int t_ = (IT) >> 2, cc_ = ((IT) & 3) * 32;                              \
        int ih_ = ohr + t_/3 - 1, iw_ = owr + t_%3 - 1;                         \
        bool ok_ = ((unsigned)ih_ < 32u) && ((unsigned)iw_ < 32u);              \
        pa0 = (uint4){0,0,0,0}; pa1 = (uint4){0,0,0,0};                         \
        if (ok_) {                                                              \
            const u16* as_ = inb + ((size_t)ih_ * 32 + iw_) * 128               \
                             + half * 16 + cc_;                                 \
            pa0 = *(const uint4*)(as_);                                         \
            pa1 = *(const uint4*)(as_ + 8);                                     \
        }                                                                       \
        if (bload) {                                                            \
            const u16* bs_ = w1 + ((size_t)t_ * 64 + r) * 128                   \
                             + half * 16 + cc_;                                 \
            pb0 = *(const uint4*)(bs_);                                         \
            pb1 = *(const uint4*)(bs_ + 8);                                     \
        }                                                                       \
    } while (0)

    RLOAD(0);
    for (int it = 0; it < 36; ++it) {
        __syncthreads();
        uint4 a0 = pa0, a1 = pa1;
        a0.x = relu2(a0.x); a0.y = relu2(a0.y); a0.z = relu2(a0.z); a0.w = relu2(a0.w);
        a1.x = relu2(a1.x); a1.y = relu2(a1.y); a1.z = relu2(a1.z); a1.w = relu2(a1.w);
        *(uint4*)&aT[r * LDA + half * 16]     = a0;
        *(uint4*)&aT[r * LDA + half * 16 + 8] = a1;
        if (bload) {
            *(uint4*)&bT[r * LDA + half * 16]     = pb0;
            *(uint4*)&bT[r * LDA + half * 16 + 8] = pb1;
        }
        __syncthreads();
        if (it + 1 < 36) RLOAD(it + 1);

        bf16x8 afr[2], bfr[4];
        #pragma unroll
        for (int tm = 0; tm < 2; ++tm)
            afr[tm] = *(const bf16x8*)&aT[(mbase + tm*16 + l16) * LDA + q * 8];
        #pragma unroll
        for (int tn = 0; tn < 4; ++tn)
            bfr[tn] = *(const bf16x8*)&bT[(tn*16 + l16) * LDA + q * 8];
        #pragma unroll
        for (int tm = 0; tm < 2; ++tm)
            #pragma unroll
            for (int tn = 0; tn < 4; ++tn)
                acc[tm][tn] = __builtin_amdgcn_mfma_f32_16x16x32_bf16(
                    afr[tm], bfr[tn], acc[tm][tn], 0, 0, 0);
    }
#undef RLOAD

    __syncthreads();

    #pragma unroll
    for (int tm = 0; tm < 2; ++tm)
        #pragma unroll
        for (int tn = 0; tn < 4; ++tn) {
            u16* dst = (tn < 2) ? mT0 : mT1;
            const int kc = (tn & 1) * 16 + l16;
            #pragma unroll
            for (int rg = 0; rg < 4; ++rg) {
                int row = mbase + tm*16 + q*4 + rg;
                dst[row * LDA + kc] = f2bf(fmaxf(acc[tm][tn][rg], 0.0f));
            }
        }
    __syncthreads();

    f32x4 acc2[2][8] = {};
    #pragma unroll
    for (int kk = 0; kk < 2; ++kk) {
        const u16* mp = kk ? mT1 : mT0;
        const u16* bp = kk ? b2T1 : b2T0;
        bf16x8 af[2], bf[8];
        #pragma unroll
        for (int tm = 0; tm < 2; ++tm)
            af[tm] = *(const bf16x8*)&mp[(mbase + tm*16 + l16) * LDA + q * 8];
        #pragma unroll
        for (int tn = 0; tn < 8; ++tn)
            bf[tn] = *(const bf16x8*)&bp[(tn*16 + l16) * LDA + q * 8];
        #pragma unroll
        for (int tm = 0; tm < 2; ++tm)
            #pragma unroll
            for (int tn = 0; tn < 8; ++tn)
                acc2[tm][tn] = __builtin_amdgcn_mfma_f32_16x16x32_bf16(
                    af[tm], bf[tn], acc2[tm][tn], 0, 0, 0);
    }

    #pragma unroll
    for (int tm = 0; tm < 2; ++tm)
        #pragma unroll
        for (int tn = 0; tn < 8; ++tn) {
            const int col = tn*16 + l16;
            #pragma unroll
            for (int rg = 0; rg < 4; ++rg) {
                const int m = mbase + tm*16 + q*4 + rg;
                const int pix = pixbase + m;
                size_t off = ((size_t)n_img * 1024 + pix) * 128 + col;
                out[off] = f2bf(acc2[tm][tn][rg] + bf2f(in[off]));
            }
        }
}

// ---------------- fused enc_adj (1x1 128->64) + VQ ----------------
// Phase A: Ze = TRrelu @ Wadj^T + b (K=128, 4 chunks, acc in C-layout).
// znorm per row via cross-lane reduce. Ze -> LDS (bf16, A-frag layout),
// frags to VGPRs, then LDS reused for 2x256-code codebook passes.
// score = ||e||^2+1 - 2 z.e; packed-key argmin (first-min tie-break) +
// exact fp32 min for SSE: sse_pos = znorm + minscore - 1.
__global__ __launch_bounds__(256)
void adjvq_k(const u16* __restrict__ TRin, const u16* __restrict__ wadj,
             const float* __restrict__ bias, const u16* __restrict__ Ebf,
             const float* __restrict__ enorm1, u16* __restrict__ Zq,
             u16* __restrict__ idx_out, float* __restrict__ sse)
{
    constexpr int LDA = 40;
    __shared__ alignas(16) u16 smem[18432];   // 36.9KB aliased region
    u16* aT  = smem;             // [0,5120)   phase A
    u16* bT  = smem + 5120;      // [5120,7680)
    u16* mT0 = smem;             // [0,5120)   Ze k0..31
    u16* mT1 = smem + 5120;      // [5120,10240) Ze k32..63
    u16* eld = smem;             // [0,18432)  codebook pass
    __shared__ float znorm_s[128];
    __shared__ float bestf_s[128];
    __shared__ float en1s[256];
    __shared__ int   bestk_s[128];
    __shared__ float red[256];

    const int tid = threadIdx.x;
    const int r = tid >> 1, half = tid & 1;
    const size_t gp = (size_t)blockIdx.x * 128 + r;
    const u16* arow = TRin + gp * 128 + half * 16;
    const u16* brow = wadj + (size_t)r * 128 + half * 16;

    const int wv = tid >> 6, lane = tid & 63;
    const int q = lane >> 4, l16 = lane & 15;
    const int mbase = wv * 32;

    // ---- phase A: 1x1 conv ----
    f32x4 acc[2][4] = {};
    for (int c0 = 0; c0 < 128; c0 += 32) {
        __syncthreads();
        uint4 a0 = *(const uint4*)(arow + c0);
        uint4 a1 = *(const uint4*)(arow + c0 + 8);
        a0.x = relu2(a0.x); a0.y = relu2(a0.y); a0.z = relu2(a0.z); a0.w = relu2(a0.w);
        a1.x = relu2(a1.x); a1.y = relu2(a1.y); a1.z = relu2(a1.z); a1.w = relu2(a1.w);
        *(uint4*)&aT[r * LDA + half * 16]     = a0;
        *(uint4*)&aT[r * LDA + half * 16 + 8] = a1;
        if (r < 64) {
            *(uint4*)&bT[r * LDA + half * 16]     = *(const uint4*)(brow + c0);
            *(uint4*)&bT[r * LDA + half * 16 + 8] = *(const uint4*)(brow + c0 + 8);
        }
        __syncthreads();
        bf16x8 afr[2], bfr[4];
        #pragma unroll
        for (int tm = 0; tm < 2; ++tm)
            afr[tm] = *(const bf16x8*)&aT[(mbase + tm*16 + l16) * LDA + q * 8];
        #pragma unroll
        for (int tn = 0; tn < 4; ++tn)
            bfr[tn] = *(const bf16x8*)&bT[(tn*16 + l16) * LDA + q * 8];
        #pragma unroll
        for (int tm = 0; tm < 2; ++tm)
            #pragma unroll
            for (int tn = 0; tn < 4; ++tn)
                acc[tm][tn] = __builtin_amdgcn_mfma_f32_16x16x32_bf16(
                    afr[tm], bfr[tn], acc[tm][tn], 0, 0, 0);
    }

    // bias + znorm (fp32) per row
    float zn[2][4] = {};   // [tm][rg]
    #pragma unroll
    for (int tm = 0; tm < 2; ++tm)
        #pragma unroll
        for (int tn = 0; tn < 4; ++tn) {
            const float bv = bias[tn*16 + l16];
            #pragma unroll
            for (int rg = 0; rg < 4; ++rg) {
                float z = acc[tm][tn][rg] + bv;
                acc[tm][tn][rg] = z;
                zn[tm][rg] = fmaf(z, z, zn[tm][rg]);
            }
        }
    #pragma unroll
    for (int m = 1; m < 16; m <<= 1)
        #pragma unroll
        for (int tm = 0; tm < 2; ++tm)
            #pragma unroll
            for (int rg = 0; rg < 4; ++rg)
                zn[tm][rg] += __shfl_xor(zn[tm][rg], m, 64);

    __syncthreads();   // all phase-A LDS reads done before mT overwrite

    #pragma unroll
    for (int tm = 0; tm < 2; ++tm) {
        #pragma unroll
        for (int tn = 0; tn < 4; ++tn) {
            u16* dst = (tn < 2) ? mT0 : mT1;
            const int kc = (tn & 1) * 16 + l16;
            #pragma unroll
            for (int rg = 0; rg < 4; ++rg) {
                int row = mbase + tm*16 + q*4 + rg;
                dst[row * LDA + kc] = f2bf(acc[tm][tn][rg]);
            }
        }
        if (l16 == 0)
            #pragma unroll
            for (int rg = 0; rg < 4; ++rg)
                znorm_s[mbase + tm*16 + q*4 + rg] = zn[tm][rg];
    }
    __syncthreads();

    // Ze A-fragments (rows mbase..mbase+31)
    bf16x8 alo[2], ahi[2];
    #pragma unroll
    for (int tile = 0; tile < 2; ++tile) {
        alo[tile] = *(const bf16x8*)&mT0[(mbase + tile*16 + l16) * LDA + q * 8];
        ahi[tile] = *(const bf16x8*)&mT1[(mbase + tile*16 + l16) * LDA + q * 8];
    }

    // ---- VQ ----
    unsigned key[2][4] = {{0xFFFFFFFFu,0xFFFFFFFFu,0xFFFFFFFFu,0xFFFFFFFFu},
                          {0xFFFFFFFFu,0xFFFFFFFFu,0xFFFFFFFFu,0xFFFFFFFFu}};
    float fb[2][4] = {{1e30f,1e30f,1e30f,1e30f},{1e30f,1e30f,1e30f,1e30f}};

    for (int k0 = 0; k0 < 512; k0 += 256) {
        __syncthreads();
        const uint4* src = (const uint4*)(Ebf + k0 * 64);
        #pragma unroll
        for (int i = tid; i < 2048; i += 256) {
            int row = i >> 3, sub = i & 7;
            *(uint4*)&eld[row * 72 + sub * 8] = src[i];
        }
        en1s[tid] = enorm1[k0 + tid];
        __syncthreads();

        for (int t = 0; t < 16; ++t) {
            const int nl = t * 16 + l16;
            bf16x8 b0 = *(const bf16x8*)&eld[nl * 72 + q * 8];
            bf16x8 b1 = *(const bf16x8*)&eld[nl * 72 + 32 + q * 8];
            const float en1 = en1s[nl];
            const unsigned ng = (unsigned)(k0 + nl);
            #pragma unroll
            for (int tile = 0; tile < 2; ++tile) {
                f32x4 sc4 = {0.0f, 0.0f, 0.0f, 0.0f};
                sc4 = __builtin_amdgcn_mfma_f32_16x16x32_bf16(alo[tile], b0, sc4, 0, 0, 0);
                sc4 = __builtin_amdgcn_mfma_f32_16x16x32_bf16(ahi[tile], b1, sc4, 0, 0, 0);
                #pragma unroll
                for (int rg = 0; rg < 4; ++rg) {
                    float sc = fmaf(sc4[rg], -2.0f, en1);
                    unsigned kk2 = (__float_as_uint(sc) & 0xFFFFFE00u) | ng;
                    key[tile][rg] = min(key[tile][rg], kk2);
                    fb[tile][rg] = fminf(fb[tile][rg], sc);
                }
            }
        }
    }

    #pragma unroll
    for (int m = 1; m < 16; m <<= 1)
        #pragma unroll
        for (int tile = 0; tile < 2; ++tile)
            #pragma unroll
            for (int rg = 0; rg < 4; ++rg) {
                unsigned o = (unsigned)__shfl_xor((int)key[tile][rg], m, 64);
                key[tile][rg] = min(key[tile][rg], o);
                float of = __shfl_xor(fb[tile][rg], m, 64);
                fb[tile][rg] = fminf(fb[tile][rg], of);
            }
    if (l16 == 0)
        #pragma unroll
        for (int tile = 0; tile < 2; ++tile)
            #pragma unroll
            for (int rg = 0; rg < 4; ++rg) {
                int row = mbase + tile*16 + q*4 + rg;
                bestk_s[row] = (int)(key[tile][rg] & 511u);
                bestf_s[row] = fb[tile][rg];
            }
    __syncthreads();

    // epilogue: Zq copy + idx + SSE
    const int pos = tid >> 1, seg = tid & 1;
    const size_t p = (size_t)blockIdx.x * 128 + pos;
    const int k = bestk_s[pos];
    const u16* ep = Ebf + (size_t)k * 64 + seg * 32;
    u16* qp = Zq + p * 64 + seg * 32;
    #pragma unroll
    for (int h = 0; h < 4; ++h)
        *(uint4*)(qp + h * 8) = *(const uint4*)(ep + h * 8);
    if (seg == 0) idx_out[p] = (u16)k;
    red[tid] = (seg == 0) ? (znorm_s[pos] + bestf_s[pos] - 1.0f) : 0.0f;
    __syncthreads();
    for (int s = 128; s > 0; s >>= 1) {
        if (tid < s) red[tid] += red[tid + s];
        __syncthreads();
    }
    if (tid == 0) atomicAdd(sse, red[0]);
}

// ---------------- conv1 as MFMA im2col GEMM ----------------
__global__ __launch_bounds__(256)
void conv1_mfma_k(const float* __restrict__ x, const u16* __restrict__ wc1b,
                  const float* __restrict__ b, u16* __restrict__ out)
{
    __shared__ alignas(16) u16 smem[15360];
    u16* aT0 = smem;
    u16* aT1 = smem + 5120;
    u16* bT0 = smem + 10240;
    u16* bT1 = smem + 12800;

    const int tid = threadIdx.x;
    const int gbase = blockIdx.x * 128;
    const int r = tid >> 1, half = tid & 1;
    const int p = gbase + r;
    const int ow = p & 63, oh = (p >> 6) & 63, n = p >> 12;
    const float* xb = x + (size_t)n * 3 * 16384;

    {
        int row = tid >> 2, sub = tid & 3;
        *(uint4*)&bT0[row*40 + sub*8] = *(const uint4*)(wc1b + row*64 + sub*8);
        *(uint4*)&bT1[row*40 + sub*8] = *(const uint4*)(wc1b + row*64 + 32 + sub*8);
    }

    float vals[24];
    const int kb = half * 24;
    #pragma unroll
    for (int j = 0; j < 24; ++j) {
        int k = kb + j;
        int ci = k >> 4, kh = (k >> 2) & 3, kw = k & 3;
        int ih = oh*2 - 1 + kh, iw = ow*2 - 1 + kw;
        bool ok = ((unsigned)ih < 128u) && ((unsigned)iw < 128u);
        vals[j] = ok ? xb[ci*16384 + ih*128 + iw] : 0.0f;
    }
    unsigned pk[12];
    #pragma unroll
    for (int jj = 0; jj < 12; ++jj)
        pk[jj] = (unsigned)f2bf(vals[2*jj]) | ((unsigned)f2bf(vals[2*jj+1]) << 16);
    unsigned* a0row = (unsigned*)&aT0[r * 40];
    unsigned* a1row = (unsigned*)&aT1[r * 40];
    if (half == 0) {
        #pragma unroll
        for (int jj = 0; jj < 12; ++jj) a0row[jj] = pk[jj];
    } else {
        a0row[12] = pk[0]; a0row[13] = pk[1];
        a0row[14] = pk[2]; a0row[15] = pk[3];
        #pragma unroll
        for (int jj = 4; jj < 12; ++jj) a1row[jj - 4] = pk[jj];
        *(uint4*)&aT1[r*40 + 16] = (uint4){0,0,0,0};
        *(uint4*)&aT1[r*40 + 24] = (uint4){0,0,0,0};
    }
    __syncthreads();

    const int wv = tid >> 6, lane = tid & 63;
    const int q = lane >> 4, l16 = lane & 15;
    const int mbase = wv * 32;

    f32x4 acc[2][4] = {};
    bf16x8 af0[2], af1[2], bf0[4], bf1[4];
    #pragma unroll
    for (int tm = 0; tm < 2; ++tm) {
        af0[tm] = *(const bf16x8*)&aT0[(mbase + tm*16 + l16) * 40 + q * 8];
        af1[tm] = *(const bf16x8*)&aT1[(mbase + tm*16 + l16) * 40 + q * 8];
    }
    #pragma unroll
    for (int tn = 0; tn < 4; ++tn) {
        bf0[tn] = *(const bf16x8*)&bT0[(tn*16 + l16) * 40 + q * 8];
        bf1[tn] = *(const bf16x8*)&bT1[(tn*16 + l16) * 40 + q * 8];
    }
    #pragma unroll
    for (int tm = 0; tm < 2; ++tm)
        #pragma unroll
        for (int tn = 0; tn < 4; ++tn) {
            acc[tm][tn] = __builtin_amdgcn_mfma_f32_16x16x32_bf16(
                af0[tm], bf0[tn], acc[tm][tn], 0, 0, 0);
            acc[tm][tn] = __builtin_amdgcn_mfma_f32_16x16x32_bf16(
                af1[tm], bf1[tn], acc[tm][tn], 0, 0, 0);
        }

    float bv[4];
    #pragma unroll
    for (int tn = 0; tn < 4; ++tn) bv[tn] = b[tn*16 + l16];

    __syncthreads();
    u16* cbuf = smem;
    #pragma unroll
    for (int tm = 0; tm < 2; ++tm)
        #pragma unroll
        for (int tn = 0; tn < 4; ++tn)
            #pragma unroll
            for (int rg = 0; rg < 4; ++rg) {
                int row = mbase + tm*16 + q*4 + rg;
                int col = tn*16 + l16;
                cbuf[row*72 + col] = f2bf(fmaxf(acc[tm][tn][rg] + bv[tn], 0.0f));
            }
    __syncthreads();

    u16* ob = out + (size_t)gbase * 64;
    #pragma unroll
    for (int it = 0; it < 4; ++it) {
        int j = it * 256 + tid;
        uint4 v = *(const uint4*)&cbuf[(j >> 3) * 72 + (j & 7) * 8];
        *(uint4*)(ob + j * 8) = v;
    }
}

// ---------------- tc2 as MFMA parity GEMM ----------------
__global__ __launch_bounds__(256)
void tc2_mfma_k(const u16* __restrict__ in, const u16* __restrict__ wT,
                const float* __restrict__ bias, float* __restrict__ out)
{
    constexpr int LDA = 40;
    __shared__ alignas(16) u16 aT[128 * LDA];
    __shared__ alignas(16) u16 bT[16 * LDA];
    __shared__ float cT[128 * 17];

    const int tid = threadIdx.x;
    const int m0 = blockIdx.x * 128;
    const int n_img = m0 >> 12;
    const int pixbase = m0 & 4095;
    const int y0 = pixbase >> 6;

    const int r = tid >> 1, half = tid & 1;
    const int pr = pixbase + r;
    const int yr = pr >> 6, xr = pr & 63;
    const u16* inb = in + (size_t)n_img * 4096 * 64;

    const int wv = tid >> 6, lane = tid & 63;
    const int q = lane >> 4, l16 = lane & 15;
    const int mbase = wv * 32;

    f32x4 acc[2] = {};

    for (int t = 0; t < 9; ++t) {
        const int ih = yr + t/3 - 1;
        const int iw = xr + t%3 - 1;
        const bool ok = ((unsigned)ih < 64u) && ((unsigned)iw < 64u);
        const u16* asrc = ok ? (inb + ((size_t)ih * 64 + iw) * 64 + half * 16) : inb;
        const u16* bsrc = wT + ((size_t)t * 16 + r) * 64 + half * 16;

        for (int c0 = 0; c0 < 64; c0 += 32) {
            __syncthreads();
            uint4 a0 = {0,0,0,0}, a1 = {0,0,0,0};
            if (ok) {
                a0 = *(const uint4*)(asrc + c0);
                a1 = *(const uint4*)(asrc + c0 + 8);
            }
            *(uint4*)&aT[r * LDA + half * 16]     = a0;
            *(uint4*)&aT[r * LDA + half * 16 + 8] = a1;
            if (r < 16) {
                *(uint4*)&bT[r * LDA + half * 16]     = *(const uint4*)(bsrc + c0);
                *(uint4*)&bT[r * LDA + half * 16 + 8] = *(const uint4*)(bsrc + c0 + 8);
            }
            __syncthreads();

            bf16x8 af0 = *(const bf16x8*)&aT[(mbase + l16) * LDA + q * 8];
            bf16x8 af1 = *(const bf16x8*)&aT[(mbase + 16 + l16) * LDA + q * 8];
            bf16x8 bf  = *(const bf16x8*)&bT[l16 * LDA + q * 8];
            acc[0] = __builtin_amdgcn_mfma_f32_16x16x32_bf16(af0, bf, acc[0], 0, 0, 0);
            acc[1] = __builtin_amdgcn_mfma_f32_16x16x32_bf16(af1, bf, acc[1], 0, 0, 0);
        }
    }

    #pragma unroll
    for (int tm = 0; tm < 2; ++tm)
        #pragma unroll
        for (int rg = 0; rg < 4; ++rg)
            cT[(mbase + tm*16 + q*4 + rg) * 17 + l16] = acc[tm][rg];
    __syncthreads();

    #pragma unroll
    for (int it = 0; it < 6; ++it) {
        int j = it * 256 + tid;
        int co  = j >> 9;
        int rem = j & 511;
        int ohl = rem >> 7;
        int ow  = rem & 127;
        int oh  = 2*y0 + ohl;
        int lp  = (ohl >> 1) * 64 + (ow >> 1);
        int col = ((ohl & 1) * 2 + (ow & 1)) * 4 + co;
        float v = cT[lp * 17 + col] + bias[co];
        out[(((size_t)n_img * 3 + co) * 128 + oh) * 128 + ow] = v;
    }
}

// ---------------- histogram by scan ----------------
__global__ __launch_bounds__(256)
void hist_k(const u16* __restrict__ idx, float* __restrict__ counts)
{
    __shared__ int red[256];
    const int k = blockIdx.x;
    const int tid = threadIdx.x;
    int c = 0;
    const uint4* p4 = (const uint4*)idx;
    for (int i = tid; i < 8192; i += 256) {
        uint4 v = p4[i];
        unsigned ua[4] = {v.x, v.y, v.z, v.w};
        #pragma unroll
        for (int j = 0; j < 4; ++j) {
            c += ((ua[j] & 0xFFFFu) == (unsigned)k);
            c += ((ua[j] >> 16)     == (unsigned)k);
        }
    }
    red[tid] = c;
    __syncthreads();
    for (int s = 128; s > 0; s >>= 1) {
        if (tid < s) red[tid] += red[tid + s];
        __syncthreads();
    }
    if (tid == 0) counts[k] = (float)red[0];
}

// ---------------- merged prep ----------------
__device__ __forceinline__ void wconv_tf(const float* __restrict__ w,
                                         u16* __restrict__ o,
                                         int COUT, int CIN, int KK, int i)
{
    int ci = i % CIN; int t = i / CIN; int co = t % COUT; t /= COUT;
    o[i] = f2bf(w[(co*CIN + ci)*KK + t]);
}

__global__ __launch_bounds__(256)
void prep_k(const float* __restrict__ enc_w1, const float* __restrict__ enc_w2,
            const float* __restrict__ enc_w3, const float* __restrict__ enc_w4,
            const float* __restrict__ enc_res_w1, const float* __restrict__ enc_res_w2,
            const float* __restrict__ dec_res_w1, const float* __restrict__ dec_res_w2,
            const float* __restrict__ enc_adj_w, const float* __restrict__ dec_adj_w,
            const float* __restrict__ tc1_w, const float* __restrict__ tc2_w,
            const float* __restrict__ E,
            u16* __restrict__ wc1b, u16* __restrict__ wc2, u16* __restrict__ wc3,
            u16* __restrict__ wc4, u16* __restrict__ wer1, u16* __restrict__ wer2,
            u16* __restrict__ wdr1, u16* __restrict__ wdr2, u16* __restrict__ weadj,
            u16* __restrict__ wdadj, u16* __restrict__ wtc1, u16* __restrict__ wtc2b,
            u16* __restrict__ Ebf, float* __restrict__ enorm1, float* __restrict__ sse)
{
    const int b = blockIdx.x, tid = threadIdx.x;
    if (b < 512) {
        wconv_tf(enc_w2, wc2, 128, 64, 16, b * 256 + tid);
    } else if (b < 1088) {
        wconv_tf(enc_w3, wc3, 128, 128, 9, (b - 512) * 256 + tid);
    } else if (b < 1664) {
        wconv_tf(enc_w4, wc4, 128, 128, 9, (b - 1088) * 256 + tid);
    } else if (b < 2240) {
        int i = (b - 1664) * 256 + tid;
        int sub = i / 73728, rem = i - sub * 73728;
        wconv_tf(enc_res_w1 + sub * 73728, wer1 + sub * 73728, 64, 128, 9, rem);
    } else if (b < 2816) {
        int i = (b - 2240) * 256 + tid;
        int sub = i / 73728, rem = i - sub * 73728;
        wconv_tf(dec_res_w1 + sub * 73728, wdr1 + sub * 73728, 64, 128, 9, rem);
    } else if (b < 2880) {
        int i = (b - 2816) * 256 + tid;
        int sub = i >> 13, rem = i & 8191;
        wconv_tf(enc_res_w2 + sub * 8192, wer2 + sub * 8192, 128, 64, 1, rem);
    } else if (b < 2944) {
        int i = (b - 2880) * 256 + tid;
        int sub = i >> 13, rem = i & 8191;
        wconv_tf(dec_res_w2 + sub * 8192, wdr2 + sub * 8192, 128, 64, 1, rem);
    } else if (b < 2976) {
        wconv_tf(enc_adj_w, weadj, 64, 128, 1, (b - 2944) * 256 + tid);
    } else if (b < 3264) {
        wconv_tf(dec_adj_w, wdadj, 128, 64, 9, (b - 2976) * 256 + tid);
    } else if (b < 3776) {
        int i = (b - 3264) * 256 + tid;
        int ci = i & 127; int co = (i >> 7) & 63; int t = (i >> 13) & 3; int p = i >> 15;
        int poh = p >> 1, pw = p & 1; int a = t >> 1, bb = t & 1;
        int kh = poh ? (a ? 2 : 0) : (a ? 3 : 1);
        int kw = pw  ? (bb ? 2 : 0) : (bb ? 3 : 1);
        wtc1[i] = f2bf(tc1_w[((ci*64 + co)*4 + kh)*4 + kw]);
    } else if (b < 3812) {
        int i = (b - 3776) * 256 + tid;
        int ci = i & 63; int col = (i >> 6) & 15; int t = i >> 10;
        int dh = t / 3 - 1, dw = t % 3 - 1;
        int pp = col >> 2, co = col & 3;
        float v = 0.0f;
        if (co < 3) {
            int poh = pp >> 1, pw = pp & 1;
            int kh = poh ? (dh == 1 ? 0 : (dh == 0 ? 2 : -1))
                         : (dh == 0 ? 1 : (dh == -1 ? 3 : -1));
            int kw = pw  ? (dw == 1 ? 0 : (dw == 0 ? 2 : -1))
                         : (dw == 0 ? 1 : (dw == -1 ? 3 : -1));
            if (kh >= 0 && kw >= 0)
                v = tc2_w[((ci*3 + co)*4 + kh)*4 + kw];
        }
        wtc2b[i] = f2bf(v);
    } else if (b < 3814) {
        int k = (b - 3812) * 256 + tid;
        float s = 0.0f;
        #pragma unroll
        for (int d = 0; d < 64; ++d) {
            u16 h = f2bf(E[k*64 + d]);
            Ebf[k*64 + d] = h;
            float v = bf2f(h);
            s = fmaf(v, v, s);
        }
        enorm1[k] = s + 1.0f;
    } else if (b < 3830) {
        int i = (b - 3814) * 256 + tid;
        int co = i >> 6, k = i & 63;
        float v = 0.0f;
        if (k < 48) {
            int ci = k >> 4, kh = (k >> 2) & 3, kw = k & 3;
            v = enc_w1[((co*3 + ci)*4 + kh)*4 + kw];
        }
        wc1b[i] = f2bf(v);
    } else {
        if (tid == 0) sse[0] = 0.0f;
    }
}

// ---------------- scalars ----------------
__global__ void finalize_k(const float* __restrict__ counts, const float* __restrict__ sse,
                           float* __restrict__ out_head, float* __restrict__ out_tail)
{
    __shared__ float red[512];
    int t = threadIdx.x;
    float pr = counts[t] / 65536.0f;
    red[t] = -pr * log2f(pr + 1e-10f);
    __syncthreads();
    for (int s = 256; s > 0; s >>= 1) {
        if (t < s) red[t] += red[t + s];
        __syncthreads();
    }
    if (t == 0) {
        float entropy = red[0];
        float mse = sse[0] / 4194304.0f;
        out_head[0] = 1.25f * mse;
        out_tail[0] = mse;
        out_tail[1] = mse;
        out_tail[2] = exp2f(entropy);
    }
}

// ---------------------------------------------------------------------------
extern "C" void kernel_launch(void* const* d_in, const int* in_sizes, int n_in,
                              void* d_out, int out_size, void* d_ws, size_t ws_size,
                              hipStream_t stream)
{
    const float* x         = (const float*)d_in[0];
    const float* enc_w1    = (const float*)d_in[1];
    const float* enc_b1    = (const float*)d_in[2];
    const float* enc_w2    = (const float*)d_in[3];
    const float* enc_b2    = (const float*)d_in[4];
    const float* enc_w3    = (const float*)d_in[5];
    const float* enc_b3    = (const float*)d_in[6];
    const float* enc_w4    = (const float*)d_in[7];
    const float* enc_b4    = (const float*)d_in[8];
    const float* enc_res_w1= (const float*)d_in[9];
    const float* enc_res_w2= (const float*)d_in[10];
    const float* enc_adj_w = (const float*)d_in[11];
    const float* enc_adj_b = (const float*)d_in[12];
    const float* Ecb       = (const float*)d_in[13];
    const float* dec_adj_w = (const float*)d_in[14];
    const float* dec_adj_b = (const float*)d_in[15];
    const float* dec_res_w1= (const float*)d_in[16];
    const float* dec_res_w2= (const float*)d_in[17];
    const float* tc1_w     = (const float*)d_in[18];
    const float* tc1_b     = (const float*)d_in[19];
    const float* tc2_w     = (const float*)d_in[20];
    const float* tc2_b     = (const float*)d_in[21];

    char* wsb = (char*)d_ws;
    u16*   wc2   = (u16*)(wsb + 0);
    u16*   wc3   = (u16*)(wsb + 262144);
    u16*   wc4   = (u16*)(wsb + 557056);
    u16*   wer1  = (u16*)(wsb + 851968);
    u16*   wer2  = (u16*)(wsb + 1146880);
    u16*   weadj = (u16*)(wsb + 1179648);
    u16*   wdadj = (u16*)(wsb + 1196032);
    u16*   wdr1  = (u16*)(wsb + 1343488);
    u16*   wdr2  = (u16*)(wsb + 1638400);
    u16*   wtc1  = (u16*)(wsb + 1671168);
    u16*   wtc2b = (u16*)(wsb + 1933312);
    float* counts= (float*)(wsb + 1951744);
    float* sse   = counts + 512;
    u16*   Ebf   = (u16*)(wsb + 1955840);
    float* enorm1= (float*)(wsb + 2021376);
    u16*   wc1b  = (u16*)(wsb + 2023424);
    u16*   H1    = (u16*)(wsb + 2097152);
    u16*   TR    = (u16*)(wsb + 35651584);
    u16*   H3    = (u16*)(wsb + 52428800);
    u16*   ZQ    = (u16*)(wsb + 85983232);
    u16*   IDX   = (u16*)(wsb + 94371840);
    u16*   TC1O  = H1;

    float* out  = (float*)d_out;
    float* xrec = out + 1;
    float* tail = out + 1 + 3145728;

    // ---- single merged prep dispatch ----
    prep_k<<<3831, 256, 0, stream>>>(enc_w1, enc_w2, enc_w3, enc_w4,
        enc_res_w1, enc_res_w2, dec_res_w1, dec_res_w2, enc_adj_w, dec_adj_w,
        tc1_w, tc2_w, Ecb, wc1b, wc2, wc3, wc4, wer1, wer2, wdr1, wdr2,
        weadj, wdadj, wtc1, wtc2b, Ebf, enorm1, sse);

    // ---- encoder ----
    conv1_mfma_k<<<2048, 256, 0, stream>>>(x, wc1b, enc_b1, H1);
    mfma_conv_k<64,128,2,false,true,true,false><<<dim3(512,2), 256, 0, stream>>>
        (H1, wc2, enc_b2, TR, 64, 64, 32, 32, 1);
    mfma_conv_k<128,128,1,false,true,true,false><<<dim3(512,2), 256, 0, stream>>>
        (TR, wc3, enc_b3, H3, 32, 32, 32, 32, 1);
    mfma_conv_k<128,128,1,false,false,true,false><<<dim3(512,2), 256, 0, stream>>>
        (H3, wc4, enc_b4, TR, 32, 32, 32, 32, 1);
    // fused res blocks: TR -> H3 -> TR
    res_fused_k<<<512, 256, 0, stream>>>(TR, wer1,         wer2,        H3);
    res_fused_k<<<512, 256, 0, stream>>>(H3, wer1 + 73728, wer2 + 8192, TR);

    // ---- fused enc_adj + VQ ----
    adjvq_k<<<512, 256, 0, stream>>>(TR, weadj, enc_adj_b, Ebf, enorm1,
                                     ZQ, IDX, sse);
    hist_k<<<512, 256, 0, stream>>>(IDX, counts);

    // ---- decoder ----
    mfma_conv_k<64,128,1,false,false,true,false><<<dim3(512,2), 256, 0, stream>>>
        (ZQ, wdadj, dec_adj_b, H3, 32, 32, 32, 32, 1);
    // fused res blocks: H3 -> TR -> H3
    res_fused_k<<<512, 256, 0, stream>>>(H3, wdr1,         wdr2,        TR);
    res_fused_k<<<512, 256, 0, stream>>>(TR, wdr1 + 73728, wdr2 + 8192, H3);
    // tc1: all 4 parities in one dispatch (blockIdx.z)
    mfma_conv_k<128,64,3,true,true,true,false><<<dim3(512,1,4), 256, 0, stream>>>
        (H3, wtc1, tc1_b, TC1O, 32, 32, 64, 64, 2);
    tc2_mfma_k<<<2048, 256, 0, stream>>>(TC1O, wtc2b, tc2_b, xrec);

    // ---- scalars ----
    finalize_k<<<1, 512, 0, stream>>>(counts, sse, out, tail);
}